// Round 1
// baseline (4655.839 us; speedup 1.0000x reference)
//
#include <hip/hip_runtime.h>
#include <cstdint>
#include <cstddef>

typedef unsigned long long u64;

// Problem constants (B=1)
static constexpr int S_    = 2048;   // sequence
static constexpr int H_    = 2048;   // hidden
static constexpr int QL_   = 1536;
static constexpr int KVL_  = 512;
static constexpr int NH_   = 16;
static constexpr int DQ_   = 192;    // NOPE+ROPE
static constexpr int TOPKC = 512;

#define SCALE_ATTN 0.07216878364870323f   // (192)^-0.5
#define ISCALE_ID  0.08838834764831845f   // (128)^-0.5
#define EPS_F 1e-6f

// ---------------- generic f32 GEMM: C[M,N] = A[M,K]@B[K,N], strided A ----------------
__global__ __launch_bounds__(256) void k_gemm(const float* __restrict__ A, int lda,
                                              const float* __restrict__ B, int ldb,
                                              float* __restrict__ C, int ldc,
                                              int M, int N, int K) {
  __shared__ float As[64][17];   // [m][k], +1 pad breaks bank conflicts
  __shared__ float Bs[16][64];   // [k][n]
  const int bm = blockIdx.y * 64, bn = blockIdx.x * 64;
  const int tid = threadIdx.x;
  const int tm = (tid & 15) * 4, tn = (tid >> 4) * 4;
  float acc[4][4] = {};
  for (int k0 = 0; k0 < K; k0 += 16) {
#pragma unroll
    for (int i = 0; i < 4; i++) {
      int m = (tid >> 4) + i * 16;
      int kk = tid & 15;
      float v = 0.f;
      if (bm + m < M && k0 + kk < K) v = A[(size_t)(bm + m) * lda + k0 + kk];
      As[m][kk] = v;
    }
#pragma unroll
    for (int i = 0; i < 4; i++) {
      int n = tid & 63;
      int kk = (tid >> 6) + i * 4;
      float v = 0.f;
      if (k0 + kk < K && bn + n < N) v = B[(size_t)(k0 + kk) * ldb + bn + n];
      Bs[kk][n] = v;
    }
    __syncthreads();
#pragma unroll
    for (int kk = 0; kk < 16; kk++) {
      float a[4], b[4];
#pragma unroll
      for (int i = 0; i < 4; i++) a[i] = As[tm + i][kk];
#pragma unroll
      for (int j = 0; j < 4; j++) b[j] = Bs[kk][tn + j];
#pragma unroll
      for (int i = 0; i < 4; i++)
#pragma unroll
        for (int j = 0; j < 4; j++) acc[i][j] = fmaf(a[i], b[j], acc[i][j]);
    }
    __syncthreads();
  }
#pragma unroll
  for (int i = 0; i < 4; i++) {
    int m = bm + tm + i;
    if (m >= M) continue;
#pragma unroll
    for (int j = 0; j < 4; j++) {
      int n = bn + tn + j;
      if (n < N) C[(size_t)m * ldc + n] = acc[i][j];
    }
  }
}

// ---------------- RMSNorm in-place over n cols of each row (row stride given) ----------------
__global__ __launch_bounds__(256) void k_rmsnorm(float* __restrict__ x, const float* __restrict__ gamma,
                                                 int rowstride, int n) {
  int r = blockIdx.x;
  float* p = x + (size_t)r * rowstride;
  __shared__ float red[256];
  float s = 0.f;
  for (int i = threadIdx.x; i < n; i += 256) { float v = p[i]; s += v * v; }
  red[threadIdx.x] = s; __syncthreads();
  for (int st = 128; st > 0; st >>= 1) { if (threadIdx.x < st) red[threadIdx.x] += red[threadIdx.x + st]; __syncthreads(); }
  float scl = rsqrtf(red[0] / (float)n + EPS_F);
  for (int i = threadIdx.x; i < n; i += 256) p[i] = p[i] * scl * gamma[i];
}

// ---------------- RoPE in-place: pairs (i, i+32), i<32, at base + t*rowstride + h*hstride + off ----------------
__global__ __launch_bounds__(256) void k_rope(float* __restrict__ base, int rowstride, int nh, int hstride,
                                              int off, const float* __restrict__ cosb, const float* __restrict__ sinb,
                                              int total) {
  int idx = blockIdx.x * 256 + threadIdx.x;
  if (idx >= total) return;
  int i = idx & 31;
  int h = (idx >> 5) % nh;
  int t = idx / (32 * nh);
  float* p = base + (size_t)t * rowstride + h * hstride + off;
  float x1 = p[i], x2 = p[i + 32];
  float c = cosb[t * 32 + i], s = sinb[t * 32 + i];
  p[i] = x1 * c - x2 * s;
  p[i + 32] = x1 * s + x2 * c;
}

// ---------------- ki: LayerNorm(128) then RoPE on first 64, in-place. 128 threads/block ----------------
__global__ __launch_bounds__(128) void k_ki_ln_rope(float* __restrict__ ki, const float* __restrict__ g,
                                                    const float* __restrict__ b,
                                                    const float* __restrict__ cosb, const float* __restrict__ sinb) {
  int t = blockIdx.x, i = threadIdx.x;
  float* p = ki + (size_t)t * 128;
  __shared__ float red[128];
  __shared__ float buf[128];
  float v = p[i];
  red[i] = v; __syncthreads();
  for (int st = 64; st > 0; st >>= 1) { if (i < st) red[i] += red[i + st]; __syncthreads(); }
  float mean = red[0] * (1.f / 128.f);
  __syncthreads();
  float d = v - mean;
  red[i] = d * d; __syncthreads();
  for (int st = 64; st > 0; st >>= 1) { if (i < st) red[i] += red[i + st]; __syncthreads(); }
  float var = red[0] * (1.f / 128.f);
  float y = d * rsqrtf(var + EPS_F) * g[i] + b[i];
  buf[i] = y; __syncthreads();
  float out;
  if (i < 32) {
    float c = cosb[t * 32 + i], s = sinb[t * 32 + i];
    out = buf[i] * c - buf[i + 32] * s;
  } else if (i < 64) {
    int j = i - 32;
    float c = cosb[t * 32 + j], s = sinb[t * 32 + j];
    out = buf[j] * s + buf[i] * c;
  } else out = y;
  p[i] = out;
}

// ---------------- indexer scores: idx[t][s] = sum_h w[t,h]*relu(qi[t,h,:].ki[s,:])*ISCALE, causal tiles ----------------
__global__ __launch_bounds__(256) void k_idx_scores(const float* __restrict__ qi, const float* __restrict__ ki,
                                                    const float* __restrict__ wb, float* __restrict__ out) {
  int tb = blockIdx.x, sb = blockIdx.y;
  if (sb > tb) return;
  int t0 = tb * 32, s0 = sb * 32;
  __shared__ float Ks[32][130];
  __shared__ float Qs[32][130];
  __shared__ float Ws[32][16];
  int tid = threadIdx.x;
  for (int i = tid; i < 32 * 128; i += 256) {
    int r = i >> 7, c = i & 127;
    Ks[r][c] = ki[(size_t)(s0 + r) * 128 + c];
  }
  for (int i = tid; i < 32 * 16; i += 256) {
    int r = i >> 4, c = i & 15;
    Ws[r][c] = wb[(size_t)(t0 + r) * 16 + c];
  }
  int ttb = (tid & 15) * 2, ssb = (tid >> 4) * 2;
  float acc00 = 0.f, acc01 = 0.f, acc10 = 0.f, acc11 = 0.f;
  for (int h = 0; h < 16; h++) {
    __syncthreads();
    for (int i = tid; i < 32 * 128; i += 256) {
      int r = i >> 7, c = i & 127;
      Qs[r][c] = qi[(size_t)(t0 + r) * 2048 + h * 128 + c];
    }
    __syncthreads();
    float d00 = 0.f, d01 = 0.f, d10 = 0.f, d11 = 0.f;
    for (int d = 0; d < 128; d++) {
      float q0 = Qs[ttb][d], q1 = Qs[ttb + 1][d];
      float k0 = Ks[ssb][d], k1 = Ks[ssb + 1][d];
      d00 = fmaf(q0, k0, d00); d01 = fmaf(q0, k1, d01);
      d10 = fmaf(q1, k0, d10); d11 = fmaf(q1, k1, d11);
    }
    float w0 = Ws[ttb][h], w1 = Ws[ttb + 1][h];
    acc00 += w0 * fmaxf(d00, 0.f);
    acc01 += w0 * fmaxf(d01, 0.f);
    acc10 += w1 * fmaxf(d10, 0.f);
    acc11 += w1 * fmaxf(d11, 0.f);
  }
  out[(size_t)(t0 + ttb)     * 2048 + s0 + ssb]     = acc00 * ISCALE_ID;
  out[(size_t)(t0 + ttb)     * 2048 + s0 + ssb + 1] = acc01 * ISCALE_ID;
  out[(size_t)(t0 + ttb + 1) * 2048 + s0 + ssb]     = acc10 * ISCALE_ID;
  out[(size_t)(t0 + ttb + 1) * 2048 + s0 + ssb + 1] = acc11 * ISCALE_ID;
}

// ---------------- per-row top-K -> 2048-bit mask (32 u64 words per row) ----------------
__global__ __launch_bounds__(256) void k_topk_mask(const float* __restrict__ idx_sc, u64* __restrict__ maskw) {
  int t = blockIdx.x;
  int tid = threadIdx.x;
  int n = t + 1;
  if (n <= TOPKC) {             // all causal positions selected
    if (tid < 32) {
      int lo = tid * 64, hi = lo + 63;
      u64 wv;
      if (t >= hi) wv = ~0ULL;
      else if (t < lo) wv = 0ULL;
      else wv = (~0ULL) >> (63 - (t - lo));
      maskw[(size_t)t * 32 + tid] = wv;
    }
    return;
  }
  __shared__ unsigned int u[2048];
  __shared__ int hist[256];
  __shared__ u64 mw[32];
  __shared__ int sel_b, new_target, tie_base;
  __shared__ int wcnt[4];
  if (tid < 32) mw[tid] = 0ULL;
  const float* row = idx_sc + (size_t)t * 2048;
  for (int s = tid; s < n; s += 256) {
    unsigned int bb = __float_as_uint(row[s]);
    u[s] = (bb & 0x80000000u) ? ~bb : (bb | 0x80000000u);   // order-preserving key
  }
  __syncthreads();
  unsigned int prefix = 0;
  int target = TOPKC;
  for (int shift = 24; shift >= 0; shift -= 8) {
    hist[tid] = 0;
    __syncthreads();
    unsigned int himask = (shift == 24) ? 0u : (0xFFFFFFFFu << (shift + 8));
    for (int s = tid; s < n; s += 256) {
      unsigned int uv = u[s];
      if ((uv & himask) == prefix) atomicAdd(&hist[(uv >> shift) & 0xFF], 1);
    }
    __syncthreads();
    if (tid == 0) {
      int cum = 0, b = 255;
      for (; b > 0; b--) {
        if (cum + hist[b] >= target) break;
        cum += hist[b];
      }
      sel_b = b;
      new_target = target - cum;
    }
    __syncthreads();
    prefix |= ((unsigned int)sel_b) << shift;
    target = new_target;
    __syncthreads();
  }
  // selected: u > prefix, plus first `target` ties (ascending s) at u == prefix
  if (tid == 0) tie_base = 0;
  __syncthreads();
  int wid = tid >> 6, lane = tid & 63;
  for (int s0 = 0; s0 < n; s0 += 256) {
    int s = s0 + tid;
    bool in = (s < n);
    unsigned int uv = in ? u[s] : 0u;
    bool gt = in && (uv > prefix);
    bool tie = in && (uv == prefix);
    u64 bal = __ballot(tie);
    if (lane == 0) wcnt[wid] = __popcll(bal);
    __syncthreads();
    int wbase = tie_base;
    for (int wI = 0; wI < wid; wI++) wbase += wcnt[wI];
    int rank = wbase + __popcll(bal & ((1ULL << lane) - 1ULL));
    bool sel = gt || (tie && rank < target);
    if (sel) atomicOr(&mw[s >> 6], 1ULL << (s & 63));
    __syncthreads();
    if (tid == 0) tie_base += wcnt[0] + wcnt[1] + wcnt[2] + wcnt[3];
    __syncthreads();
  }
  if (tid < 32) maskw[(size_t)t * 32 + tid] = mw[tid];
}

// ---------------- masked flash attention: 16 queries x 1 head per block ----------------
__global__ __launch_bounds__(256) void k_attn(const float* __restrict__ qraw,   // [S][3072], head h at h*192, roped
                                              const float* __restrict__ kvb,   // [S][4096], k_nope at h*256, v at +128
                                              const float* __restrict__ kvraw, // [S][576], k_pe at 512, roped
                                              const u64* __restrict__ maskw,
                                              float* __restrict__ attn_out) {  // [S][2048]
  int tb = blockIdx.x;   // 128 blocks of 16 queries
  int h = blockIdx.y;
  int t0 = tb * 16;
  int tid = threadIdx.x;
  __shared__ float Q[16][192];
  __shared__ float Kt[32][194];
  __shared__ float Vt[32][132];
  __shared__ float P[16][33];
  __shared__ float rowM[16], rowL[16], rowScale[16];

  for (int i = tid; i < 16 * 192; i += 256) {
    int r = i / 192, c = i - r * 192;
    Q[r][c] = qraw[(size_t)(t0 + r) * 3072 + h * 192 + c];
  }
  if (tid < 16) { rowM[tid] = -INFINITY; rowL[tid] = 0.f; }

  float acc[8];
#pragma unroll
  for (int j = 0; j < 8; j++) acc[j] = 0.f;
  const int pv_t = tid >> 4;           // 0..15
  const int pv_c = (tid & 15) * 8;     // 0..120

  int nsb = (t0 + 16 + 31) / 32;
  for (int sb = 0; sb < nsb; sb++) {
    int s0 = sb * 32;
    __syncthreads();
    for (int i = tid; i < 32 * 128; i += 256) {
      int r = i >> 7, c = i & 127;
      const float* kr = kvb + (size_t)(s0 + r) * 4096 + h * 256;
      Kt[r][c] = kr[c];
      Vt[r][c] = kr[128 + c];
    }
    for (int i = tid; i < 32 * 64; i += 256) {
      int r = i >> 6, c = i & 63;
      Kt[r][128 + c] = kvraw[(size_t)(s0 + r) * 576 + 512 + c];
    }
    __syncthreads();
    { // scores 16x32, 2 rows per thread
      int si = tid & 31;
      int tq = (tid >> 5) * 2;
      float sc0 = 0.f, sc1 = 0.f;
      for (int d = 0; d < 192; d++) {
        float kv = Kt[si][d];
        sc0 = fmaf(Q[tq][d], kv, sc0);
        sc1 = fmaf(Q[tq + 1][d], kv, sc1);
      }
      int s = s0 + si;
      u64 w0 = maskw[(size_t)(t0 + tq) * 32 + (s >> 6)];
      u64 w1 = maskw[(size_t)(t0 + tq + 1) * 32 + (s >> 6)];
      P[tq][si]     = ((w0 >> (s & 63)) & 1ULL) ? sc0 * SCALE_ATTN : -INFINITY;
      P[tq + 1][si] = ((w1 >> (s & 63)) & 1ULL) ? sc1 * SCALE_ATTN : -INFINITY;
    }
    __syncthreads();
    if (tid < 16) {  // online softmax per row
      int ti = tid;
      float m = rowM[ti];
      float mx = m;
      for (int s = 0; s < 32; s++) mx = fmaxf(mx, P[ti][s]);
      float scl;
      if (mx == -INFINITY) {
        scl = 1.f;
        for (int s = 0; s < 32; s++) P[ti][s] = 0.f;
      } else {
        scl = expf(m - mx);
        float l = rowL[ti] * scl;
        for (int s = 0; s < 32; s++) {
          float p = expf(P[ti][s] - mx);
          P[ti][s] = p;
          l += p;
        }
        rowL[ti] = l;
        rowM[ti] = mx;
      }
      rowScale[ti] = scl;
    }
    __syncthreads();
    { // PV accumulate
      float rs = rowScale[pv_t];
#pragma unroll
      for (int j = 0; j < 8; j++) acc[j] *= rs;
      for (int s = 0; s < 32; s++) {
        float p = P[pv_t][s];
#pragma unroll
        for (int j = 0; j < 8; j++) acc[j] = fmaf(p, Vt[s][pv_c + j], acc[j]);
      }
    }
  }
  __syncthreads();
  float l = rowL[pv_t];
  float inv = (l > 0.f) ? 1.f / l : 0.f;
#pragma unroll
  for (int j = 0; j < 8; j++)
    attn_out[(size_t)(t0 + pv_t) * 2048 + h * 128 + pv_c + j] = acc[j] * inv;
}

// ---------------- host launch ----------------
extern "C" void kernel_launch(void* const* d_in, const int* in_sizes, int n_in,
                              void* d_out, int out_size, void* d_ws, size_t ws_size,
                              hipStream_t stream) {
  const float* hs       = (const float*)d_in[0];
  const float* cosb     = (const float*)d_in[1];
  const float* sinb     = (const float*)d_in[2];
  const float* Wq_a     = (const float*)d_in[3];
  const float* q_a_g    = (const float*)d_in[4];
  const float* Wq_b     = (const float*)d_in[5];
  const float* Wkv_a    = (const float*)d_in[6];
  const float* kv_a_g   = (const float*)d_in[7];
  const float* Wkv_b    = (const float*)d_in[8];
  const float* Wo       = (const float*)d_in[9];
  const float* Wq_idx   = (const float*)d_in[10];
  const float* Wk_idx   = (const float*)d_in[11];
  const float* Ww_idx   = (const float*)d_in[12];
  const float* kn_g     = (const float*)d_in[13];
  const float* kn_b     = (const float*)d_in[14];
  float* out = (float*)d_out;

  // workspace layout (f32 unless noted)
  char* base = (char*)d_ws;
  size_t off = 0;
  auto alloc = [&](size_t bytes) { void* p = base + off; off += (bytes + 255) & ~size_t(255); return p; };
  float* qa    = (float*)alloc((size_t)S_ * QL_ * 4);      // 12 MB
  float* qraw  = (float*)alloc((size_t)S_ * 3072 * 4);     // 24 MB
  float* kvraw = (float*)alloc((size_t)S_ * 576 * 4);      // 4.5 MB
  float* kvb   = (float*)alloc((size_t)S_ * 4096 * 4);     // 32 MB
  float* qi    = (float*)alloc((size_t)S_ * 2048 * 4);     // 16 MB
  float* ki    = (float*)alloc((size_t)S_ * 128 * 4);      // 1 MB
  float* wb    = (float*)alloc((size_t)S_ * 16 * 4);       // 128 KB
  float* idxs  = (float*)alloc((size_t)S_ * 2048 * 4);     // 16 MB
  u64*   maskw = (u64*)alloc((size_t)S_ * 32 * 8);         // 512 KB
  float* attn_out = idxs;  // reuse: idx_scores dead after top-k

  dim3 blk(256);

  // q_a = rmsnorm(hs @ Wq_a)
  k_gemm<<<dim3(QL_ / 64, S_ / 64), blk, 0, stream>>>(hs, H_, Wq_a, QL_, qa, QL_, S_, QL_, H_);
  k_rmsnorm<<<dim3(S_), blk, 0, stream>>>(qa, q_a_g, QL_, QL_);
  // q = q_a @ Wq_b; rope q_pe in place
  k_gemm<<<dim3(3072 / 64, S_ / 64), blk, 0, stream>>>(qa, QL_, Wq_b, 3072, qraw, 3072, S_, 3072, QL_);
  k_rope<<<dim3((S_ * 16 * 32) / 256), blk, 0, stream>>>(qraw, 3072, 16, 192, 128, cosb, sinb, S_ * 16 * 32);
  // kv = hs @ Wkv_a; rmsnorm kv_c in place; rope k_pe in place
  k_gemm<<<dim3(576 / 64, S_ / 64), blk, 0, stream>>>(hs, H_, Wkv_a, 576, kvraw, 576, S_, 576, H_);
  k_rmsnorm<<<dim3(S_), blk, 0, stream>>>(kvraw, kv_a_g, 576, KVL_);
  k_rope<<<dim3((S_ * 1 * 32) / 256), blk, 0, stream>>>(kvraw, 576, 1, 0, 512, cosb, sinb, S_ * 32);
  // kvb = kv_c @ Wkv_b   (A strided: lda=576, K=512)
  k_gemm<<<dim3(4096 / 64, S_ / 64), blk, 0, stream>>>(kvraw, 576, Wkv_b, 4096, kvb, 4096, S_, 4096, KVL_);
  // qi = q_a @ Wq_idx; rope first 64 of each 128-head in place
  k_gemm<<<dim3(2048 / 64, S_ / 64), blk, 0, stream>>>(qa, QL_, Wq_idx, 2048, qi, 2048, S_, 2048, QL_);
  k_rope<<<dim3((S_ * 16 * 32) / 256), blk, 0, stream>>>(qi, 2048, 16, 128, 0, cosb, sinb, S_ * 16 * 32);
  // ki = layernorm(hs @ Wk_idx); rope first 64 in place
  k_gemm<<<dim3(128 / 64, S_ / 64), blk, 0, stream>>>(hs, H_, Wk_idx, 128, ki, 128, S_, 128, H_);
  k_ki_ln_rope<<<dim3(S_), dim3(128), 0, stream>>>(ki, kn_g, kn_b, cosb, sinb);
  // w = hs @ Ww_idx
  k_gemm<<<dim3(1, S_ / 64), blk, 0, stream>>>(hs, H_, Ww_idx, 16, wb, 16, S_, 16, H_);
  // indexer scores (causal tiles only)
  k_idx_scores<<<dim3(64, 64), blk, 0, stream>>>(qi, ki, wb, idxs);
  // top-512 per row -> bitmask
  k_topk_mask<<<dim3(S_), blk, 0, stream>>>(idxs, maskw);
  // masked flash attention (attn_out aliases idxs; topk already consumed idxs)
  k_attn<<<dim3(128, 16), blk, 0, stream>>>(qraw, kvb, kvraw, maskw, attn_out);
  // final projection
  k_gemm<<<dim3(2048 / 64, S_ / 64), blk, 0, stream>>>(attn_out, 2048, Wo, 2048, out, 2048, S_, 2048, H_);

  (void)in_sizes; (void)n_in; (void)out_size; (void)ws_size;
}

// Round 2
// 1507.184 us; speedup vs baseline: 3.0891x; 3.0891x over previous
//
#include <hip/hip_runtime.h>
#include <cstdint>
#include <cstddef>

typedef unsigned long long u64;
typedef __attribute__((ext_vector_type(8))) short bf16x8;   // 8 bf16 in 4 VGPRs (guide §3)
typedef __attribute__((ext_vector_type(4))) float f32x4;

static constexpr int S_    = 2048;
static constexpr int H_    = 2048;
static constexpr int QL_   = 1536;
static constexpr int KVL_  = 512;
static constexpr int TOPKC = 512;

#define SCALE_ATTN 0.07216878364870323f   // (192)^-0.5
#define ISCALE_ID  0.08838834764831845f   // (128)^-0.5
#define EPS_F 1e-6f

__device__ inline unsigned short f2b(float f) {
  unsigned u = __float_as_uint(f);
  return (unsigned short)((u + 0x7FFFu + ((u >> 16) & 1u)) >> 16);
}
__device__ inline float b2f(unsigned short b) {
  return __uint_as_float(((unsigned)b) << 16);
}

// ================= bf16 MFMA GEMM: C[M,N] = A[M,K] @ Bt[N,K]^T =================
// 128x128 tile, BK=64, 256 threads / 4 waves (2x2 of 64x64). M multiple of 128.
__global__ __launch_bounds__(256) void k_gemm_bf16(
    const unsigned short* __restrict__ A, int lda,
    const unsigned short* __restrict__ Bt, int K,      // Bt pitch = K
    void* __restrict__ C, int ldc, int N, int out_bf16) {
  __shared__ unsigned short As[128 * 64];
  __shared__ unsigned short Bs[128 * 64];
  const int bm = blockIdx.y * 128, bn = blockIdx.x * 128;
  const int tid = threadIdx.x;
  const int lane = tid & 63, w = tid >> 6;
  const int wm = w >> 1, wn = w & 1;
  const int l15 = lane & 15, quarter = lane >> 4;

  f32x4 acc[4][4];
#pragma unroll
  for (int i = 0; i < 4; i++)
#pragma unroll
    for (int j = 0; j < 4; j++) acc[i][j] = (f32x4){0.f, 0.f, 0.f, 0.f};

  for (int k0 = 0; k0 < K; k0 += 64) {
    __syncthreads();
#pragma unroll
    for (int i = 0; i < 4; i++) {
      int c = tid + 256 * i;
      int row = c >> 3, cc = c & 7;
      int byte = row * 128 + ((cc * 16) ^ ((row & 7) << 4));
      bf16x8 va = *(const bf16x8*)(A + (size_t)(bm + row) * lda + k0 + cc * 8);
      *(bf16x8*)((char*)As + byte) = va;
      bf16x8 vb = (bf16x8)(short)0;
      if (bn + row < N) vb = *(const bf16x8*)(Bt + (size_t)(bn + row) * K + k0 + cc * 8);
      *(bf16x8*)((char*)Bs + byte) = vb;
    }
    __syncthreads();
#pragma unroll
    for (int kc = 0; kc < 2; kc++) {
      bf16x8 af[4], bfr[4];
#pragma unroll
      for (int mf = 0; mf < 4; mf++) {
        int row = wm * 64 + mf * 16 + l15;
        int byte = row * 128 + (((kc * 64 + quarter * 16)) ^ ((row & 7) << 4));
        af[mf] = *(const bf16x8*)((const char*)As + byte);
      }
#pragma unroll
      for (int nf = 0; nf < 4; nf++) {
        int row = wn * 64 + nf * 16 + l15;
        int byte = row * 128 + (((kc * 64 + quarter * 16)) ^ ((row & 7) << 4));
        bfr[nf] = *(const bf16x8*)((const char*)Bs + byte);
      }
#pragma unroll
      for (int mf = 0; mf < 4; mf++)
#pragma unroll
        for (int nf = 0; nf < 4; nf++)
          acc[mf][nf] = __builtin_amdgcn_mfma_f32_16x16x32_bf16(af[mf], bfr[nf], acc[mf][nf], 0, 0, 0);
    }
  }
#pragma unroll
  for (int mf = 0; mf < 4; mf++)
#pragma unroll
    for (int nf = 0; nf < 4; nf++)
#pragma unroll
      for (int r = 0; r < 4; r++) {
        int grow = bm + wm * 64 + mf * 16 + quarter * 4 + r;
        int gcol = bn + wn * 64 + nf * 16 + l15;
        if (gcol < N) {
          if (out_bf16) ((unsigned short*)C)[(size_t)grow * ldc + gcol] = f2b(acc[mf][nf][r]);
          else          ((float*)C)[(size_t)grow * ldc + gcol] = acc[mf][nf][r];
        }
      }
}

// ================= transpose + cast: Wt[n][k] = bf16(W[k][n]), dims mult of 32 =================
__global__ __launch_bounds__(256) void k_tcast(const float* __restrict__ W, int K, int N,
                                               unsigned short* __restrict__ Wt) {
  __shared__ float T[32][33];
  int n0 = blockIdx.x * 32, k0 = blockIdx.y * 32;
  int tid = threadIdx.x;
#pragma unroll
  for (int i = 0; i < 4; i++) {
    int idx = tid + 256 * i;
    int r = idx >> 5, c = idx & 31;
    T[r][c] = W[(size_t)(k0 + r) * N + n0 + c];
  }
  __syncthreads();
#pragma unroll
  for (int i = 0; i < 4; i++) {
    int idx = tid + 256 * i;
    int r = idx >> 5, c = idx & 31;
    Wt[(size_t)(n0 + r) * K + k0 + c] = f2b(T[c][r]);
  }
}

// ================= strided f32 -> bf16 cast =================
__global__ __launch_bounds__(256) void k_cast_bf16(const float* __restrict__ in, int pin,
                                                   unsigned short* __restrict__ outp, int pout,
                                                   int rows, int cols) {
  int cols4 = cols >> 2;
  int idx = blockIdx.x * 256 + threadIdx.x;
  if (idx >= rows * cols4) return;
  int r = idx / cols4, c = (idx - r * cols4) * 4;
  const float* ip = in + (size_t)r * pin + c;
  unsigned short* op = outp + (size_t)r * pout + c;
  op[0] = f2b(ip[0]); op[1] = f2b(ip[1]); op[2] = f2b(ip[2]); op[3] = f2b(ip[3]);
}

// ================= generic f32 GEMM (small N only: wb) =================
__global__ __launch_bounds__(256) void k_gemm(const float* __restrict__ A, int lda,
                                              const float* __restrict__ B, int ldb,
                                              float* __restrict__ C, int ldc,
                                              int M, int N, int K) {
  __shared__ float As[64][17];
  __shared__ float Bs[16][64];
  const int bm = blockIdx.y * 64, bn = blockIdx.x * 64;
  const int tid = threadIdx.x;
  const int tm = (tid & 15) * 4, tn = (tid >> 4) * 4;
  float acc[4][4] = {};
  for (int k0 = 0; k0 < K; k0 += 16) {
#pragma unroll
    for (int i = 0; i < 4; i++) {
      int m = (tid >> 4) + i * 16, kk = tid & 15;
      float v = 0.f;
      if (bm + m < M && k0 + kk < K) v = A[(size_t)(bm + m) * lda + k0 + kk];
      As[m][kk] = v;
    }
#pragma unroll
    for (int i = 0; i < 4; i++) {
      int n = tid & 63, kk = (tid >> 6) + i * 4;
      float v = 0.f;
      if (k0 + kk < K && bn + n < N) v = B[(size_t)(k0 + kk) * ldb + bn + n];
      Bs[kk][n] = v;
    }
    __syncthreads();
#pragma unroll
    for (int kk = 0; kk < 16; kk++) {
      float a[4], b[4];
#pragma unroll
      for (int i = 0; i < 4; i++) a[i] = As[tm + i][kk];
#pragma unroll
      for (int j = 0; j < 4; j++) b[j] = Bs[kk][tn + j];
#pragma unroll
      for (int i = 0; i < 4; i++)
#pragma unroll
        for (int j = 0; j < 4; j++) acc[i][j] = fmaf(a[i], b[j], acc[i][j]);
    }
    __syncthreads();
  }
#pragma unroll
  for (int i = 0; i < 4; i++) {
    int m = bm + tm + i;
    if (m >= M) continue;
#pragma unroll
    for (int j = 0; j < 4; j++) {
      int n = bn + tn + j;
      if (n < N) C[(size_t)m * ldc + n] = acc[i][j];
    }
  }
}

// ================= RMSNorm in-place =================
__global__ __launch_bounds__(256) void k_rmsnorm(float* __restrict__ x, const float* __restrict__ gamma,
                                                 int rowstride, int n) {
  int r = blockIdx.x;
  float* p = x + (size_t)r * rowstride;
  __shared__ float red[256];
  float s = 0.f;
  for (int i = threadIdx.x; i < n; i += 256) { float v = p[i]; s += v * v; }
  red[threadIdx.x] = s; __syncthreads();
  for (int st = 128; st > 0; st >>= 1) { if (threadIdx.x < st) red[threadIdx.x] += red[threadIdx.x + st]; __syncthreads(); }
  float scl = rsqrtf(red[0] / (float)n + EPS_F);
  for (int i = threadIdx.x; i < n; i += 256) p[i] = p[i] * scl * gamma[i];
}

// ================= RoPE in-place (f32) =================
__global__ __launch_bounds__(256) void k_rope(float* __restrict__ base, int rowstride, int nh, int hstride,
                                              int off, const float* __restrict__ cosb, const float* __restrict__ sinb,
                                              int total) {
  int idx = blockIdx.x * 256 + threadIdx.x;
  if (idx >= total) return;
  int i = idx & 31, h = (idx >> 5) % nh, t = idx / (32 * nh);
  float* p = base + (size_t)t * rowstride + h * hstride + off;
  float x1 = p[i], x2 = p[i + 32];
  float c = cosb[t * 32 + i], s = sinb[t * 32 + i];
  p[i] = x1 * c - x2 * s;
  p[i + 32] = x1 * s + x2 * c;
}

// ================= RoPE in-place (bf16) =================
__global__ __launch_bounds__(256) void k_rope_b(unsigned short* __restrict__ base, int rowstride, int nh,
                                                int hstride, int off, const float* __restrict__ cosb,
                                                const float* __restrict__ sinb, int total) {
  int idx = blockIdx.x * 256 + threadIdx.x;
  if (idx >= total) return;
  int i = idx & 31, h = (idx >> 5) % nh, t = idx / (32 * nh);
  unsigned short* p = base + (size_t)t * rowstride + h * hstride + off;
  float x1 = b2f(p[i]), x2 = b2f(p[i + 32]);
  float c = cosb[t * 32 + i], s = sinb[t * 32 + i];
  p[i] = f2b(x1 * c - x2 * s);
  p[i + 32] = f2b(x1 * s + x2 * c);
}

// ================= ki: LayerNorm(128) + RoPE on first 64, in-place =================
__global__ __launch_bounds__(128) void k_ki_ln_rope(float* __restrict__ ki, const float* __restrict__ g,
                                                    const float* __restrict__ b,
                                                    const float* __restrict__ cosb, const float* __restrict__ sinb) {
  int t = blockIdx.x, i = threadIdx.x;
  float* p = ki + (size_t)t * 128;
  __shared__ float red[128];
  __shared__ float buf[128];
  float v = p[i];
  red[i] = v; __syncthreads();
  for (int st = 64; st > 0; st >>= 1) { if (i < st) red[i] += red[i + st]; __syncthreads(); }
  float mean = red[0] * (1.f / 128.f);
  __syncthreads();
  float d = v - mean;
  red[i] = d * d; __syncthreads();
  for (int st = 64; st > 0; st >>= 1) { if (i < st) red[i] += red[i + st]; __syncthreads(); }
  float var = red[0] * (1.f / 128.f);
  float y = d * rsqrtf(var + EPS_F) * g[i] + b[i];
  buf[i] = y; __syncthreads();
  float outv;
  if (i < 32) {
    float c = cosb[t * 32 + i], s = sinb[t * 32 + i];
    outv = buf[i] * c - buf[i + 32] * s;
  } else if (i < 64) {
    int j = i - 32;
    float c = cosb[t * 32 + j], s = sinb[t * 32 + j];
    outv = buf[j] * s + buf[i] * c;
  } else outv = y;
  p[i] = outv;
}

// ================= indexer scores (f32, causal tiles) =================
__global__ __launch_bounds__(256) void k_idx_scores(const float* __restrict__ qi, const float* __restrict__ ki,
                                                    const float* __restrict__ wb, float* __restrict__ out) {
  int tb = blockIdx.x, sb = blockIdx.y;
  if (sb > tb) return;
  int t0 = tb * 32, s0 = sb * 32;
  __shared__ float Ks[32][130];
  __shared__ float Qs[32][130];
  __shared__ float Ws[32][16];
  int tid = threadIdx.x;
  for (int i = tid; i < 32 * 128; i += 256) {
    int r = i >> 7, c = i & 127;
    Ks[r][c] = ki[(size_t)(s0 + r) * 128 + c];
  }
  for (int i = tid; i < 32 * 16; i += 256) {
    int r = i >> 4, c = i & 15;
    Ws[r][c] = wb[(size_t)(t0 + r) * 16 + c];
  }
  int ttb = (tid & 15) * 2, ssb = (tid >> 4) * 2;
  float acc00 = 0.f, acc01 = 0.f, acc10 = 0.f, acc11 = 0.f;
  for (int h = 0; h < 16; h++) {
    __syncthreads();
    for (int i = tid; i < 32 * 128; i += 256) {
      int r = i >> 7, c = i & 127;
      Qs[r][c] = qi[(size_t)(t0 + r) * 2048 + h * 128 + c];
    }
    __syncthreads();
    float d00 = 0.f, d01 = 0.f, d10 = 0.f, d11 = 0.f;
    for (int d = 0; d < 128; d++) {
      float q0 = Qs[ttb][d], q1 = Qs[ttb + 1][d];
      float k0 = Ks[ssb][d], k1 = Ks[ssb + 1][d];
      d00 = fmaf(q0, k0, d00); d01 = fmaf(q0, k1, d01);
      d10 = fmaf(q1, k0, d10); d11 = fmaf(q1, k1, d11);
    }
    float w0 = Ws[ttb][h], w1 = Ws[ttb + 1][h];
    acc00 += w0 * fmaxf(d00, 0.f);
    acc01 += w0 * fmaxf(d01, 0.f);
    acc10 += w1 * fmaxf(d10, 0.f);
    acc11 += w1 * fmaxf(d11, 0.f);
  }
  out[(size_t)(t0 + ttb)     * 2048 + s0 + ssb]     = acc00 * ISCALE_ID;
  out[(size_t)(t0 + ttb)     * 2048 + s0 + ssb + 1] = acc01 * ISCALE_ID;
  out[(size_t)(t0 + ttb + 1) * 2048 + s0 + ssb]     = acc10 * ISCALE_ID;
  out[(size_t)(t0 + ttb + 1) * 2048 + s0 + ssb + 1] = acc11 * ISCALE_ID;
}

// ================= per-row top-K -> bitmask =================
__global__ __launch_bounds__(256) void k_topk_mask(const float* __restrict__ idx_sc, u64* __restrict__ maskw) {
  int t = blockIdx.x;
  int tid = threadIdx.x;
  int n = t + 1;
  if (n <= TOPKC) {
    if (tid < 32) {
      int lo = tid * 64, hi = lo + 63;
      u64 wv;
      if (t >= hi) wv = ~0ULL;
      else if (t < lo) wv = 0ULL;
      else wv = (~0ULL) >> (63 - (t - lo));
      maskw[(size_t)t * 32 + tid] = wv;
    }
    return;
  }
  __shared__ unsigned int u[2048];
  __shared__ int hist[256];
  __shared__ u64 mw[32];
  __shared__ int sel_b, new_target, tie_base;
  __shared__ int wcnt[4];
  if (tid < 32) mw[tid] = 0ULL;
  const float* row = idx_sc + (size_t)t * 2048;
  for (int s = tid; s < n; s += 256) {
    unsigned int bb = __float_as_uint(row[s]);
    u[s] = (bb & 0x80000000u) ? ~bb : (bb | 0x80000000u);
  }
  __syncthreads();
  unsigned int prefix = 0;
  int target = TOPKC;
  for (int shift = 24; shift >= 0; shift -= 8) {
    hist[tid] = 0;
    __syncthreads();
    unsigned int himask = (shift == 24) ? 0u : (0xFFFFFFFFu << (shift + 8));
    for (int s = tid; s < n; s += 256) {
      unsigned int uv = u[s];
      if ((uv & himask) == prefix) atomicAdd(&hist[(uv >> shift) & 0xFF], 1);
    }
    __syncthreads();
    if (tid == 0) {
      int cum = 0, b = 255;
      for (; b > 0; b--) {
        if (cum + hist[b] >= target) break;
        cum += hist[b];
      }
      sel_b = b;
      new_target = target - cum;
    }
    __syncthreads();
    prefix |= ((unsigned int)sel_b) << shift;
    target = new_target;
    __syncthreads();
  }
  if (tid == 0) tie_base = 0;
  __syncthreads();
  int wid = tid >> 6, lane = tid & 63;
  for (int s0 = 0; s0 < n; s0 += 256) {
    int s = s0 + tid;
    bool in = (s < n);
    unsigned int uv = in ? u[s] : 0u;
    bool gt = in && (uv > prefix);
    bool tie = in && (uv == prefix);
    u64 bal = __ballot(tie);
    if (lane == 0) wcnt[wid] = __popcll(bal);
    __syncthreads();
    int wbase = tie_base;
    for (int wI = 0; wI < wid; wI++) wbase += wcnt[wI];
    int rank = wbase + __popcll(bal & ((1ULL << lane) - 1ULL));
    bool sel = gt || (tie && rank < target);
    if (sel) atomicOr(&mw[s >> 6], 1ULL << (s & 63));
    __syncthreads();
    if (tid == 0) tie_base += wcnt[0] + wcnt[1] + wcnt[2] + wcnt[3];
    __syncthreads();
  }
  if (tid < 32) maskw[(size_t)t * 32 + tid] = mw[tid];
}

// ================= MFMA flash attention: 64 queries x 1 head per block =================
__global__ __launch_bounds__(256) void k_attn_mfma(
    const unsigned short* __restrict__ qb,     // [S][3072] bf16, roped
    const unsigned short* __restrict__ kvb_b,  // [S][4096] bf16: per head k_nope@h*256, v@h*256+128
    const unsigned short* __restrict__ kpe_b,  // [S][64]   bf16, roped
    const u64* __restrict__ maskw,             // [S][32]
    unsigned short* __restrict__ attn_b) {     // [S][2048] bf16
  int ybm = blockIdx.x;
  int h = blockIdx.y;
  int yb = (ybm < 16) ? ybm : (47 - ybm);      // pair heavy+light blocks per CU
  int t0 = yb * 64;
  int tid = threadIdx.x;
  int lane = tid & 63, wq = tid >> 6;
  int quarter = lane >> 4, l15 = lane & 15;

  __shared__ unsigned short Ks[32 * 192];   // pitch 384B, swz ((r&7)<<4)
  __shared__ unsigned short Vts[128 * 32];  // V^T, pitch 64B, swz ((d&3)<<4)
  __shared__ unsigned short Ps[64 * 32];    // P,   pitch 64B, swz ((t&3)<<4)
  __shared__ u64 Mw[64];

  bf16x8 qf[6];
  {
    const unsigned short* qp = qb + (size_t)(t0 + wq * 16 + l15) * 3072 + h * 192 + quarter * 8;
#pragma unroll
    for (int kc = 0; kc < 6; kc++) qf[kc] = *(const bf16x8*)(qp + kc * 32);
  }
  f32x4 o[8];
#pragma unroll
  for (int df = 0; df < 8; df++) o[df] = (f32x4){0.f, 0.f, 0.f, 0.f};
  float m[4], l[4];
#pragma unroll
  for (int r = 0; r < 4; r++) { m[r] = -__builtin_inff(); l[r] = 0.f; }

  int nsb = t0 / 32 + 2;
  for (int sb = 0; sb < nsb; sb++) {
    int s0 = sb * 32;
    __syncthreads();
    if (tid < 64) Mw[tid] = maskw[(size_t)(t0 + tid) * 32 + (s0 >> 6)];
#pragma unroll
    for (int i = 0; i < 3; i++) {
      int c = tid + 256 * i;
      int row = c / 24, cc = c - row * 24;
      bf16x8 v;
      if (cc < 16) v = *(const bf16x8*)(kvb_b + (size_t)(s0 + row) * 4096 + h * 256 + cc * 8);
      else         v = *(const bf16x8*)(kpe_b + (size_t)(s0 + row) * 64 + (cc - 16) * 8);
      int byte = row * 384 + ((cc * 16) ^ ((row & 7) << 4));
      *(bf16x8*)((char*)Ks + byte) = v;
    }
    {
      int dg = tid & 15, sp = tid >> 4;
      int s = sp * 2, d0 = dg * 8;
      const unsigned short* vp0 = kvb_b + (size_t)(s0 + s) * 4096 + h * 256 + 128 + d0;
      bf16x8 v0 = *(const bf16x8*)vp0;
      bf16x8 v1 = *(const bf16x8*)(vp0 + 4096);
#pragma unroll
      for (int j = 0; j < 8; j++) {
        int d = d0 + j;
        unsigned pack = (unsigned)(unsigned short)v0[j] | (((unsigned)(unsigned short)v1[j]) << 16);
        int byte = d * 64 + ((s * 2) ^ ((d & 3) << 4));
        *(unsigned*)((char*)Vts + byte) = pack;
      }
    }
    __syncthreads();

    // QK^T: 16x32 scores per wave
    f32x4 sf[2];
#pragma unroll
    for (int sc = 0; sc < 2; sc++) {
      f32x4 a = (f32x4){0.f, 0.f, 0.f, 0.f};
      int row = sc * 16 + l15;
      int rx = (row & 7) << 4;
#pragma unroll
      for (int kc = 0; kc < 6; kc++) {
        int byte = row * 384 + ((kc * 64 + quarter * 16) ^ rx);
        bf16x8 kf = *(const bf16x8*)((const char*)Ks + byte);
        a = __builtin_amdgcn_mfma_f32_16x16x32_bf16(qf[kc], kf, a, 0, 0, 0);
      }
      sf[sc] = a;
    }
    // mask + online softmax
    float p[2][4];
#pragma unroll
    for (int r = 0; r < 4; r++) {
      int rq = wq * 16 + quarter * 4 + r;
      u64 w = Mw[rq];
#pragma unroll
      for (int sc = 0; sc < 2; sc++) {
        int s = s0 + sc * 16 + l15;
        bool sel = (w >> (s & 63)) & 1ULL;
        p[sc][r] = sel ? sf[sc][r] * SCALE_ATTN : -__builtin_inff();
      }
    }
#pragma unroll
    for (int r = 0; r < 4; r++) {
      float v = fmaxf(p[0][r], p[1][r]);
      v = fmaxf(v, __shfl_xor(v, 1));
      v = fmaxf(v, __shfl_xor(v, 2));
      v = fmaxf(v, __shfl_xor(v, 4));
      v = fmaxf(v, __shfl_xor(v, 8));
      float mn = fmaxf(m[r], v);
      float scl;
      if (mn == -__builtin_inff()) {
        scl = 1.f; p[0][r] = 0.f; p[1][r] = 0.f;
      } else {
        scl = __expf(m[r] - mn);            // m=-inf -> 0
        p[0][r] = __expf(p[0][r] - mn);     // p=-inf -> 0
        p[1][r] = __expf(p[1][r] - mn);
        m[r] = mn;
      }
      float rs = p[0][r] + p[1][r];
      rs += __shfl_xor(rs, 1);
      rs += __shfl_xor(rs, 2);
      rs += __shfl_xor(rs, 4);
      rs += __shfl_xor(rs, 8);
      l[r] = l[r] * scl + rs;
#pragma unroll
      for (int df = 0; df < 8; df++) o[df][r] *= scl;
      // P -> LDS (bf16)
      int rowp = wq * 16 + quarter * 4 + r;
      int rxp = (rowp & 3) << 4;
      *(unsigned short*)((char*)Ps + rowp * 64 + (((0 * 16 + l15) * 2) ^ rxp)) = f2b(p[0][r]);
      *(unsigned short*)((char*)Ps + rowp * 64 + (((1 * 16 + l15) * 2) ^ rxp)) = f2b(p[1][r]);
    }
    // PV (wave-local P; compiler inserts lgkmcnt waits)
    {
      int rowp = wq * 16 + l15;
      int byte = rowp * 64 + ((quarter * 16) ^ ((rowp & 3) << 4));
      bf16x8 pa = *(const bf16x8*)((const char*)Ps + byte);
#pragma unroll
      for (int df = 0; df < 8; df++) {
        int d = df * 16 + l15;
        int vbyte = d * 64 + ((quarter * 16) ^ ((d & 3) << 4));
        bf16x8 vf = *(const bf16x8*)((const char*)Vts + vbyte);
        o[df] = __builtin_amdgcn_mfma_f32_16x16x32_bf16(pa, vf, o[df], 0, 0, 0);
      }
    }
  }
#pragma unroll
  for (int r = 0; r < 4; r++) {
    float inv = (l[r] > 0.f) ? 1.f / l[r] : 0.f;
    int t = t0 + wq * 16 + quarter * 4 + r;
    unsigned short* op = attn_b + (size_t)t * 2048 + h * 128 + l15;
#pragma unroll
    for (int df = 0; df < 8; df++) op[df * 16] = f2b(o[df][r] * inv);
  }
}

// ================= host launch =================
extern "C" void kernel_launch(void* const* d_in, const int* in_sizes, int n_in,
                              void* d_out, int out_size, void* d_ws, size_t ws_size,
                              hipStream_t stream) {
  const float* hs     = (const float*)d_in[0];
  const float* cosb   = (const float*)d_in[1];
  const float* sinb   = (const float*)d_in[2];
  const float* Wq_a   = (const float*)d_in[3];
  const float* q_a_g  = (const float*)d_in[4];
  const float* Wq_b   = (const float*)d_in[5];
  const float* Wkv_a  = (const float*)d_in[6];
  const float* kv_a_g = (const float*)d_in[7];
  const float* Wkv_b  = (const float*)d_in[8];
  const float* Wo     = (const float*)d_in[9];
  const float* Wq_idx = (const float*)d_in[10];
  const float* Wk_idx = (const float*)d_in[11];
  const float* Ww_idx = (const float*)d_in[12];
  const float* kn_g   = (const float*)d_in[13];
  const float* kn_b   = (const float*)d_in[14];
  float* out = (float*)d_out;

  char* base = (char*)d_ws;
  size_t off = 0;
  auto alloc = [&](size_t bytes) { void* p = base + off; off += (bytes + 255) & ~size_t(255); return p; };

  float* regionA = (float*)alloc((size_t)S_ * 2048 * 4);   // qa (2048x1536 f32) then idxs (2048x2048 f32)
  float* qa   = regionA;
  float* idxs = regionA;
  float* qi   = (float*)alloc((size_t)S_ * 2048 * 4);      // then attn_b (bf16) aliases it
  unsigned short* attn_b = (unsigned short*)qi;
  float* kvraw = (float*)alloc((size_t)S_ * 576 * 4);
  float* ki    = (float*)alloc((size_t)S_ * 128 * 4);
  float* wb    = (float*)alloc((size_t)S_ * 16 * 4);
  u64*   maskw = (u64*)alloc((size_t)S_ * 32 * 8);
  unsigned short* hs_b  = (unsigned short*)alloc((size_t)S_ * 2048 * 2);
  unsigned short* qa_b  = (unsigned short*)alloc((size_t)S_ * 1536 * 2);
  unsigned short* qb    = (unsigned short*)alloc((size_t)S_ * 3072 * 2);
  unsigned short* kvc_b = (unsigned short*)alloc((size_t)S_ * 512 * 2);
  unsigned short* kpe_b = (unsigned short*)alloc((size_t)S_ * 64 * 2);
  unsigned short* kvb_b = (unsigned short*)alloc((size_t)S_ * 4096 * 2);
  unsigned short* WT    = (unsigned short*)alloc((size_t)3072 * 1536 * 2);  // JIT weight^T scratch

  dim3 blk(256);

  // hs -> bf16
  k_cast_bf16<<<dim3((S_ * 2048 / 4) / 256), blk, 0, stream>>>(hs, 2048, hs_b, 2048, S_, 2048);
  // q_a = rmsnorm(hs @ Wq_a)
  k_tcast<<<dim3(1536 / 32, 2048 / 32), blk, 0, stream>>>(Wq_a, 2048, 1536, WT);
  k_gemm_bf16<<<dim3(12, 16), blk, 0, stream>>>(hs_b, 2048, WT, 2048, qa, 1536, 1536, 0);
  k_rmsnorm<<<dim3(S_), blk, 0, stream>>>(qa, q_a_g, 1536, 1536);
  k_cast_bf16<<<dim3((S_ * 1536 / 4) / 256), blk, 0, stream>>>(qa, 1536, qa_b, 1536, S_, 1536);
  // q = q_a @ Wq_b (bf16 out), rope q_pe
  k_tcast<<<dim3(3072 / 32, 1536 / 32), blk, 0, stream>>>(Wq_b, 1536, 3072, WT);
  k_gemm_bf16<<<dim3(24, 16), blk, 0, stream>>>(qa_b, 1536, WT, 1536, qb, 3072, 3072, 1);
  k_rope_b<<<dim3((S_ * 16 * 32) / 256), blk, 0, stream>>>(qb, 3072, 16, 192, 128, cosb, sinb, S_ * 16 * 32);
  // kv = hs @ Wkv_a (f32), rmsnorm + rope, casts
  k_tcast<<<dim3(576 / 32, 2048 / 32), blk, 0, stream>>>(Wkv_a, 2048, 576, WT);
  k_gemm_bf16<<<dim3(5, 16), blk, 0, stream>>>(hs_b, 2048, WT, 2048, kvraw, 576, 576, 0);
  k_rmsnorm<<<dim3(S_), blk, 0, stream>>>(kvraw, kv_a_g, 576, KVL_);
  k_rope<<<dim3((S_ * 32) / 256), blk, 0, stream>>>(kvraw, 576, 1, 0, 512, cosb, sinb, S_ * 32);
  k_cast_bf16<<<dim3((S_ * 512 / 4) / 256), blk, 0, stream>>>(kvraw, 576, kvc_b, 512, S_, 512);
  k_cast_bf16<<<dim3((S_ * 64 / 4) / 256), blk, 0, stream>>>(kvraw + 512, 576, kpe_b, 64, S_, 64);
  // kvb = kv_c @ Wkv_b (bf16 out)
  k_tcast<<<dim3(4096 / 32, 512 / 32), blk, 0, stream>>>(Wkv_b, 512, 4096, WT);
  k_gemm_bf16<<<dim3(32, 16), blk, 0, stream>>>(kvc_b, 512, WT, 512, kvb_b, 4096, 4096, 1);
  // qi = q_a @ Wq_idx (f32), rope
  k_tcast<<<dim3(2048 / 32, 1536 / 32), blk, 0, stream>>>(Wq_idx, 1536, 2048, WT);
  k_gemm_bf16<<<dim3(16, 16), blk, 0, stream>>>(qa_b, 1536, WT, 1536, qi, 2048, 2048, 0);
  k_rope<<<dim3((S_ * 16 * 32) / 256), blk, 0, stream>>>(qi, 2048, 16, 128, 0, cosb, sinb, S_ * 16 * 32);
  // ki = layernorm(hs @ Wk_idx) + rope
  k_tcast<<<dim3(128 / 32, 2048 / 32), blk, 0, stream>>>(Wk_idx, 2048, 128, WT);
  k_gemm_bf16<<<dim3(1, 16), blk, 0, stream>>>(hs_b, 2048, WT, 2048, ki, 128, 128, 0);
  k_ki_ln_rope<<<dim3(S_), dim3(128), 0, stream>>>(ki, kn_g, kn_b, cosb, sinb);
  // w = hs @ Ww_idx (small f32 GEMM)
  k_gemm<<<dim3(1, S_ / 64), blk, 0, stream>>>(hs, H_, Ww_idx, 16, wb, 16, S_, 16, H_);
  // indexer scores + top-k mask
  k_idx_scores<<<dim3(64, 64), blk, 0, stream>>>(qi, ki, wb, idxs);
  k_topk_mask<<<dim3(S_), blk, 0, stream>>>(idxs, maskw);
  // MFMA flash attention -> attn_b (bf16)
  k_attn_mfma<<<dim3(32, 16), blk, 0, stream>>>(qb, kvb_b, kpe_b, maskw, attn_b);
  // out = attn @ Wo
  k_tcast<<<dim3(2048 / 32, 2048 / 32), blk, 0, stream>>>(Wo, 2048, 2048, WT);
  k_gemm_bf16<<<dim3(16, 16), blk, 0, stream>>>(attn_b, 2048, WT, 2048, out, 2048, 2048, 0);

  (void)in_sizes; (void)n_in; (void)out_size; (void)ws_size;
}

// Round 3
// 1054.252 us; speedup vs baseline: 4.4162x; 1.4296x over previous
//
#include <hip/hip_runtime.h>
#include <cstdint>
#include <cstddef>
#include <cmath>

typedef unsigned long long u64;
typedef __attribute__((ext_vector_type(8))) short bf16x8;   // 8 bf16 in 4 VGPRs (guide §3)
typedef __attribute__((ext_vector_type(4))) float f32x4;

static constexpr int S_    = 2048;
static constexpr int H_    = 2048;
static constexpr int QL_   = 1536;
static constexpr int KVL_  = 512;
static constexpr int TOPKC = 512;

#define SCALE_ATTN 0.07216878364870323f   // (192)^-0.5
#define ISCALE_ID  0.08838834764831845f   // (128)^-0.5
#define EPS_F 1e-6f

__device__ inline unsigned short f2b(float f) {
  unsigned u = __float_as_uint(f);
  return (unsigned short)((u + 0x7FFFu + ((u >> 16) & 1u)) >> 16);
}
__device__ inline float b2f(unsigned short b) {
  return __uint_as_float(((unsigned)b) << 16);
}

// ================= bf16 MFMA GEMM: C[M,N] = A[M,K] @ Bt[N,K]^T =================
// 128x128 tile, BK=64, 256 threads / 4 waves (2x2 of 64x64). M multiple of 128.
__global__ __launch_bounds__(256) void k_gemm_bf16(
    const unsigned short* __restrict__ A, int lda,
    const unsigned short* __restrict__ Bt, int K,      // Bt pitch = K
    void* __restrict__ C, int ldc, int N, int out_bf16) {
  __shared__ unsigned short As[128 * 64];
  __shared__ unsigned short Bs[128 * 64];
  const int bm = blockIdx.y * 128, bn = blockIdx.x * 128;
  const int tid = threadIdx.x;
  const int lane = tid & 63, w = tid >> 6;
  const int wm = w >> 1, wn = w & 1;
  const int l15 = lane & 15, quarter = lane >> 4;

  f32x4 acc[4][4];
#pragma unroll
  for (int i = 0; i < 4; i++)
#pragma unroll
    for (int j = 0; j < 4; j++) acc[i][j] = (f32x4){0.f, 0.f, 0.f, 0.f};

  for (int k0 = 0; k0 < K; k0 += 64) {
    __syncthreads();
#pragma unroll
    for (int i = 0; i < 4; i++) {
      int c = tid + 256 * i;
      int row = c >> 3, cc = c & 7;
      int byte = row * 128 + ((cc * 16) ^ ((row & 7) << 4));
      bf16x8 va = *(const bf16x8*)(A + (size_t)(bm + row) * lda + k0 + cc * 8);
      *(bf16x8*)((char*)As + byte) = va;
      bf16x8 vb = (bf16x8)(short)0;
      if (bn + row < N) vb = *(const bf16x8*)(Bt + (size_t)(bn + row) * K + k0 + cc * 8);
      *(bf16x8*)((char*)Bs + byte) = vb;
    }
    __syncthreads();
#pragma unroll
    for (int kc = 0; kc < 2; kc++) {
      bf16x8 af[4], bfr[4];
#pragma unroll
      for (int mf = 0; mf < 4; mf++) {
        int row = wm * 64 + mf * 16 + l15;
        int byte = row * 128 + (((kc * 64 + quarter * 16)) ^ ((row & 7) << 4));
        af[mf] = *(const bf16x8*)((const char*)As + byte);
      }
#pragma unroll
      for (int nf = 0; nf < 4; nf++) {
        int row = wn * 64 + nf * 16 + l15;
        int byte = row * 128 + (((kc * 64 + quarter * 16)) ^ ((row & 7) << 4));
        bfr[nf] = *(const bf16x8*)((const char*)Bs + byte);
      }
#pragma unroll
      for (int mf = 0; mf < 4; mf++)
#pragma unroll
        for (int nf = 0; nf < 4; nf++)
          acc[mf][nf] = __builtin_amdgcn_mfma_f32_16x16x32_bf16(af[mf], bfr[nf], acc[mf][nf], 0, 0, 0);
    }
  }
#pragma unroll
  for (int mf = 0; mf < 4; mf++)
#pragma unroll
    for (int nf = 0; nf < 4; nf++)
#pragma unroll
      for (int r = 0; r < 4; r++) {
        int grow = bm + wm * 64 + mf * 16 + quarter * 4 + r;
        int gcol = bn + wn * 64 + nf * 16 + l15;
        if (gcol < N) {
          if (out_bf16) ((unsigned short*)C)[(size_t)grow * ldc + gcol] = f2b(acc[mf][nf][r]);
          else          ((float*)C)[(size_t)grow * ldc + gcol] = acc[mf][nf][r];
        }
      }
}

// ================= transpose + cast: Wt[n][k] = bf16(W[k][n]), dims mult of 32 =================
__global__ __launch_bounds__(256) void k_tcast(const float* __restrict__ W, int K, int N,
                                               unsigned short* __restrict__ Wt) {
  __shared__ float T[32][33];
  int n0 = blockIdx.x * 32, k0 = blockIdx.y * 32;
  int tid = threadIdx.x;
#pragma unroll
  for (int i = 0; i < 4; i++) {
    int idx = tid + 256 * i;
    int r = idx >> 5, c = idx & 31;
    T[r][c] = W[(size_t)(k0 + r) * N + n0 + c];
  }
  __syncthreads();
#pragma unroll
  for (int i = 0; i < 4; i++) {
    int idx = tid + 256 * i;
    int r = idx >> 5, c = idx & 31;
    Wt[(size_t)(n0 + r) * K + k0 + c] = f2b(T[c][r]);
  }
}

// ================= strided f32 -> bf16 cast =================
__global__ __launch_bounds__(256) void k_cast_bf16(const float* __restrict__ in, int pin,
                                                   unsigned short* __restrict__ outp, int pout,
                                                   int rows, int cols) {
  int cols4 = cols >> 2;
  int idx = blockIdx.x * 256 + threadIdx.x;
  if (idx >= rows * cols4) return;
  int r = idx / cols4, c = (idx - r * cols4) * 4;
  const float* ip = in + (size_t)r * pin + c;
  unsigned short* op = outp + (size_t)r * pout + c;
  op[0] = f2b(ip[0]); op[1] = f2b(ip[1]); op[2] = f2b(ip[2]); op[3] = f2b(ip[3]);
}

// ================= generic f32 GEMM (small N only: wb) =================
__global__ __launch_bounds__(256) void k_gemm(const float* __restrict__ A, int lda,
                                              const float* __restrict__ B, int ldb,
                                              float* __restrict__ C, int ldc,
                                              int M, int N, int K) {
  __shared__ float As[64][17];
  __shared__ float Bs[16][64];
  const int bm = blockIdx.y * 64, bn = blockIdx.x * 64;
  const int tid = threadIdx.x;
  const int tm = (tid & 15) * 4, tn = (tid >> 4) * 4;
  float acc[4][4] = {};
  for (int k0 = 0; k0 < K; k0 += 16) {
#pragma unroll
    for (int i = 0; i < 4; i++) {
      int m = (tid >> 4) + i * 16, kk = tid & 15;
      float v = 0.f;
      if (bm + m < M && k0 + kk < K) v = A[(size_t)(bm + m) * lda + k0 + kk];
      As[m][kk] = v;
    }
#pragma unroll
    for (int i = 0; i < 4; i++) {
      int n = tid & 63, kk = (tid >> 6) + i * 4;
      float v = 0.f;
      if (k0 + kk < K && bn + n < N) v = B[(size_t)(k0 + kk) * ldb + bn + n];
      Bs[kk][n] = v;
    }
    __syncthreads();
#pragma unroll
    for (int kk = 0; kk < 16; kk++) {
      float a[4], b[4];
#pragma unroll
      for (int i = 0; i < 4; i++) a[i] = As[tm + i][kk];
#pragma unroll
      for (int j = 0; j < 4; j++) b[j] = Bs[kk][tn + j];
#pragma unroll
      for (int i = 0; i < 4; i++)
#pragma unroll
        for (int j = 0; j < 4; j++) acc[i][j] = fmaf(a[i], b[j], acc[i][j]);
    }
    __syncthreads();
  }
#pragma unroll
  for (int i = 0; i < 4; i++) {
    int m = bm + tm + i;
    if (m >= M) continue;
#pragma unroll
    for (int j = 0; j < 4; j++) {
      int n = bn + tn + j;
      if (n < N) C[(size_t)m * ldc + n] = acc[i][j];
    }
  }
}

// ================= RMSNorm in-place =================
__global__ __launch_bounds__(256) void k_rmsnorm(float* __restrict__ x, const float* __restrict__ gamma,
                                                 int rowstride, int n) {
  int r = blockIdx.x;
  float* p = x + (size_t)r * rowstride;
  __shared__ float red[256];
  float s = 0.f;
  for (int i = threadIdx.x; i < n; i += 256) { float v = p[i]; s += v * v; }
  red[threadIdx.x] = s; __syncthreads();
  for (int st = 128; st > 0; st >>= 1) { if (threadIdx.x < st) red[threadIdx.x] += red[threadIdx.x + st]; __syncthreads(); }
  float scl = rsqrtf(red[0] / (float)n + EPS_F);
  for (int i = threadIdx.x; i < n; i += 256) p[i] = p[i] * scl * gamma[i];
}

// ================= RoPE in-place (f32) =================
__global__ __launch_bounds__(256) void k_rope(float* __restrict__ base, int rowstride, int nh, int hstride,
                                              int off, const float* __restrict__ cosb, const float* __restrict__ sinb,
                                              int total) {
  int idx = blockIdx.x * 256 + threadIdx.x;
  if (idx >= total) return;
  int i = idx & 31, h = (idx >> 5) % nh, t = idx / (32 * nh);
  float* p = base + (size_t)t * rowstride + h * hstride + off;
  float x1 = p[i], x2 = p[i + 32];
  float c = cosb[t * 32 + i], s = sinb[t * 32 + i];
  p[i] = x1 * c - x2 * s;
  p[i + 32] = x1 * s + x2 * c;
}

// ================= RoPE in-place (bf16) =================
__global__ __launch_bounds__(256) void k_rope_b(unsigned short* __restrict__ base, int rowstride, int nh,
                                                int hstride, int off, const float* __restrict__ cosb,
                                                const float* __restrict__ sinb, int total) {
  int idx = blockIdx.x * 256 + threadIdx.x;
  if (idx >= total) return;
  int i = idx & 31, h = (idx >> 5) % nh, t = idx / (32 * nh);
  unsigned short* p = base + (size_t)t * rowstride + h * hstride + off;
  float x1 = b2f(p[i]), x2 = b2f(p[i + 32]);
  float c = cosb[t * 32 + i], s = sinb[t * 32 + i];
  p[i] = f2b(x1 * c - x2 * s);
  p[i + 32] = f2b(x1 * s + x2 * c);
}

// ================= ki: LayerNorm(128) + RoPE on first 64, in-place =================
__global__ __launch_bounds__(128) void k_ki_ln_rope(float* __restrict__ ki, const float* __restrict__ g,
                                                    const float* __restrict__ b,
                                                    const float* __restrict__ cosb, const float* __restrict__ sinb) {
  int t = blockIdx.x, i = threadIdx.x;
  float* p = ki + (size_t)t * 128;
  __shared__ float red[128];
  __shared__ float buf[128];
  float v = p[i];
  red[i] = v; __syncthreads();
  for (int st = 64; st > 0; st >>= 1) { if (i < st) red[i] += red[i + st]; __syncthreads(); }
  float mean = red[0] * (1.f / 128.f);
  __syncthreads();
  float d = v - mean;
  red[i] = d * d; __syncthreads();
  for (int st = 64; st > 0; st >>= 1) { if (i < st) red[i] += red[i + st]; __syncthreads(); }
  float var = red[0] * (1.f / 128.f);
  float y = d * rsqrtf(var + EPS_F) * g[i] + b[i];
  buf[i] = y; __syncthreads();
  float outv;
  if (i < 32) {
    float c = cosb[t * 32 + i], s = sinb[t * 32 + i];
    outv = buf[i] * c - buf[i + 32] * s;
  } else if (i < 64) {
    int j = i - 32;
    float c = cosb[t * 32 + j], s = sinb[t * 32 + j];
    outv = buf[j] * s + buf[i] * c;
  } else outv = y;
  p[i] = outv;
}

// ================= indexer scores via MFMA: 64x64 causal tiles =================
// out[t][s] = ISCALE * sum_h w[t,h] * relu( Qi_h[t,:] . Ki[s,:] )
__global__ __launch_bounds__(256) void k_idx_mfma(
    const unsigned short* __restrict__ qi_b,  // [S][2048] bf16 (16 heads x 128, roped)
    const unsigned short* __restrict__ ki_b,  // [S][128]  bf16 (ln+roped)
    const float* __restrict__ wb,             // [S][16]   f32
    float* __restrict__ out) {                // [S][2048] f32
  int bid = blockIdx.x;
  int tb = (int)((sqrtf(8.f * bid + 1.f) - 1.f) * 0.5f);
  while ((tb + 1) * (tb + 2) / 2 <= bid) tb++;
  while (tb * (tb + 1) / 2 > bid) tb--;
  int sb = bid - tb * (tb + 1) / 2;
  int t0 = tb * 64, s0 = sb * 64;

  int tid = threadIdx.x, lane = tid & 63, w = tid >> 6;
  int wm = w >> 1, wn = w & 1;
  int l15 = lane & 15, quarter = lane >> 4;

  __shared__ unsigned short Ks[64 * 128];   // pitch 256B, swz ((row&7)<<4)
  __shared__ unsigned short Qs[64 * 128];
  __shared__ float Ws[64][16];

  // stage Ki tile once
#pragma unroll
  for (int i = 0; i < 4; i++) {
    int c = tid + 256 * i;
    int row = c >> 4, cc = c & 15;
    bf16x8 v = *(const bf16x8*)(ki_b + (size_t)(s0 + row) * 128 + cc * 8);
    *(bf16x8*)((char*)Ks + row * 256 + ((cc * 16) ^ ((row & 7) << 4))) = v;
  }
  for (int i = tid; i < 64 * 16; i += 256) Ws[i >> 4][i & 15] = wb[(size_t)(t0 + (i >> 4)) * 16 + (i & 15)];
  __syncthreads();

  // B fragments (Ki rows = s), kept in registers across all heads
  bf16x8 bfr[2][4];
#pragma unroll
  for (int nf = 0; nf < 2; nf++) {
    int row = wn * 32 + nf * 16 + l15;
    int rx = (row & 7) << 4;
#pragma unroll
    for (int kc = 0; kc < 4; kc++)
      bfr[nf][kc] = *(const bf16x8*)((const char*)Ks + row * 256 + ((kc * 64 + quarter * 16) ^ rx));
  }

  f32x4 acc[2][2];
#pragma unroll
  for (int mf = 0; mf < 2; mf++)
#pragma unroll
    for (int nf = 0; nf < 2; nf++) acc[mf][nf] = (f32x4){0.f, 0.f, 0.f, 0.f};

  for (int h = 0; h < 16; h++) {
    __syncthreads();   // previous head's A-frag reads complete before overwrite
#pragma unroll
    for (int i = 0; i < 4; i++) {
      int c = tid + 256 * i;
      int row = c >> 4, cc = c & 15;
      bf16x8 v = *(const bf16x8*)(qi_b + (size_t)(t0 + row) * 2048 + h * 128 + cc * 8);
      *(bf16x8*)((char*)Qs + row * 256 + ((cc * 16) ^ ((row & 7) << 4))) = v;
    }
    __syncthreads();

    f32x4 acch[2][2];
#pragma unroll
    for (int mf = 0; mf < 2; mf++)
#pragma unroll
      for (int nf = 0; nf < 2; nf++) acch[mf][nf] = (f32x4){0.f, 0.f, 0.f, 0.f};

#pragma unroll
    for (int mf = 0; mf < 2; mf++) {
      int row = wm * 32 + mf * 16 + l15;
      int rx = (row & 7) << 4;
      bf16x8 af[4];
#pragma unroll
      for (int kc = 0; kc < 4; kc++)
        af[kc] = *(const bf16x8*)((const char*)Qs + row * 256 + ((kc * 64 + quarter * 16) ^ rx));
#pragma unroll
      for (int nf = 0; nf < 2; nf++)
#pragma unroll
        for (int kc = 0; kc < 4; kc++)
          acch[mf][nf] = __builtin_amdgcn_mfma_f32_16x16x32_bf16(af[kc], bfr[nf][kc], acch[mf][nf], 0, 0, 0);
    }
    // relu + per-row weight, accumulate over heads
#pragma unroll
    for (int mf = 0; mf < 2; mf++) {
#pragma unroll
      for (int r = 0; r < 4; r++) {
        float wv = Ws[wm * 32 + mf * 16 + quarter * 4 + r][h];
#pragma unroll
        for (int nf = 0; nf < 2; nf++)
          acc[mf][nf][r] = fmaf(wv, fmaxf(acch[mf][nf][r], 0.f), acc[mf][nf][r]);
      }
    }
  }
#pragma unroll
  for (int mf = 0; mf < 2; mf++)
#pragma unroll
    for (int nf = 0; nf < 2; nf++)
#pragma unroll
      for (int r = 0; r < 4; r++) {
        int t = t0 + wm * 32 + mf * 16 + quarter * 4 + r;
        int s = s0 + wn * 32 + nf * 16 + l15;
        out[(size_t)t * 2048 + s] = acc[mf][nf][r] * ISCALE_ID;
      }
}

// ================= per-row top-K -> bitmask =================
__global__ __launch_bounds__(256) void k_topk_mask(const float* __restrict__ idx_sc, u64* __restrict__ maskw) {
  int t = blockIdx.x;
  int tid = threadIdx.x;
  int n = t + 1;
  if (n <= TOPKC) {
    if (tid < 32) {
      int lo = tid * 64, hi = lo + 63;
      u64 wv;
      if (t >= hi) wv = ~0ULL;
      else if (t < lo) wv = 0ULL;
      else wv = (~0ULL) >> (63 - (t - lo));
      maskw[(size_t)t * 32 + tid] = wv;
    }
    return;
  }
  __shared__ unsigned int u[2048];
  __shared__ int hist[256];
  __shared__ u64 mw[32];
  __shared__ int sel_b, new_target, tie_base;
  __shared__ int wcnt[4];
  if (tid < 32) mw[tid] = 0ULL;
  const float* row = idx_sc + (size_t)t * 2048;
  for (int s = tid; s < n; s += 256) {
    unsigned int bb = __float_as_uint(row[s]);
    u[s] = (bb & 0x80000000u) ? ~bb : (bb | 0x80000000u);
  }
  __syncthreads();
  unsigned int prefix = 0;
  int target = TOPKC;
  for (int shift = 24; shift >= 0; shift -= 8) {
    hist[tid] = 0;
    __syncthreads();
    unsigned int himask = (shift == 24) ? 0u : (0xFFFFFFFFu << (shift + 8));
    for (int s = tid; s < n; s += 256) {
      unsigned int uv = u[s];
      if ((uv & himask) == prefix) atomicAdd(&hist[(uv >> shift) & 0xFF], 1);
    }
    __syncthreads();
    if (tid == 0) {
      int cum = 0, b = 255;
      for (; b > 0; b--) {
        if (cum + hist[b] >= target) break;
        cum += hist[b];
      }
      sel_b = b;
      new_target = target - cum;
    }
    __syncthreads();
    prefix |= ((unsigned int)sel_b) << shift;
    target = new_target;
    __syncthreads();
  }
  if (tid == 0) tie_base = 0;
  __syncthreads();
  int wid = tid >> 6, lane = tid & 63;
  for (int s0 = 0; s0 < n; s0 += 256) {
    int s = s0 + tid;
    bool in = (s < n);
    unsigned int uv = in ? u[s] : 0u;
    bool gt = in && (uv > prefix);
    bool tie = in && (uv == prefix);
    u64 bal = __ballot(tie);
    if (lane == 0) wcnt[wid] = __popcll(bal);
    __syncthreads();
    int wbase = tie_base;
    for (int wI = 0; wI < wid; wI++) wbase += wcnt[wI];
    int rank = wbase + __popcll(bal & ((1ULL << lane) - 1ULL));
    bool sel = gt || (tie && rank < target);
    if (sel) atomicOr(&mw[s >> 6], 1ULL << (s & 63));
    __syncthreads();
    if (tid == 0) tie_base += wcnt[0] + wcnt[1] + wcnt[2] + wcnt[3];
    __syncthreads();
  }
  if (tid < 32) maskw[(size_t)t * 32 + tid] = mw[tid];
}

// ================= MFMA flash attention: 64 queries x 1 head per block =================
__global__ __launch_bounds__(256) void k_attn_mfma(
    const unsigned short* __restrict__ qb,     // [S][3072] bf16, roped
    const unsigned short* __restrict__ kvb_b,  // [S][4096] bf16: per head k_nope@h*256, v@h*256+128
    const unsigned short* __restrict__ kpe_b,  // [S][64]   bf16, roped
    const u64* __restrict__ maskw,             // [S][32]
    unsigned short* __restrict__ attn_b) {     // [S][2048] bf16
  int ybm = blockIdx.x;
  int h = blockIdx.y;
  int yb = (ybm < 16) ? ybm : (47 - ybm);      // pair heavy+light blocks per CU
  int t0 = yb * 64;
  int tid = threadIdx.x;
  int lane = tid & 63, wq = tid >> 6;
  int quarter = lane >> 4, l15 = lane & 15;

  __shared__ unsigned short Ks[32 * 192];   // pitch 384B, swz ((r&7)<<4)
  __shared__ unsigned short Vts[128 * 32];  // V^T, pitch 64B, swz ((d&3)<<4)
  __shared__ unsigned short Ps[64 * 32];    // P,   pitch 64B, swz ((t&3)<<4)
  __shared__ u64 Mw[64];

  bf16x8 qf[6];
  {
    const unsigned short* qp = qb + (size_t)(t0 + wq * 16 + l15) * 3072 + h * 192 + quarter * 8;
#pragma unroll
    for (int kc = 0; kc < 6; kc++) qf[kc] = *(const bf16x8*)(qp + kc * 32);
  }
  f32x4 o[8];
#pragma unroll
  for (int df = 0; df < 8; df++) o[df] = (f32x4){0.f, 0.f, 0.f, 0.f};
  float m[4], l[4];
#pragma unroll
  for (int r = 0; r < 4; r++) { m[r] = -__builtin_inff(); l[r] = 0.f; }

  int nsb = t0 / 32 + 2;
  for (int sb = 0; sb < nsb; sb++) {
    int s0 = sb * 32;
    __syncthreads();
    if (tid < 64) Mw[tid] = maskw[(size_t)(t0 + tid) * 32 + (s0 >> 6)];
#pragma unroll
    for (int i = 0; i < 3; i++) {
      int c = tid + 256 * i;
      int row = c / 24, cc = c - row * 24;
      bf16x8 v;
      if (cc < 16) v = *(const bf16x8*)(kvb_b + (size_t)(s0 + row) * 4096 + h * 256 + cc * 8);
      else         v = *(const bf16x8*)(kpe_b + (size_t)(s0 + row) * 64 + (cc - 16) * 8);
      int byte = row * 384 + ((cc * 16) ^ ((row & 7) << 4));
      *(bf16x8*)((char*)Ks + byte) = v;
    }
    {
      int dg = tid & 15, sp = tid >> 4;
      int s = sp * 2, d0 = dg * 8;
      const unsigned short* vp0 = kvb_b + (size_t)(s0 + s) * 4096 + h * 256 + 128 + d0;
      bf16x8 v0 = *(const bf16x8*)vp0;
      bf16x8 v1 = *(const bf16x8*)(vp0 + 4096);
#pragma unroll
      for (int j = 0; j < 8; j++) {
        int d = d0 + j;
        unsigned pack = (unsigned)(unsigned short)v0[j] | (((unsigned)(unsigned short)v1[j]) << 16);
        int byte = d * 64 + ((s * 2) ^ ((d & 3) << 4));
        *(unsigned*)((char*)Vts + byte) = pack;
      }
    }
    __syncthreads();

    // QK^T: 16x32 scores per wave
    f32x4 sf[2];
#pragma unroll
    for (int sc = 0; sc < 2; sc++) {
      f32x4 a = (f32x4){0.f, 0.f, 0.f, 0.f};
      int row = sc * 16 + l15;
      int rx = (row & 7) << 4;
#pragma unroll
      for (int kc = 0; kc < 6; kc++) {
        int byte = row * 384 + ((kc * 64 + quarter * 16) ^ rx);
        bf16x8 kf = *(const bf16x8*)((const char*)Ks + byte);
        a = __builtin_amdgcn_mfma_f32_16x16x32_bf16(qf[kc], kf, a, 0, 0, 0);
      }
      sf[sc] = a;
    }
    // mask + online softmax
    float p[2][4];
#pragma unroll
    for (int r = 0; r < 4; r++) {
      int rq = wq * 16 + quarter * 4 + r;
      u64 w = Mw[rq];
#pragma unroll
      for (int sc = 0; sc < 2; sc++) {
        int s = s0 + sc * 16 + l15;
        bool sel = (w >> (s & 63)) & 1ULL;
        p[sc][r] = sel ? sf[sc][r] * SCALE_ATTN : -__builtin_inff();
      }
    }
#pragma unroll
    for (int r = 0; r < 4; r++) {
      float v = fmaxf(p[0][r], p[1][r]);
      v = fmaxf(v, __shfl_xor(v, 1));
      v = fmaxf(v, __shfl_xor(v, 2));
      v = fmaxf(v, __shfl_xor(v, 4));
      v = fmaxf(v, __shfl_xor(v, 8));
      float mn = fmaxf(m[r], v);
      float scl;
      if (mn == -__builtin_inff()) {
        scl = 1.f; p[0][r] = 0.f; p[1][r] = 0.f;
      } else {
        scl = __expf(m[r] - mn);
        p[0][r] = __expf(p[0][r] - mn);
        p[1][r] = __expf(p[1][r] - mn);
        m[r] = mn;
      }
      float rs = p[0][r] + p[1][r];
      rs += __shfl_xor(rs, 1);
      rs += __shfl_xor(rs, 2);
      rs += __shfl_xor(rs, 4);
      rs += __shfl_xor(rs, 8);
      l[r] = l[r] * scl + rs;
#pragma unroll
      for (int df = 0; df < 8; df++) o[df][r] *= scl;
      int rowp = wq * 16 + quarter * 4 + r;
      int rxp = (rowp & 3) << 4;
      *(unsigned short*)((char*)Ps + rowp * 64 + (((0 * 16 + l15) * 2) ^ rxp)) = f2b(p[0][r]);
      *(unsigned short*)((char*)Ps + rowp * 64 + (((1 * 16 + l15) * 2) ^ rxp)) = f2b(p[1][r]);
    }
    // PV
    {
      int rowp = wq * 16 + l15;
      int byte = rowp * 64 + ((quarter * 16) ^ ((rowp & 3) << 4));
      bf16x8 pa = *(const bf16x8*)((const char*)Ps + byte);
#pragma unroll
      for (int df = 0; df < 8; df++) {
        int d = df * 16 + l15;
        int vbyte = d * 64 + ((quarter * 16) ^ ((d & 3) << 4));
        bf16x8 vf = *(const bf16x8*)((const char*)Vts + vbyte);
        o[df] = __builtin_amdgcn_mfma_f32_16x16x32_bf16(pa, vf, o[df], 0, 0, 0);
      }
    }
  }
#pragma unroll
  for (int r = 0; r < 4; r++) {
    float inv = (l[r] > 0.f) ? 1.f / l[r] : 0.f;
    int t = t0 + wq * 16 + quarter * 4 + r;
    unsigned short* op = attn_b + (size_t)t * 2048 + h * 128 + l15;
#pragma unroll
    for (int df = 0; df < 8; df++) op[df * 16] = f2b(o[df][r] * inv);
  }
}

// ================= host launch =================
extern "C" void kernel_launch(void* const* d_in, const int* in_sizes, int n_in,
                              void* d_out, int out_size, void* d_ws, size_t ws_size,
                              hipStream_t stream) {
  const float* hs     = (const float*)d_in[0];
  const float* cosb   = (const float*)d_in[1];
  const float* sinb   = (const float*)d_in[2];
  const float* Wq_a   = (const float*)d_in[3];
  const float* q_a_g  = (const float*)d_in[4];
  const float* Wq_b   = (const float*)d_in[5];
  const float* Wkv_a  = (const float*)d_in[6];
  const float* kv_a_g = (const float*)d_in[7];
  const float* Wkv_b  = (const float*)d_in[8];
  const float* Wo     = (const float*)d_in[9];
  const float* Wq_idx = (const float*)d_in[10];
  const float* Wk_idx = (const float*)d_in[11];
  const float* Ww_idx = (const float*)d_in[12];
  const float* kn_g   = (const float*)d_in[13];
  const float* kn_b   = (const float*)d_in[14];
  float* out = (float*)d_out;

  char* base = (char*)d_ws;
  size_t off = 0;
  auto alloc = [&](size_t bytes) { void* p = base + off; off += (bytes + 255) & ~size_t(255); return p; };

  float* regionA = (float*)alloc((size_t)S_ * 2048 * 4);   // qa (f32) then idxs (f32)
  float* qa   = regionA;
  float* idxs = regionA;
  unsigned short* qi_b = (unsigned short*)alloc((size_t)S_ * 2048 * 2);  // qi bf16; attn_b aliases after idx_scores
  unsigned short* attn_b = qi_b;
  float* kvraw = (float*)alloc((size_t)S_ * 576 * 4);
  float* ki    = (float*)alloc((size_t)S_ * 128 * 4);
  float* wb    = (float*)alloc((size_t)S_ * 16 * 4);
  u64*   maskw = (u64*)alloc((size_t)S_ * 32 * 8);
  unsigned short* hs_b  = (unsigned short*)alloc((size_t)S_ * 2048 * 2);
  unsigned short* qa_b  = (unsigned short*)alloc((size_t)S_ * 1536 * 2);
  unsigned short* qb    = (unsigned short*)alloc((size_t)S_ * 3072 * 2);
  unsigned short* kvc_b = (unsigned short*)alloc((size_t)S_ * 512 * 2);
  unsigned short* kpe_b = (unsigned short*)alloc((size_t)S_ * 64 * 2);
  unsigned short* kvb_b = (unsigned short*)alloc((size_t)S_ * 4096 * 2);
  unsigned short* ki_b  = (unsigned short*)alloc((size_t)S_ * 128 * 2);
  unsigned short* WT    = (unsigned short*)alloc((size_t)3072 * 1536 * 2);  // JIT weight^T scratch

  dim3 blk(256);

  // hs -> bf16
  k_cast_bf16<<<dim3((S_ * 2048 / 4) / 256), blk, 0, stream>>>(hs, 2048, hs_b, 2048, S_, 2048);
  // q_a = rmsnorm(hs @ Wq_a)
  k_tcast<<<dim3(1536 / 32, 2048 / 32), blk, 0, stream>>>(Wq_a, 2048, 1536, WT);
  k_gemm_bf16<<<dim3(12, 16), blk, 0, stream>>>(hs_b, 2048, WT, 2048, qa, 1536, 1536, 0);
  k_rmsnorm<<<dim3(S_), blk, 0, stream>>>(qa, q_a_g, 1536, 1536);
  k_cast_bf16<<<dim3((S_ * 1536 / 4) / 256), blk, 0, stream>>>(qa, 1536, qa_b, 1536, S_, 1536);
  // q = q_a @ Wq_b (bf16 out), rope q_pe
  k_tcast<<<dim3(3072 / 32, 1536 / 32), blk, 0, stream>>>(Wq_b, 1536, 3072, WT);
  k_gemm_bf16<<<dim3(24, 16), blk, 0, stream>>>(qa_b, 1536, WT, 1536, qb, 3072, 3072, 1);
  k_rope_b<<<dim3((S_ * 16 * 32) / 256), blk, 0, stream>>>(qb, 3072, 16, 192, 128, cosb, sinb, S_ * 16 * 32);
  // kv = hs @ Wkv_a (f32), rmsnorm + rope, casts
  k_tcast<<<dim3(576 / 32, 2048 / 32), blk, 0, stream>>>(Wkv_a, 2048, 576, WT);
  k_gemm_bf16<<<dim3(5, 16), blk, 0, stream>>>(hs_b, 2048, WT, 2048, kvraw, 576, 576, 0);
  k_rmsnorm<<<dim3(S_), blk, 0, stream>>>(kvraw, kv_a_g, 576, KVL_);
  k_rope<<<dim3((S_ * 32) / 256), blk, 0, stream>>>(kvraw, 576, 1, 0, 512, cosb, sinb, S_ * 32);
  k_cast_bf16<<<dim3((S_ * 512 / 4) / 256), blk, 0, stream>>>(kvraw, 576, kvc_b, 512, S_, 512);
  k_cast_bf16<<<dim3((S_ * 64 / 4) / 256), blk, 0, stream>>>(kvraw + 512, 576, kpe_b, 64, S_, 64);
  // kvb = kv_c @ Wkv_b (bf16 out)
  k_tcast<<<dim3(4096 / 32, 512 / 32), blk, 0, stream>>>(Wkv_b, 512, 4096, WT);
  k_gemm_bf16<<<dim3(32, 16), blk, 0, stream>>>(kvc_b, 512, WT, 512, kvb_b, 4096, 4096, 1);
  // qi = q_a @ Wq_idx (bf16 out), rope (bf16)
  k_tcast<<<dim3(2048 / 32, 1536 / 32), blk, 0, stream>>>(Wq_idx, 1536, 2048, WT);
  k_gemm_bf16<<<dim3(16, 16), blk, 0, stream>>>(qa_b, 1536, WT, 1536, qi_b, 2048, 2048, 1);
  k_rope_b<<<dim3((S_ * 16 * 32) / 256), blk, 0, stream>>>(qi_b, 2048, 16, 128, 0, cosb, sinb, S_ * 16 * 32);
  // ki = layernorm(hs @ Wk_idx) + rope, then cast bf16
  k_tcast<<<dim3(128 / 32, 2048 / 32), blk, 0, stream>>>(Wk_idx, 2048, 128, WT);
  k_gemm_bf16<<<dim3(1, 16), blk, 0, stream>>>(hs_b, 2048, WT, 2048, ki, 128, 128, 0);
  k_ki_ln_rope<<<dim3(S_), dim3(128), 0, stream>>>(ki, kn_g, kn_b, cosb, sinb);
  k_cast_bf16<<<dim3((S_ * 128 / 4) / 256), blk, 0, stream>>>(ki, 128, ki_b, 128, S_, 128);
  // w = hs @ Ww_idx (small f32 GEMM)
  k_gemm<<<dim3(1, S_ / 64), blk, 0, stream>>>(hs, H_, Ww_idx, 16, wb, 16, S_, 16, H_);
  // indexer scores via MFMA (triangular grid: 32*33/2 = 528 tiles)
  k_idx_mfma<<<dim3(528), blk, 0, stream>>>(qi_b, ki_b, wb, idxs);
  // top-512 per row -> bitmask
  k_topk_mask<<<dim3(S_), blk, 0, stream>>>(idxs, maskw);
  // MFMA flash attention -> attn_b (bf16, aliases qi_b which is dead now)
  k_attn_mfma<<<dim3(32, 16), blk, 0, stream>>>(qb, kvb_b, kpe_b, maskw, attn_b);
  // out = attn @ Wo
  k_tcast<<<dim3(2048 / 32, 2048 / 32), blk, 0, stream>>>(Wo, 2048, 2048, WT);
  k_gemm_bf16<<<dim3(16, 16), blk, 0, stream>>>(attn_b, 2048, WT, 2048, out, 2048, 2048, 0);

  (void)in_sizes; (void)n_in; (void)out_size; (void)ws_size;
}

// Round 4
// 830.935 us; speedup vs baseline: 5.6031x; 1.2688x over previous
//
#include <hip/hip_runtime.h>
#include <cstdint>
#include <cstddef>
#include <cmath>

typedef unsigned long long u64;
typedef __attribute__((ext_vector_type(8))) short bf16x8;   // 8 bf16 in 4 VGPRs (guide §3)
typedef __attribute__((ext_vector_type(4))) float f32x4;

static constexpr int S_    = 2048;
static constexpr int H_    = 2048;
static constexpr int QL_   = 1536;
static constexpr int KVL_  = 512;
static constexpr int TOPKC = 512;

#define SCALE_ATTN 0.07216878364870323f   // (192)^-0.5
#define ISCALE_ID  0.08838834764831845f   // (128)^-0.5
#define EPS_F 1e-6f

__device__ inline unsigned short f2b(float f) {
  unsigned u = __float_as_uint(f);
  return (unsigned short)((u + 0x7FFFu + ((u >> 16) & 1u)) >> 16);
}
__device__ inline float b2f(unsigned short b) {
  return __uint_as_float(((unsigned)b) << 16);
}

// ================= bf16 MFMA GEMM: C[M,N] = A[M,K] @ Bt[N,K]^T =================
// 128x128 tile, BK=64, 256 threads / 4 waves (2x2 of 64x64). M multiple of 128.
__global__ __launch_bounds__(256) void k_gemm_bf16(
    const unsigned short* __restrict__ A, int lda,
    const unsigned short* __restrict__ Bt, int K,      // Bt pitch = K
    void* __restrict__ C, int ldc, int N, int out_bf16) {
  __shared__ unsigned short As[128 * 64];
  __shared__ unsigned short Bs[128 * 64];
  const int bm = blockIdx.y * 128, bn = blockIdx.x * 128;
  const int tid = threadIdx.x;
  const int lane = tid & 63, w = tid >> 6;
  const int wm = w >> 1, wn = w & 1;
  const int l15 = lane & 15, quarter = lane >> 4;

  f32x4 acc[4][4];
#pragma unroll
  for (int i = 0; i < 4; i++)
#pragma unroll
    for (int j = 0; j < 4; j++) acc[i][j] = (f32x4){0.f, 0.f, 0.f, 0.f};

  for (int k0 = 0; k0 < K; k0 += 64) {
    __syncthreads();
#pragma unroll
    for (int i = 0; i < 4; i++) {
      int c = tid + 256 * i;
      int row = c >> 3, cc = c & 7;
      int byte = row * 128 + ((cc * 16) ^ ((row & 7) << 4));
      bf16x8 va = *(const bf16x8*)(A + (size_t)(bm + row) * lda + k0 + cc * 8);
      *(bf16x8*)((char*)As + byte) = va;
      bf16x8 vb = (bf16x8)(short)0;
      if (bn + row < N) vb = *(const bf16x8*)(Bt + (size_t)(bn + row) * K + k0 + cc * 8);
      *(bf16x8*)((char*)Bs + byte) = vb;
    }
    __syncthreads();
#pragma unroll
    for (int kc = 0; kc < 2; kc++) {
      bf16x8 af[4], bfr[4];
#pragma unroll
      for (int mf = 0; mf < 4; mf++) {
        int row = wm * 64 + mf * 16 + l15;
        int byte = row * 128 + (((kc * 64 + quarter * 16)) ^ ((row & 7) << 4));
        af[mf] = *(const bf16x8*)((const char*)As + byte);
      }
#pragma unroll
      for (int nf = 0; nf < 4; nf++) {
        int row = wn * 64 + nf * 16 + l15;
        int byte = row * 128 + (((kc * 64 + quarter * 16)) ^ ((row & 7) << 4));
        bfr[nf] = *(const bf16x8*)((const char*)Bs + byte);
      }
#pragma unroll
      for (int mf = 0; mf < 4; mf++)
#pragma unroll
        for (int nf = 0; nf < 4; nf++)
          acc[mf][nf] = __builtin_amdgcn_mfma_f32_16x16x32_bf16(af[mf], bfr[nf], acc[mf][nf], 0, 0, 0);
    }
  }
#pragma unroll
  for (int mf = 0; mf < 4; mf++)
#pragma unroll
    for (int nf = 0; nf < 4; nf++)
#pragma unroll
      for (int r = 0; r < 4; r++) {
        int grow = bm + wm * 64 + mf * 16 + quarter * 4 + r;
        int gcol = bn + wn * 64 + nf * 16 + l15;
        if (gcol < N) {
          if (out_bf16) ((unsigned short*)C)[(size_t)grow * ldc + gcol] = f2b(acc[mf][nf][r]);
          else          ((float*)C)[(size_t)grow * ldc + gcol] = acc[mf][nf][r];
        }
      }
}

// ================= transpose + cast: Wt[n][k] = bf16(W[k][n]), dims mult of 32 =================
__global__ __launch_bounds__(256) void k_tcast(const float* __restrict__ W, int K, int N,
                                               unsigned short* __restrict__ Wt) {
  __shared__ float T[32][33];
  int n0 = blockIdx.x * 32, k0 = blockIdx.y * 32;
  int tid = threadIdx.x;
#pragma unroll
  for (int i = 0; i < 4; i++) {
    int idx = tid + 256 * i;
    int r = idx >> 5, c = idx & 31;
    T[r][c] = W[(size_t)(k0 + r) * N + n0 + c];
  }
  __syncthreads();
#pragma unroll
  for (int i = 0; i < 4; i++) {
    int idx = tid + 256 * i;
    int r = idx >> 5, c = idx & 31;
    Wt[(size_t)(n0 + r) * K + k0 + c] = f2b(T[c][r]);
  }
}

// ================= strided f32 -> bf16 cast =================
__global__ __launch_bounds__(256) void k_cast_bf16(const float* __restrict__ in, int pin,
                                                   unsigned short* __restrict__ outp, int pout,
                                                   int rows, int cols) {
  int cols4 = cols >> 2;
  int idx = blockIdx.x * 256 + threadIdx.x;
  if (idx >= rows * cols4) return;
  int r = idx / cols4, c = (idx - r * cols4) * 4;
  const float* ip = in + (size_t)r * pin + c;
  unsigned short* op = outp + (size_t)r * pout + c;
  op[0] = f2b(ip[0]); op[1] = f2b(ip[1]); op[2] = f2b(ip[2]); op[3] = f2b(ip[3]);
}

// ================= wb = hs @ Ww_idx  (M=2048, N=16, K=2048)  GEMV-style =================
// 8 rows/block (2 per wave). lane: h = lane&15, kg = lane>>4 covers K/4.
__global__ __launch_bounds__(256) void k_wb(const float* __restrict__ hs, const float* __restrict__ W,
                                            float* __restrict__ wb) {
  int r0 = blockIdx.x * 8;
  int tid = threadIdx.x;
  int w = tid >> 6, lane = tid & 63;
  int h = lane & 15, kg = lane >> 4;
#pragma unroll
  for (int rr = 0; rr < 2; rr++) {
    int r = r0 + w * 2 + rr;
    const float* hp = hs + (size_t)r * 2048;
    float acc = 0.f;
    int kbeg = kg * 512, kend = kbeg + 512;
    for (int k = kbeg; k < kend; k += 4) {
      float4 hv = *(const float4*)(hp + k);
      acc = fmaf(hv.x, W[(k    ) * 16 + h], acc);
      acc = fmaf(hv.y, W[(k + 1) * 16 + h], acc);
      acc = fmaf(hv.z, W[(k + 2) * 16 + h], acc);
      acc = fmaf(hv.w, W[(k + 3) * 16 + h], acc);
    }
    acc += __shfl_xor(acc, 16);
    acc += __shfl_xor(acc, 32);
    if (kg == 0) wb[(size_t)r * 16 + h] = acc;
  }
}

// ================= RMSNorm in-place =================
__global__ __launch_bounds__(256) void k_rmsnorm(float* __restrict__ x, const float* __restrict__ gamma,
                                                 int rowstride, int n) {
  int r = blockIdx.x;
  float* p = x + (size_t)r * rowstride;
  __shared__ float red[256];
  float s = 0.f;
  for (int i = threadIdx.x; i < n; i += 256) { float v = p[i]; s += v * v; }
  red[threadIdx.x] = s; __syncthreads();
  for (int st = 128; st > 0; st >>= 1) { if (threadIdx.x < st) red[threadIdx.x] += red[threadIdx.x + st]; __syncthreads(); }
  float scl = rsqrtf(red[0] / (float)n + EPS_F);
  for (int i = threadIdx.x; i < n; i += 256) p[i] = p[i] * scl * gamma[i];
}

// ================= RoPE in-place (f32) =================
__global__ __launch_bounds__(256) void k_rope(float* __restrict__ base, int rowstride, int nh, int hstride,
                                              int off, const float* __restrict__ cosb, const float* __restrict__ sinb,
                                              int total) {
  int idx = blockIdx.x * 256 + threadIdx.x;
  if (idx >= total) return;
  int i = idx & 31, h = (idx >> 5) % nh, t = idx / (32 * nh);
  float* p = base + (size_t)t * rowstride + h * hstride + off;
  float x1 = p[i], x2 = p[i + 32];
  float c = cosb[t * 32 + i], s = sinb[t * 32 + i];
  p[i] = x1 * c - x2 * s;
  p[i + 32] = x1 * s + x2 * c;
}

// ================= RoPE in-place (bf16) =================
__global__ __launch_bounds__(256) void k_rope_b(unsigned short* __restrict__ base, int rowstride, int nh,
                                                int hstride, int off, const float* __restrict__ cosb,
                                                const float* __restrict__ sinb, int total) {
  int idx = blockIdx.x * 256 + threadIdx.x;
  if (idx >= total) return;
  int i = idx & 31, h = (idx >> 5) % nh, t = idx / (32 * nh);
  unsigned short* p = base + (size_t)t * rowstride + h * hstride + off;
  float x1 = b2f(p[i]), x2 = b2f(p[i + 32]);
  float c = cosb[t * 32 + i], s = sinb[t * 32 + i];
  p[i] = f2b(x1 * c - x2 * s);
  p[i + 32] = f2b(x1 * s + x2 * c);
}

// ================= ki: LayerNorm(128) + RoPE on first 64, in-place =================
__global__ __launch_bounds__(128) void k_ki_ln_rope(float* __restrict__ ki, const float* __restrict__ g,
                                                    const float* __restrict__ b,
                                                    const float* __restrict__ cosb, const float* __restrict__ sinb) {
  int t = blockIdx.x, i = threadIdx.x;
  float* p = ki + (size_t)t * 128;
  __shared__ float red[128];
  __shared__ float buf[128];
  float v = p[i];
  red[i] = v; __syncthreads();
  for (int st = 64; st > 0; st >>= 1) { if (i < st) red[i] += red[i + st]; __syncthreads(); }
  float mean = red[0] * (1.f / 128.f);
  __syncthreads();
  float d = v - mean;
  red[i] = d * d; __syncthreads();
  for (int st = 64; st > 0; st >>= 1) { if (i < st) red[i] += red[i + st]; __syncthreads(); }
  float var = red[0] * (1.f / 128.f);
  float y = d * rsqrtf(var + EPS_F) * g[i] + b[i];
  buf[i] = y; __syncthreads();
  float outv;
  if (i < 32) {
    float c = cosb[t * 32 + i], s = sinb[t * 32 + i];
    outv = buf[i] * c - buf[i + 32] * s;
  } else if (i < 64) {
    int j = i - 32;
    float c = cosb[t * 32 + j], s = sinb[t * 32 + j];
    outv = buf[j] * s + buf[i] * c;
  } else outv = y;
  p[i] = outv;
}

// ================= indexer scores via MFMA: 64x64 causal tiles =================
// out[t][s] = ISCALE * sum_h w[t,h] * relu( Qi_h[t,:] . Ki[s,:] )
__global__ __launch_bounds__(256) void k_idx_mfma(
    const unsigned short* __restrict__ qi_b,  // [S][2048] bf16 (16 heads x 128, roped)
    const unsigned short* __restrict__ ki_b,  // [S][128]  bf16 (ln+roped)
    const float* __restrict__ wb,             // [S][16]   f32
    float* __restrict__ out) {                // [S][2048] f32
  int bid = blockIdx.x;
  int tb = (int)((sqrtf(8.f * bid + 1.f) - 1.f) * 0.5f);
  while ((tb + 1) * (tb + 2) / 2 <= bid) tb++;
  while (tb * (tb + 1) / 2 > bid) tb--;
  int sb = bid - tb * (tb + 1) / 2;
  int t0 = tb * 64, s0 = sb * 64;

  int tid = threadIdx.x, lane = tid & 63, w = tid >> 6;
  int wm = w >> 1, wn = w & 1;
  int l15 = lane & 15, quarter = lane >> 4;

  __shared__ unsigned short Ks[64 * 128];   // pitch 256B, swz ((row&7)<<4)
  __shared__ unsigned short Qs[64 * 128];
  __shared__ float Ws[64][16];

#pragma unroll
  for (int i = 0; i < 4; i++) {
    int c = tid + 256 * i;
    int row = c >> 4, cc = c & 15;
    bf16x8 v = *(const bf16x8*)(ki_b + (size_t)(s0 + row) * 128 + cc * 8);
    *(bf16x8*)((char*)Ks + row * 256 + ((cc * 16) ^ ((row & 7) << 4))) = v;
  }
  for (int i = tid; i < 64 * 16; i += 256) Ws[i >> 4][i & 15] = wb[(size_t)(t0 + (i >> 4)) * 16 + (i & 15)];
  __syncthreads();

  bf16x8 bfr[2][4];
#pragma unroll
  for (int nf = 0; nf < 2; nf++) {
    int row = wn * 32 + nf * 16 + l15;
    int rx = (row & 7) << 4;
#pragma unroll
    for (int kc = 0; kc < 4; kc++)
      bfr[nf][kc] = *(const bf16x8*)((const char*)Ks + row * 256 + ((kc * 64 + quarter * 16) ^ rx));
  }

  f32x4 acc[2][2];
#pragma unroll
  for (int mf = 0; mf < 2; mf++)
#pragma unroll
    for (int nf = 0; nf < 2; nf++) acc[mf][nf] = (f32x4){0.f, 0.f, 0.f, 0.f};

  for (int h = 0; h < 16; h++) {
    __syncthreads();
#pragma unroll
    for (int i = 0; i < 4; i++) {
      int c = tid + 256 * i;
      int row = c >> 4, cc = c & 15;
      bf16x8 v = *(const bf16x8*)(qi_b + (size_t)(t0 + row) * 2048 + h * 128 + cc * 8);
      *(bf16x8*)((char*)Qs + row * 256 + ((cc * 16) ^ ((row & 7) << 4))) = v;
    }
    __syncthreads();

    f32x4 acch[2][2];
#pragma unroll
    for (int mf = 0; mf < 2; mf++)
#pragma unroll
      for (int nf = 0; nf < 2; nf++) acch[mf][nf] = (f32x4){0.f, 0.f, 0.f, 0.f};

#pragma unroll
    for (int mf = 0; mf < 2; mf++) {
      int row = wm * 32 + mf * 16 + l15;
      int rx = (row & 7) << 4;
      bf16x8 af[4];
#pragma unroll
      for (int kc = 0; kc < 4; kc++)
        af[kc] = *(const bf16x8*)((const char*)Qs + row * 256 + ((kc * 64 + quarter * 16) ^ rx));
#pragma unroll
      for (int nf = 0; nf < 2; nf++)
#pragma unroll
        for (int kc = 0; kc < 4; kc++)
          acch[mf][nf] = __builtin_amdgcn_mfma_f32_16x16x32_bf16(af[kc], bfr[nf][kc], acch[mf][nf], 0, 0, 0);
    }
#pragma unroll
    for (int mf = 0; mf < 2; mf++) {
#pragma unroll
      for (int r = 0; r < 4; r++) {
        float wv = Ws[wm * 32 + mf * 16 + quarter * 4 + r][h];
#pragma unroll
        for (int nf = 0; nf < 2; nf++)
          acc[mf][nf][r] = fmaf(wv, fmaxf(acch[mf][nf][r], 0.f), acc[mf][nf][r]);
      }
    }
  }
#pragma unroll
  for (int mf = 0; mf < 2; mf++)
#pragma unroll
    for (int nf = 0; nf < 2; nf++)
#pragma unroll
      for (int r = 0; r < 4; r++) {
        int t = t0 + wm * 32 + mf * 16 + quarter * 4 + r;
        int s = s0 + wn * 32 + nf * 16 + l15;
        out[(size_t)t * 2048 + s] = acc[mf][nf][r] * ISCALE_ID;
      }
}

// ================= per-row top-K -> bitmask =================
__global__ __launch_bounds__(256) void k_topk_mask(const float* __restrict__ idx_sc, u64* __restrict__ maskw) {
  int t = blockIdx.x;
  int tid = threadIdx.x;
  int n = t + 1;
  if (n <= TOPKC) {
    if (tid < 32) {
      int lo = tid * 64, hi = lo + 63;
      u64 wv;
      if (t >= hi) wv = ~0ULL;
      else if (t < lo) wv = 0ULL;
      else wv = (~0ULL) >> (63 - (t - lo));
      maskw[(size_t)t * 32 + tid] = wv;
    }
    return;
  }
  __shared__ unsigned int u[2048];
  __shared__ int hist[256];
  __shared__ u64 mw[32];
  __shared__ int sel_b, new_target, tie_base;
  __shared__ int wcnt[4];
  if (tid < 32) mw[tid] = 0ULL;
  const float* row = idx_sc + (size_t)t * 2048;
  for (int s = tid; s < n; s += 256) {
    unsigned int bb = __float_as_uint(row[s]);
    u[s] = (bb & 0x80000000u) ? ~bb : (bb | 0x80000000u);
  }
  __syncthreads();
  unsigned int prefix = 0;
  int target = TOPKC;
  for (int shift = 24; shift >= 0; shift -= 8) {
    hist[tid] = 0;
    __syncthreads();
    unsigned int himask = (shift == 24) ? 0u : (0xFFFFFFFFu << (shift + 8));
    for (int s = tid; s < n; s += 256) {
      unsigned int uv = u[s];
      if ((uv & himask) == prefix) atomicAdd(&hist[(uv >> shift) & 0xFF], 1);
    }
    __syncthreads();
    if (tid == 0) {
      int cum = 0, b = 255;
      for (; b > 0; b--) {
        if (cum + hist[b] >= target) break;
        cum += hist[b];
      }
      sel_b = b;
      new_target = target - cum;
    }
    __syncthreads();
    prefix |= ((unsigned int)sel_b) << shift;
    target = new_target;
    __syncthreads();
  }
  if (tid == 0) tie_base = 0;
  __syncthreads();
  int wid = tid >> 6, lane = tid & 63;
  for (int s0 = 0; s0 < n; s0 += 256) {
    int s = s0 + tid;
    bool in = (s < n);
    unsigned int uv = in ? u[s] : 0u;
    bool gt = in && (uv > prefix);
    bool tie = in && (uv == prefix);
    u64 bal = __ballot(tie);
    if (lane == 0) wcnt[wid] = __popcll(bal);
    __syncthreads();
    int wbase = tie_base;
    for (int wI = 0; wI < wid; wI++) wbase += wcnt[wI];
    int rank = wbase + __popcll(bal & ((1ULL << lane) - 1ULL));
    bool sel = gt || (tie && rank < target);
    if (sel) atomicOr(&mw[s >> 6], 1ULL << (s & 63));
    __syncthreads();
    if (tid == 0) tie_base += wcnt[0] + wcnt[1] + wcnt[2] + wcnt[3];
    __syncthreads();
  }
  if (tid < 32) maskw[(size_t)t * 32 + tid] = mw[tid];
}

// ================= MFMA flash attention: 64 queries x 1 head per block =================
__global__ __launch_bounds__(256) void k_attn_mfma(
    const unsigned short* __restrict__ qb,     // [S][3072] bf16, roped
    const unsigned short* __restrict__ kvb_b,  // [S][4096] bf16: per head k_nope@h*256, v@h*256+128
    const unsigned short* __restrict__ kpe_b,  // [S][64]   bf16, roped
    const u64* __restrict__ maskw,             // [S][32]
    unsigned short* __restrict__ attn_b) {     // [S][2048] bf16
  int ybm = blockIdx.x;
  int h = blockIdx.y;
  int yb = (ybm < 16) ? ybm : (47 - ybm);      // pair heavy+light blocks per CU
  int t0 = yb * 64;
  int tid = threadIdx.x;
  int lane = tid & 63, wq = tid >> 6;
  int quarter = lane >> 4, l15 = lane & 15;

  __shared__ unsigned short Ks[32 * 192];   // pitch 384B, swz ((r&7)<<4)
  __shared__ unsigned short Vts[128 * 32];  // V^T, pitch 64B, swz ((d&3)<<4)
  __shared__ unsigned short Ps[64 * 32];    // P,   pitch 64B, swz ((t&3)<<4)
  __shared__ u64 Mw[64];

  bf16x8 qf[6];
  {
    const unsigned short* qp = qb + (size_t)(t0 + wq * 16 + l15) * 3072 + h * 192 + quarter * 8;
#pragma unroll
    for (int kc = 0; kc < 6; kc++) qf[kc] = *(const bf16x8*)(qp + kc * 32);
  }
  f32x4 o[8];
#pragma unroll
  for (int df = 0; df < 8; df++) o[df] = (f32x4){0.f, 0.f, 0.f, 0.f};
  float m[4], l[4];
#pragma unroll
  for (int r = 0; r < 4; r++) { m[r] = -__builtin_inff(); l[r] = 0.f; }

  int nsb = t0 / 32 + 2;
  for (int sb = 0; sb < nsb; sb++) {
    int s0 = sb * 32;
    __syncthreads();
    if (tid < 64) Mw[tid] = maskw[(size_t)(t0 + tid) * 32 + (s0 >> 6)];
#pragma unroll
    for (int i = 0; i < 3; i++) {
      int c = tid + 256 * i;
      int row = c / 24, cc = c - row * 24;
      bf16x8 v;
      if (cc < 16) v = *(const bf16x8*)(kvb_b + (size_t)(s0 + row) * 4096 + h * 256 + cc * 8);
      else         v = *(const bf16x8*)(kpe_b + (size_t)(s0 + row) * 64 + (cc - 16) * 8);
      int byte = row * 384 + ((cc * 16) ^ ((row & 7) << 4));
      *(bf16x8*)((char*)Ks + byte) = v;
    }
    {
      int dg = tid & 15, sp = tid >> 4;
      int s = sp * 2, d0 = dg * 8;
      const unsigned short* vp0 = kvb_b + (size_t)(s0 + s) * 4096 + h * 256 + 128 + d0;
      bf16x8 v0 = *(const bf16x8*)vp0;
      bf16x8 v1 = *(const bf16x8*)(vp0 + 4096);
#pragma unroll
      for (int j = 0; j < 8; j++) {
        int d = d0 + j;
        unsigned pack = (unsigned)(unsigned short)v0[j] | (((unsigned)(unsigned short)v1[j]) << 16);
        int byte = d * 64 + ((s * 2) ^ ((d & 3) << 4));
        *(unsigned*)((char*)Vts + byte) = pack;
      }
    }
    __syncthreads();

    f32x4 sf[2];
#pragma unroll
    for (int sc = 0; sc < 2; sc++) {
      f32x4 a = (f32x4){0.f, 0.f, 0.f, 0.f};
      int row = sc * 16 + l15;
      int rx = (row & 7) << 4;
#pragma unroll
      for (int kc = 0; kc < 6; kc++) {
        int byte = row * 384 + ((kc * 64 + quarter * 16) ^ rx);
        bf16x8 kf = *(const bf16x8*)((const char*)Ks + byte);
        a = __builtin_amdgcn_mfma_f32_16x16x32_bf16(qf[kc], kf, a, 0, 0, 0);
      }
      sf[sc] = a;
    }
    float p[2][4];
#pragma unroll
    for (int r = 0; r < 4; r++) {
      int rq = wq * 16 + quarter * 4 + r;
      u64 w = Mw[rq];
#pragma unroll
      for (int sc = 0; sc < 2; sc++) {
        int s = s0 + sc * 16 + l15;
        bool sel = (w >> (s & 63)) & 1ULL;
        p[sc][r] = sel ? sf[sc][r] * SCALE_ATTN : -__builtin_inff();
      }
    }
#pragma unroll
    for (int r = 0; r < 4; r++) {
      float v = fmaxf(p[0][r], p[1][r]);
      v = fmaxf(v, __shfl_xor(v, 1));
      v = fmaxf(v, __shfl_xor(v, 2));
      v = fmaxf(v, __shfl_xor(v, 4));
      v = fmaxf(v, __shfl_xor(v, 8));
      float mn = fmaxf(m[r], v);
      float scl;
      if (mn == -__builtin_inff()) {
        scl = 1.f; p[0][r] = 0.f; p[1][r] = 0.f;
      } else {
        scl = __expf(m[r] - mn);
        p[0][r] = __expf(p[0][r] - mn);
        p[1][r] = __expf(p[1][r] - mn);
        m[r] = mn;
      }
      float rs = p[0][r] + p[1][r];
      rs += __shfl_xor(rs, 1);
      rs += __shfl_xor(rs, 2);
      rs += __shfl_xor(rs, 4);
      rs += __shfl_xor(rs, 8);
      l[r] = l[r] * scl + rs;
#pragma unroll
      for (int df = 0; df < 8; df++) o[df][r] *= scl;
      int rowp = wq * 16 + quarter * 4 + r;
      int rxp = (rowp & 3) << 4;
      *(unsigned short*)((char*)Ps + rowp * 64 + (((0 * 16 + l15) * 2) ^ rxp)) = f2b(p[0][r]);
      *(unsigned short*)((char*)Ps + rowp * 64 + (((1 * 16 + l15) * 2) ^ rxp)) = f2b(p[1][r]);
    }
    {
      int rowp = wq * 16 + l15;
      int byte = rowp * 64 + ((quarter * 16) ^ ((rowp & 3) << 4));
      bf16x8 pa = *(const bf16x8*)((const char*)Ps + byte);
#pragma unroll
      for (int df = 0; df < 8; df++) {
        int d = df * 16 + l15;
        int vbyte = d * 64 + ((quarter * 16) ^ ((d & 3) << 4));
        bf16x8 vf = *(const bf16x8*)((const char*)Vts + vbyte);
        o[df] = __builtin_amdgcn_mfma_f32_16x16x32_bf16(pa, vf, o[df], 0, 0, 0);
      }
    }
  }
#pragma unroll
  for (int r = 0; r < 4; r++) {
    float inv = (l[r] > 0.f) ? 1.f / l[r] : 0.f;
    int t = t0 + wq * 16 + quarter * 4 + r;
    unsigned short* op = attn_b + (size_t)t * 2048 + h * 128 + l15;
#pragma unroll
    for (int df = 0; df < 8; df++) op[df * 16] = f2b(o[df][r] * inv);
  }
}

// ================= host launch =================
extern "C" void kernel_launch(void* const* d_in, const int* in_sizes, int n_in,
                              void* d_out, int out_size, void* d_ws, size_t ws_size,
                              hipStream_t stream) {
  const float* hs     = (const float*)d_in[0];
  const float* cosb   = (const float*)d_in[1];
  const float* sinb   = (const float*)d_in[2];
  const float* Wq_a   = (const float*)d_in[3];
  const float* q_a_g  = (const float*)d_in[4];
  const float* Wq_b   = (const float*)d_in[5];
  const float* Wkv_a  = (const float*)d_in[6];
  const float* kv_a_g = (const float*)d_in[7];
  const float* Wkv_b  = (const float*)d_in[8];
  const float* Wo     = (const float*)d_in[9];
  const float* Wq_idx = (const float*)d_in[10];
  const float* Wk_idx = (const float*)d_in[11];
  const float* Ww_idx = (const float*)d_in[12];
  const float* kn_g   = (const float*)d_in[13];
  const float* kn_b   = (const float*)d_in[14];
  float* out = (float*)d_out;

  char* base = (char*)d_ws;
  size_t off = 0;
  auto alloc = [&](size_t bytes) { void* p = base + off; off += (bytes + 255) & ~size_t(255); return p; };

  float* regionA = (float*)alloc((size_t)S_ * 2048 * 4);   // qa (f32) then idxs (f32)
  float* qa   = regionA;
  float* idxs = regionA;
  unsigned short* qi_b = (unsigned short*)alloc((size_t)S_ * 2048 * 2);  // qi bf16; attn_b aliases after idx_scores
  unsigned short* attn_b = qi_b;
  float* kvraw = (float*)alloc((size_t)S_ * 576 * 4);
  float* ki    = (float*)alloc((size_t)S_ * 128 * 4);
  float* wb    = (float*)alloc((size_t)S_ * 16 * 4);
  u64*   maskw = (u64*)alloc((size_t)S_ * 32 * 8);
  unsigned short* hs_b  = (unsigned short*)alloc((size_t)S_ * 2048 * 2);
  unsigned short* qa_b  = (unsigned short*)alloc((size_t)S_ * 1536 * 2);
  unsigned short* qb    = (unsigned short*)alloc((size_t)S_ * 3072 * 2);
  unsigned short* kvc_b = (unsigned short*)alloc((size_t)S_ * 512 * 2);
  unsigned short* kpe_b = (unsigned short*)alloc((size_t)S_ * 64 * 2);
  unsigned short* kvb_b = (unsigned short*)alloc((size_t)S_ * 4096 * 2);
  unsigned short* ki_b  = (unsigned short*)alloc((size_t)S_ * 128 * 2);
  unsigned short* WT    = (unsigned short*)alloc((size_t)3072 * 1536 * 2);  // JIT weight^T scratch

  dim3 blk(256);

  // hs -> bf16
  k_cast_bf16<<<dim3((S_ * 2048 / 4) / 256), blk, 0, stream>>>(hs, 2048, hs_b, 2048, S_, 2048);
  // q_a = rmsnorm(hs @ Wq_a)
  k_tcast<<<dim3(1536 / 32, 2048 / 32), blk, 0, stream>>>(Wq_a, 2048, 1536, WT);
  k_gemm_bf16<<<dim3(12, 16), blk, 0, stream>>>(hs_b, 2048, WT, 2048, qa, 1536, 1536, 0);
  k_rmsnorm<<<dim3(S_), blk, 0, stream>>>(qa, q_a_g, 1536, 1536);
  k_cast_bf16<<<dim3((S_ * 1536 / 4) / 256), blk, 0, stream>>>(qa, 1536, qa_b, 1536, S_, 1536);
  // q = q_a @ Wq_b (bf16 out), rope q_pe
  k_tcast<<<dim3(3072 / 32, 1536 / 32), blk, 0, stream>>>(Wq_b, 1536, 3072, WT);
  k_gemm_bf16<<<dim3(24, 16), blk, 0, stream>>>(qa_b, 1536, WT, 1536, qb, 3072, 3072, 1);
  k_rope_b<<<dim3((S_ * 16 * 32) / 256), blk, 0, stream>>>(qb, 3072, 16, 192, 128, cosb, sinb, S_ * 16 * 32);
  // kv = hs @ Wkv_a (f32), rmsnorm + rope, casts
  k_tcast<<<dim3(576 / 32, 2048 / 32), blk, 0, stream>>>(Wkv_a, 2048, 576, WT);
  k_gemm_bf16<<<dim3(5, 16), blk, 0, stream>>>(hs_b, 2048, WT, 2048, kvraw, 576, 576, 0);
  k_rmsnorm<<<dim3(S_), blk, 0, stream>>>(kvraw, kv_a_g, 576, KVL_);
  k_rope<<<dim3((S_ * 32) / 256), blk, 0, stream>>>(kvraw, 576, 1, 0, 512, cosb, sinb, S_ * 32);
  k_cast_bf16<<<dim3((S_ * 512 / 4) / 256), blk, 0, stream>>>(kvraw, 576, kvc_b, 512, S_, 512);
  k_cast_bf16<<<dim3((S_ * 64 / 4) / 256), blk, 0, stream>>>(kvraw + 512, 576, kpe_b, 64, S_, 64);
  // kvb = kv_c @ Wkv_b (bf16 out)
  k_tcast<<<dim3(4096 / 32, 512 / 32), blk, 0, stream>>>(Wkv_b, 512, 4096, WT);
  k_gemm_bf16<<<dim3(32, 16), blk, 0, stream>>>(kvc_b, 512, WT, 512, kvb_b, 4096, 4096, 1);
  // qi = q_a @ Wq_idx (bf16 out), rope (bf16)
  k_tcast<<<dim3(2048 / 32, 1536 / 32), blk, 0, stream>>>(Wq_idx, 1536, 2048, WT);
  k_gemm_bf16<<<dim3(16, 16), blk, 0, stream>>>(qa_b, 1536, WT, 1536, qi_b, 2048, 2048, 1);
  k_rope_b<<<dim3((S_ * 16 * 32) / 256), blk, 0, stream>>>(qi_b, 2048, 16, 128, 0, cosb, sinb, S_ * 16 * 32);
  // ki = layernorm(hs @ Wk_idx) + rope, then cast bf16
  k_tcast<<<dim3(128 / 32, 2048 / 32), blk, 0, stream>>>(Wk_idx, 2048, 128, WT);
  k_gemm_bf16<<<dim3(1, 16), blk, 0, stream>>>(hs_b, 2048, WT, 2048, ki, 128, 128, 0);
  k_ki_ln_rope<<<dim3(S_), dim3(128), 0, stream>>>(ki, kn_g, kn_b, cosb, sinb);
  k_cast_bf16<<<dim3((S_ * 128 / 4) / 256), blk, 0, stream>>>(ki, 128, ki_b, 128, S_, 128);
  // w = hs @ Ww_idx  (GEMV-style, K-parallel)
  k_wb<<<dim3(S_ / 8), blk, 0, stream>>>(hs, Ww_idx, wb);
  // indexer scores via MFMA (triangular grid: 32*33/2 = 528 tiles)
  k_idx_mfma<<<dim3(528), blk, 0, stream>>>(qi_b, ki_b, wb, idxs);
  // top-512 per row -> bitmask
  k_topk_mask<<<dim3(S_), blk, 0, stream>>>(idxs, maskw);
  // MFMA flash attention -> attn_b (bf16, aliases qi_b which is dead now)
  k_attn_mfma<<<dim3(32, 16), blk, 0, stream>>>(qb, kvb_b, kpe_b, maskw, attn_b);
  // out = attn @ Wo
  k_tcast<<<dim3(2048 / 32, 2048 / 32), blk, 0, stream>>>(Wo, 2048, 2048, WT);
  k_gemm_bf16<<<dim3(16, 16), blk, 0, stream>>>(attn_b, 2048, WT, 2048, out, 2048, 2048, 0);

  (void)in_sizes; (void)n_in; (void)out_size; (void)ws_size;
}

// Round 5
// 698.088 us; speedup vs baseline: 6.6694x; 1.1903x over previous
//
#include <hip/hip_runtime.h>
#include <cstdint>
#include <cstddef>
#include <cmath>

typedef unsigned long long u64;
typedef __attribute__((ext_vector_type(8))) short bf16x8;   // 8 bf16 in 4 VGPRs
typedef __attribute__((ext_vector_type(4))) float f32x4;

static constexpr int S_    = 2048;
static constexpr int H_    = 2048;
static constexpr int QL_   = 1536;
static constexpr int KVL_  = 512;
static constexpr int TOPKC = 512;

#define SCALE_ATTN 0.07216878364870323f   // (192)^-0.5
#define ISCALE_ID  0.08838834764831845f   // (128)^-0.5
#define EPS_F 1e-6f

__device__ inline unsigned short f2b(float f) {
  unsigned u = __float_as_uint(f);
  return (unsigned short)((u + 0x7FFFu + ((u >> 16) & 1u)) >> 16);
}
__device__ inline float b2f(unsigned short b) {
  return __uint_as_float(((unsigned)b) << 16);
}
// async global->LDS, 16B per lane; LDS dest = wave-uniform base + lane*16
__device__ inline void gload16(const unsigned short* g, unsigned short* l) {
  __builtin_amdgcn_global_load_lds((const __attribute__((address_space(1))) void*)g,
                                   (__attribute__((address_space(3))) void*)l, 16, 0, 0);
}

// ================= bf16 MFMA GEMM: C[M,N] = A[M,K] @ Bt[N,K]^T =================
// 128x128 tile, BK=64, 4 waves (2x2 of 64x64). M mult of 128. Linear LDS + global_load_lds.
// OOB Bt rows (N not mult of 128) read garbage inside caller-owned scratch; epilogue masks cols.
__global__ __launch_bounds__(256) void k_gemm_bf16(
    const unsigned short* __restrict__ A, int lda,
    const unsigned short* __restrict__ Bt, int K,      // Bt pitch = K
    void* __restrict__ C, int ldc, int N, int out_bf16) {
  __shared__ unsigned short As[128 * 64];
  __shared__ unsigned short Bs[128 * 64];
  const int bm = blockIdx.y * 128, bn = blockIdx.x * 128;
  const int tid = threadIdx.x;
  const int lane = tid & 63, w = tid >> 6;
  const int wm = w >> 1, wn = w & 1;
  const int l15 = lane & 15, quarter = lane >> 4;
  const int srow = (lane >> 3), scol = (lane & 7) * 8;   // staging: 8 rows/call, 8 bf16/lane

  f32x4 acc[4][4];
#pragma unroll
  for (int i = 0; i < 4; i++)
#pragma unroll
    for (int j = 0; j < 4; j++) acc[i][j] = (f32x4){0.f, 0.f, 0.f, 0.f};

  for (int k0 = 0; k0 < K; k0 += 64) {
    __syncthreads();
#pragma unroll
    for (int i = 0; i < 4; i++) {
      int r0 = w * 32 + i * 8;
      gload16(A  + (size_t)(bm + r0 + srow) * lda + k0 + scol, &As[r0 * 64]);
      gload16(Bt + (size_t)(bn + r0 + srow) * K   + k0 + scol, &Bs[r0 * 64]);
    }
    __syncthreads();   // compiler drains vmcnt before s_barrier
#pragma unroll
    for (int kc = 0; kc < 2; kc++) {
      bf16x8 af[4], bfr[4];
#pragma unroll
      for (int mf = 0; mf < 4; mf++)
        af[mf] = *(const bf16x8*)(As + (wm * 64 + mf * 16 + l15) * 64 + kc * 32 + quarter * 8);
#pragma unroll
      for (int nf = 0; nf < 4; nf++)
        bfr[nf] = *(const bf16x8*)(Bs + (wn * 64 + nf * 16 + l15) * 64 + kc * 32 + quarter * 8);
#pragma unroll
      for (int mf = 0; mf < 4; mf++)
#pragma unroll
        for (int nf = 0; nf < 4; nf++)
          acc[mf][nf] = __builtin_amdgcn_mfma_f32_16x16x32_bf16(af[mf], bfr[nf], acc[mf][nf], 0, 0, 0);
    }
  }
#pragma unroll
  for (int mf = 0; mf < 4; mf++)
#pragma unroll
    for (int nf = 0; nf < 4; nf++)
#pragma unroll
      for (int r = 0; r < 4; r++) {
        int grow = bm + wm * 64 + mf * 16 + quarter * 4 + r;
        int gcol = bn + wn * 64 + nf * 16 + l15;
        if (gcol < N) {
          if (out_bf16) ((unsigned short*)C)[(size_t)grow * ldc + gcol] = f2b(acc[mf][nf][r]);
          else          ((float*)C)[(size_t)grow * ldc + gcol] = acc[mf][nf][r];
        }
      }
}

// ================= transpose + cast: Wt[n][k] = bf16(W[k][n]) =================
__global__ __launch_bounds__(256) void k_tcast(const float* __restrict__ W, int K, int N,
                                               unsigned short* __restrict__ Wt) {
  __shared__ float T[32][33];
  int n0 = blockIdx.x * 32, k0 = blockIdx.y * 32;
  int tid = threadIdx.x;
#pragma unroll
  for (int i = 0; i < 4; i++) {
    int idx = tid + 256 * i;
    int r = idx >> 5, c = idx & 31;
    T[r][c] = W[(size_t)(k0 + r) * N + n0 + c];
  }
  __syncthreads();
#pragma unroll
  for (int i = 0; i < 4; i++) {
    int idx = tid + 256 * i;
    int r = idx >> 5, c = idx & 31;
    Wt[(size_t)(n0 + r) * K + k0 + c] = f2b(T[c][r]);
  }
}

// ================= strided f32 -> bf16 cast =================
__global__ __launch_bounds__(256) void k_cast_bf16(const float* __restrict__ in, int pin,
                                                   unsigned short* __restrict__ outp, int pout,
                                                   int rows, int cols) {
  int cols4 = cols >> 2;
  int idx = blockIdx.x * 256 + threadIdx.x;
  if (idx >= rows * cols4) return;
  int r = idx / cols4, c = (idx - r * cols4) * 4;
  const float* ip = in + (size_t)r * pin + c;
  unsigned short* op = outp + (size_t)r * pout + c;
  op[0] = f2b(ip[0]); op[1] = f2b(ip[1]); op[2] = f2b(ip[2]); op[3] = f2b(ip[3]);
}

// ================= wb = hs @ Ww_idx  GEMV-style =================
__global__ __launch_bounds__(256) void k_wb(const float* __restrict__ hs, const float* __restrict__ W,
                                            float* __restrict__ wb) {
  int r0 = blockIdx.x * 8;
  int tid = threadIdx.x;
  int w = tid >> 6, lane = tid & 63;
  int h = lane & 15, kg = lane >> 4;
#pragma unroll
  for (int rr = 0; rr < 2; rr++) {
    int r = r0 + w * 2 + rr;
    const float* hp = hs + (size_t)r * 2048;
    float acc = 0.f;
    int kbeg = kg * 512, kend = kbeg + 512;
    for (int k = kbeg; k < kend; k += 4) {
      float4 hv = *(const float4*)(hp + k);
      acc = fmaf(hv.x, W[(k    ) * 16 + h], acc);
      acc = fmaf(hv.y, W[(k + 1) * 16 + h], acc);
      acc = fmaf(hv.z, W[(k + 2) * 16 + h], acc);
      acc = fmaf(hv.w, W[(k + 3) * 16 + h], acc);
    }
    acc += __shfl_xor(acc, 16);
    acc += __shfl_xor(acc, 32);
    if (kg == 0) wb[(size_t)r * 16 + h] = acc;
  }
}

// ================= RMSNorm in-place =================
__global__ __launch_bounds__(256) void k_rmsnorm(float* __restrict__ x, const float* __restrict__ gamma,
                                                 int rowstride, int n) {
  int r = blockIdx.x;
  float* p = x + (size_t)r * rowstride;
  __shared__ float red[256];
  float s = 0.f;
  for (int i = threadIdx.x; i < n; i += 256) { float v = p[i]; s += v * v; }
  red[threadIdx.x] = s; __syncthreads();
  for (int st = 128; st > 0; st >>= 1) { if (threadIdx.x < st) red[threadIdx.x] += red[threadIdx.x + st]; __syncthreads(); }
  float scl = rsqrtf(red[0] / (float)n + EPS_F);
  for (int i = threadIdx.x; i < n; i += 256) p[i] = p[i] * scl * gamma[i];
}

// ================= RoPE in-place (f32) =================
__global__ __launch_bounds__(256) void k_rope(float* __restrict__ base, int rowstride, int nh, int hstride,
                                              int off, const float* __restrict__ cosb, const float* __restrict__ sinb,
                                              int total) {
  int idx = blockIdx.x * 256 + threadIdx.x;
  if (idx >= total) return;
  int i = idx & 31, h = (idx >> 5) % nh, t = idx / (32 * nh);
  float* p = base + (size_t)t * rowstride + h * hstride + off;
  float x1 = p[i], x2 = p[i + 32];
  float c = cosb[t * 32 + i], s = sinb[t * 32 + i];
  p[i] = x1 * c - x2 * s;
  p[i + 32] = x1 * s + x2 * c;
}

// ================= RoPE in-place (bf16) =================
__global__ __launch_bounds__(256) void k_rope_b(unsigned short* __restrict__ base, int rowstride, int nh,
                                                int hstride, int off, const float* __restrict__ cosb,
                                                const float* __restrict__ sinb, int total) {
  int idx = blockIdx.x * 256 + threadIdx.x;
  if (idx >= total) return;
  int i = idx & 31, h = (idx >> 5) % nh, t = idx / (32 * nh);
  unsigned short* p = base + (size_t)t * rowstride + h * hstride + off;
  float x1 = b2f(p[i]), x2 = b2f(p[i + 32]);
  float c = cosb[t * 32 + i], s = sinb[t * 32 + i];
  p[i] = f2b(x1 * c - x2 * s);
  p[i + 32] = f2b(x1 * s + x2 * c);
}

// ================= ki: LayerNorm(128) + RoPE on first 64, in-place =================
__global__ __launch_bounds__(128) void k_ki_ln_rope(float* __restrict__ ki, const float* __restrict__ g,
                                                    const float* __restrict__ b,
                                                    const float* __restrict__ cosb, const float* __restrict__ sinb) {
  int t = blockIdx.x, i = threadIdx.x;
  float* p = ki + (size_t)t * 128;
  __shared__ float red[128];
  __shared__ float buf[128];
  float v = p[i];
  red[i] = v; __syncthreads();
  for (int st = 64; st > 0; st >>= 1) { if (i < st) red[i] += red[i + st]; __syncthreads(); }
  float mean = red[0] * (1.f / 128.f);
  __syncthreads();
  float d = v - mean;
  red[i] = d * d; __syncthreads();
  for (int st = 64; st > 0; st >>= 1) { if (i < st) red[i] += red[i + st]; __syncthreads(); }
  float var = red[0] * (1.f / 128.f);
  float y = d * rsqrtf(var + EPS_F) * g[i] + b[i];
  buf[i] = y; __syncthreads();
  float outv;
  if (i < 32) {
    float c = cosb[t * 32 + i], s = sinb[t * 32 + i];
    outv = buf[i] * c - buf[i + 32] * s;
  } else if (i < 64) {
    int j = i - 32;
    float c = cosb[t * 32 + j], s = sinb[t * 32 + j];
    outv = buf[j] * s + buf[i] * c;
  } else outv = y;
  p[i] = outv;
}

// ================= indexer scores via MFMA: 64x64 causal tiles (gload_lds staging) =================
__global__ __launch_bounds__(256) void k_idx_mfma(
    const unsigned short* __restrict__ qi_b,  // [S][2048] bf16
    const unsigned short* __restrict__ ki_b,  // [S][128]  bf16
    const float* __restrict__ wb,             // [S][16]   f32
    float* __restrict__ out) {                // [S][2048] f32
  int bid = blockIdx.x;
  int tb = (int)((sqrtf(8.f * bid + 1.f) - 1.f) * 0.5f);
  while ((tb + 1) * (tb + 2) / 2 <= bid) tb++;
  while (tb * (tb + 1) / 2 > bid) tb--;
  int sb = bid - tb * (tb + 1) / 2;
  int t0 = tb * 64, s0 = sb * 64;

  int tid = threadIdx.x, lane = tid & 63, w = tid >> 6;
  int wm = w >> 1, wn = w & 1;
  int l15 = lane & 15, quarter = lane >> 4;
  const int srow = lane >> 4, scol = (lane & 15) * 8;  // staging: 4 rows/call

  __shared__ unsigned short Ks[64 * 128];   // linear, pitch 256B
  __shared__ unsigned short Qs[64 * 128];
  __shared__ float Ws[64][16];

#pragma unroll
  for (int i = 0; i < 4; i++) {
    int r0 = w * 16 + i * 4;
    gload16(ki_b + (size_t)(s0 + r0 + srow) * 128 + scol, &Ks[r0 * 128]);
  }
  for (int i = tid; i < 64 * 16; i += 256) Ws[i >> 4][i & 15] = wb[(size_t)(t0 + (i >> 4)) * 16 + (i & 15)];
  __syncthreads();

  bf16x8 bfr[2][4];
#pragma unroll
  for (int nf = 0; nf < 2; nf++)
#pragma unroll
    for (int kc = 0; kc < 4; kc++)
      bfr[nf][kc] = *(const bf16x8*)(Ks + (wn * 32 + nf * 16 + l15) * 128 + kc * 32 + quarter * 8);

  f32x4 acc[2][2];
#pragma unroll
  for (int mf = 0; mf < 2; mf++)
#pragma unroll
    for (int nf = 0; nf < 2; nf++) acc[mf][nf] = (f32x4){0.f, 0.f, 0.f, 0.f};

  for (int h = 0; h < 16; h++) {
    __syncthreads();
#pragma unroll
    for (int i = 0; i < 4; i++) {
      int r0 = w * 16 + i * 4;
      gload16(qi_b + (size_t)(t0 + r0 + srow) * 2048 + h * 128 + scol, &Qs[r0 * 128]);
    }
    __syncthreads();

    f32x4 acch[2][2];
#pragma unroll
    for (int mf = 0; mf < 2; mf++)
#pragma unroll
      for (int nf = 0; nf < 2; nf++) acch[mf][nf] = (f32x4){0.f, 0.f, 0.f, 0.f};

#pragma unroll
    for (int mf = 0; mf < 2; mf++) {
      bf16x8 af[4];
#pragma unroll
      for (int kc = 0; kc < 4; kc++)
        af[kc] = *(const bf16x8*)(Qs + (wm * 32 + mf * 16 + l15) * 128 + kc * 32 + quarter * 8);
#pragma unroll
      for (int nf = 0; nf < 2; nf++)
#pragma unroll
        for (int kc = 0; kc < 4; kc++)
          acch[mf][nf] = __builtin_amdgcn_mfma_f32_16x16x32_bf16(af[kc], bfr[nf][kc], acch[mf][nf], 0, 0, 0);
    }
#pragma unroll
    for (int mf = 0; mf < 2; mf++) {
#pragma unroll
      for (int r = 0; r < 4; r++) {
        float wv = Ws[wm * 32 + mf * 16 + quarter * 4 + r][h];
#pragma unroll
        for (int nf = 0; nf < 2; nf++)
          acc[mf][nf][r] = fmaf(wv, fmaxf(acch[mf][nf][r], 0.f), acc[mf][nf][r]);
      }
    }
  }
#pragma unroll
  for (int mf = 0; mf < 2; mf++)
#pragma unroll
    for (int nf = 0; nf < 2; nf++)
#pragma unroll
      for (int r = 0; r < 4; r++) {
        int t = t0 + wm * 32 + mf * 16 + quarter * 4 + r;
        int s = s0 + wn * 32 + nf * 16 + l15;
        out[(size_t)t * 2048 + s] = acc[mf][nf][r] * ISCALE_ID;
      }
}

// ================= per-row top-K -> bitmask =================
__global__ __launch_bounds__(256) void k_topk_mask(const float* __restrict__ idx_sc, u64* __restrict__ maskw) {
  int t = blockIdx.x;
  int tid = threadIdx.x;
  int n = t + 1;
  if (n <= TOPKC) {
    if (tid < 32) {
      int lo = tid * 64, hi = lo + 63;
      u64 wv;
      if (t >= hi) wv = ~0ULL;
      else if (t < lo) wv = 0ULL;
      else wv = (~0ULL) >> (63 - (t - lo));
      maskw[(size_t)t * 32 + tid] = wv;
    }
    return;
  }
  __shared__ unsigned int u[2048];
  __shared__ int hist[256];
  __shared__ u64 mw[32];
  __shared__ int sel_b, new_target, tie_base;
  __shared__ int wcnt[4];
  if (tid < 32) mw[tid] = 0ULL;
  const float* row = idx_sc + (size_t)t * 2048;
  for (int s = tid; s < n; s += 256) {
    unsigned int bb = __float_as_uint(row[s]);
    u[s] = (bb & 0x80000000u) ? ~bb : (bb | 0x80000000u);
  }
  __syncthreads();
  unsigned int prefix = 0;
  int target = TOPKC;
  for (int shift = 24; shift >= 0; shift -= 8) {
    hist[tid] = 0;
    __syncthreads();
    unsigned int himask = (shift == 24) ? 0u : (0xFFFFFFFFu << (shift + 8));
    for (int s = tid; s < n; s += 256) {
      unsigned int uv = u[s];
      if ((uv & himask) == prefix) atomicAdd(&hist[(uv >> shift) & 0xFF], 1);
    }
    __syncthreads();
    if (tid == 0) {
      int cum = 0, b = 255;
      for (; b > 0; b--) {
        if (cum + hist[b] >= target) break;
        cum += hist[b];
      }
      sel_b = b;
      new_target = target - cum;
    }
    __syncthreads();
    prefix |= ((unsigned int)sel_b) << shift;
    target = new_target;
    __syncthreads();
  }
  if (tid == 0) tie_base = 0;
  __syncthreads();
  int wid = tid >> 6, lane = tid & 63;
  for (int s0 = 0; s0 < n; s0 += 256) {
    int s = s0 + tid;
    bool in = (s < n);
    unsigned int uv = in ? u[s] : 0u;
    bool gt = in && (uv > prefix);
    bool tie = in && (uv == prefix);
    u64 bal = __ballot(tie);
    if (lane == 0) wcnt[wid] = __popcll(bal);
    __syncthreads();
    int wbase = tie_base;
    for (int wI = 0; wI < wid; wI++) wbase += wcnt[wI];
    int rank = wbase + __popcll(bal & ((1ULL << lane) - 1ULL));
    bool sel = gt || (tie && rank < target);
    if (sel) atomicOr(&mw[s >> 6], 1ULL << (s & 63));
    __syncthreads();
    if (tid == 0) tie_base += wcnt[0] + wcnt[1] + wcnt[2] + wcnt[3];
    __syncthreads();
  }
  if (tid < 32) maskw[(size_t)t * 32 + tid] = mw[tid];
}

// ================= MFMA flash attention: swapped QK^T, in-register P (no P LDS) =================
__global__ __launch_bounds__(256) void k_attn_mfma(
    const unsigned short* __restrict__ qb,     // [S][3072] bf16, roped
    const unsigned short* __restrict__ kvb_b,  // [S][4096] bf16: k_nope@h*256, v@h*256+128
    const unsigned short* __restrict__ kpe_b,  // [S][64]   bf16, roped
    const u64* __restrict__ maskw,             // [S][32]
    unsigned short* __restrict__ attn_b) {     // [S][2048] bf16
  int ybm = blockIdx.x;
  int h = blockIdx.y;
  int yb = (ybm < 16) ? ybm : (47 - ybm);      // pair heavy+light blocks
  int t0 = yb * 64;
  int tid = threadIdx.x;
  int lane = tid & 63, wq = tid >> 6;
  int quarter = lane >> 4, l15 = lane & 15;

  __shared__ unsigned short Ks[32 * 192];   // pitch 384B, swz ((r&7)<<4)
  __shared__ unsigned short Vts[128 * 32];  // V^T, pitch 64B, swz ((d&3)<<4)

  bf16x8 qf[6];
  {
    const unsigned short* qp = qb + (size_t)(t0 + wq * 16 + l15) * 3072 + h * 192 + quarter * 8;
#pragma unroll
    for (int kc = 0; kc < 6; kc++) qf[kc] = *(const bf16x8*)(qp + kc * 32);
  }
  f32x4 o[8];
#pragma unroll
  for (int df = 0; df < 8; df++) o[df] = (f32x4){0.f, 0.f, 0.f, 0.f};
  // per-lane COLUMN state: t = t0 + wq*16 + l15 (replicated across quarters)
  float mcol = -__builtin_inff(), lcol = 0.f;
  const u64* mrow = maskw + (size_t)(t0 + wq * 16 + l15) * 32;

  int nsb = t0 / 32 + 2;
  for (int sb = 0; sb < nsb; sb++) {
    int s0 = sb * 32;
    __syncthreads();
#pragma unroll
    for (int i = 0; i < 3; i++) {
      int c = tid + 256 * i;
      int row = c / 24, cc = c - row * 24;
      bf16x8 v;
      if (cc < 16) v = *(const bf16x8*)(kvb_b + (size_t)(s0 + row) * 4096 + h * 256 + cc * 8);
      else         v = *(const bf16x8*)(kpe_b + (size_t)(s0 + row) * 64 + (cc - 16) * 8);
      int byte = row * 384 + ((cc * 16) ^ ((row & 7) << 4));
      *(bf16x8*)((char*)Ks + byte) = v;
    }
    {
      int dg = tid & 15, sp = tid >> 4;
      int s = sp * 2, d0 = dg * 8;
      const unsigned short* vp0 = kvb_b + (size_t)(s0 + s) * 4096 + h * 256 + 128 + d0;
      bf16x8 v0 = *(const bf16x8*)vp0;
      bf16x8 v1 = *(const bf16x8*)(vp0 + 4096);
#pragma unroll
      for (int j = 0; j < 8; j++) {
        int d = d0 + j;
        unsigned pack = (unsigned)(unsigned short)v0[j] | (((unsigned)(unsigned short)v1[j]) << 16);
        int byte = d * 64 + ((s * 2) ^ ((d & 3) << 4));
        *(unsigned*)((char*)Vts + byte) = pack;
      }
    }
    __syncthreads();

    // swapped QK^T: S^T = mfma(K, Q) -> lane(q,l15): S[t=l15][s = s0 + sc*16 + q*4 + r]
    f32x4 sfT[2];
#pragma unroll
    for (int sc = 0; sc < 2; sc++) {
      f32x4 a = (f32x4){0.f, 0.f, 0.f, 0.f};
      int row = sc * 16 + l15;
      int rx = (row & 7) << 4;
#pragma unroll
      for (int kc = 0; kc < 6; kc++) {
        int byte = row * 384 + ((kc * 64 + quarter * 16) ^ rx);
        bf16x8 kf = *(const bf16x8*)((const char*)Ks + byte);
        a = __builtin_amdgcn_mfma_f32_16x16x32_bf16(kf, qf[kc], a, 0, 0, 0);
      }
      sfT[sc] = a;
    }
    // mask + scale (column-local)
    u64 w64 = mrow[s0 >> 6];
    float p[2][4];
#pragma unroll
    for (int sc = 0; sc < 2; sc++)
#pragma unroll
      for (int r = 0; r < 4; r++) {
        int s = s0 + sc * 16 + quarter * 4 + r;
        bool sel = (w64 >> (s & 63)) & 1ULL;
        p[sc][r] = sel ? sfT[sc][r] * SCALE_ATTN : -__builtin_inff();
      }
    // column softmax: in-lane 8-max + 2 cross-quarter shuffles
    float v = p[0][0];
    v = fmaxf(v, p[0][1]); v = fmaxf(v, p[0][2]); v = fmaxf(v, p[0][3]);
    v = fmaxf(v, p[1][0]); v = fmaxf(v, p[1][1]); v = fmaxf(v, p[1][2]); v = fmaxf(v, p[1][3]);
    v = fmaxf(v, __shfl_xor(v, 16));
    v = fmaxf(v, __shfl_xor(v, 32));
    float mn = fmaxf(mcol, v);
    bool dead = (mn == -__builtin_inff());
    float scl = dead ? 1.f : __expf(mcol - mn);
#pragma unroll
    for (int sc = 0; sc < 2; sc++)
#pragma unroll
      for (int r = 0; r < 4; r++)
        p[sc][r] = dead ? 0.f : __expf(p[sc][r] - mn);
    mcol = dead ? mcol : mn;
    float rs = p[0][0] + p[0][1] + p[0][2] + p[0][3] + p[1][0] + p[1][1] + p[1][2] + p[1][3];
    rs += __shfl_xor(rs, 16);
    rs += __shfl_xor(rs, 32);
    lcol = lcol * scl + rs;

    // pack P to bf16 pairs, redistribute to PV A-fragment layout via shfl
    unsigned pk0[2], pk1[2];
#pragma unroll
    for (int rr = 0; rr < 2; rr++) {
      pk0[rr] = (unsigned)f2b(p[0][2 * rr]) | (((unsigned)f2b(p[0][2 * rr + 1])) << 16);
      pk1[rr] = (unsigned)f2b(p[1][2 * rr]) | (((unsigned)f2b(p[1][2 * rr + 1])) << 16);
    }
    union { unsigned d[4]; bf16x8 v; } pu;
#pragma unroll
    for (int jj = 0; jj < 4; jj++) {
      int src = ((quarter & 1) * 2 + (jj >> 1)) * 16 + l15;
      unsigned a0 = (unsigned)__shfl((int)pk0[jj & 1], src);
      unsigned a1 = (unsigned)__shfl((int)pk1[jj & 1], src);
      pu.d[jj] = (quarter < 2) ? a0 : a1;
    }
    bf16x8 pa = pu.v;

    // rescale O rows (row t = q*4+r -> fetch column scl from quarter-0 lane)
    float sclr[4];
#pragma unroll
    for (int r = 0; r < 4; r++) sclr[r] = __shfl(scl, quarter * 4 + r);
#pragma unroll
    for (int df = 0; df < 8; df++) {
#pragma unroll
      for (int r = 0; r < 4; r++) o[df][r] *= sclr[r];
    }
    // PV
#pragma unroll
    for (int df = 0; df < 8; df++) {
      int d = df * 16 + l15;
      int vbyte = d * 64 + ((quarter * 16) ^ ((d & 3) << 4));
      bf16x8 vf = *(const bf16x8*)((const char*)Vts + vbyte);
      o[df] = __builtin_amdgcn_mfma_f32_16x16x32_bf16(pa, vf, o[df], 0, 0, 0);
    }
  }
  float inv = (lcol > 0.f) ? 1.f / lcol : 0.f;
  float invr[4];
#pragma unroll
  for (int r = 0; r < 4; r++) invr[r] = __shfl(inv, quarter * 4 + r);
#pragma unroll
  for (int r = 0; r < 4; r++) {
    int t = t0 + wq * 16 + quarter * 4 + r;
    unsigned short* op = attn_b + (size_t)t * 2048 + h * 128 + l15;
#pragma unroll
    for (int df = 0; df < 8; df++) op[df * 16] = f2b(o[df][r] * invr[r]);
  }
}

// ================= host launch =================
extern "C" void kernel_launch(void* const* d_in, const int* in_sizes, int n_in,
                              void* d_out, int out_size, void* d_ws, size_t ws_size,
                              hipStream_t stream) {
  const float* hs     = (const float*)d_in[0];
  const float* cosb   = (const float*)d_in[1];
  const float* sinb   = (const float*)d_in[2];
  const float* Wq_a   = (const float*)d_in[3];
  const float* q_a_g  = (const float*)d_in[4];
  const float* Wq_b   = (const float*)d_in[5];
  const float* Wkv_a  = (const float*)d_in[6];
  const float* kv_a_g = (const float*)d_in[7];
  const float* Wkv_b  = (const float*)d_in[8];
  const float* Wo     = (const float*)d_in[9];
  const float* Wq_idx = (const float*)d_in[10];
  const float* Wk_idx = (const float*)d_in[11];
  const float* Ww_idx = (const float*)d_in[12];
  const float* kn_g   = (const float*)d_in[13];
  const float* kn_b   = (const float*)d_in[14];
  float* out = (float*)d_out;

  char* base = (char*)d_ws;
  size_t off = 0;
  auto alloc = [&](size_t bytes) { void* p = base + off; off += (bytes + 255) & ~size_t(255); return p; };

  float* regionA = (float*)alloc((size_t)S_ * 2048 * 4);   // qa (f32) then idxs (f32)
  float* qa   = regionA;
  float* idxs = regionA;
  unsigned short* qi_b = (unsigned short*)alloc((size_t)S_ * 2048 * 2);  // qi bf16; attn_b aliases later
  unsigned short* attn_b = qi_b;
  float* kvraw = (float*)alloc((size_t)S_ * 576 * 4);
  float* ki    = (float*)alloc((size_t)S_ * 128 * 4);
  float* wb    = (float*)alloc((size_t)S_ * 16 * 4);
  u64*   maskw = (u64*)alloc((size_t)S_ * 32 * 8);
  unsigned short* hs_b  = (unsigned short*)alloc((size_t)S_ * 2048 * 2);
  unsigned short* qa_b  = (unsigned short*)alloc((size_t)S_ * 1536 * 2);
  unsigned short* qb    = (unsigned short*)alloc((size_t)S_ * 3072 * 2);
  unsigned short* kvc_b = (unsigned short*)alloc((size_t)S_ * 512 * 2);
  unsigned short* kpe_b = (unsigned short*)alloc((size_t)S_ * 64 * 2);
  unsigned short* kvb_b = (unsigned short*)alloc((size_t)S_ * 4096 * 2);
  unsigned short* ki_b  = (unsigned short*)alloc((size_t)S_ * 128 * 2);
  unsigned short* WT    = (unsigned short*)alloc((size_t)3072 * 1536 * 2);  // JIT weight^T scratch

  dim3 blk(256);

  k_cast_bf16<<<dim3((S_ * 2048 / 4) / 256), blk, 0, stream>>>(hs, 2048, hs_b, 2048, S_, 2048);
  // q_a = rmsnorm(hs @ Wq_a)
  k_tcast<<<dim3(1536 / 32, 2048 / 32), blk, 0, stream>>>(Wq_a, 2048, 1536, WT);
  k_gemm_bf16<<<dim3(12, 16), blk, 0, stream>>>(hs_b, 2048, WT, 2048, qa, 1536, 1536, 0);
  k_rmsnorm<<<dim3(S_), blk, 0, stream>>>(qa, q_a_g, 1536, 1536);
  k_cast_bf16<<<dim3((S_ * 1536 / 4) / 256), blk, 0, stream>>>(qa, 1536, qa_b, 1536, S_, 1536);
  // q = q_a @ Wq_b (bf16 out), rope q_pe
  k_tcast<<<dim3(3072 / 32, 1536 / 32), blk, 0, stream>>>(Wq_b, 1536, 3072, WT);
  k_gemm_bf16<<<dim3(24, 16), blk, 0, stream>>>(qa_b, 1536, WT, 1536, qb, 3072, 3072, 1);
  k_rope_b<<<dim3((S_ * 16 * 32) / 256), blk, 0, stream>>>(qb, 3072, 16, 192, 128, cosb, sinb, S_ * 16 * 32);
  // kv = hs @ Wkv_a (f32), rmsnorm + rope, casts
  k_tcast<<<dim3(576 / 32, 2048 / 32), blk, 0, stream>>>(Wkv_a, 2048, 576, WT);
  k_gemm_bf16<<<dim3(5, 16), blk, 0, stream>>>(hs_b, 2048, WT, 2048, kvraw, 576, 576, 0);
  k_rmsnorm<<<dim3(S_), blk, 0, stream>>>(kvraw, kv_a_g, 576, KVL_);
  k_rope<<<dim3((S_ * 32) / 256), blk, 0, stream>>>(kvraw, 576, 1, 0, 512, cosb, sinb, S_ * 32);
  k_cast_bf16<<<dim3((S_ * 512 / 4) / 256), blk, 0, stream>>>(kvraw, 576, kvc_b, 512, S_, 512);
  k_cast_bf16<<<dim3((S_ * 64 / 4) / 256), blk, 0, stream>>>(kvraw + 512, 576, kpe_b, 64, S_, 64);
  // kvb = kv_c @ Wkv_b (bf16 out)
  k_tcast<<<dim3(4096 / 32, 512 / 32), blk, 0, stream>>>(Wkv_b, 512, 4096, WT);
  k_gemm_bf16<<<dim3(32, 16), blk, 0, stream>>>(kvc_b, 512, WT, 512, kvb_b, 4096, 4096, 1);
  // qi = q_a @ Wq_idx (bf16 out), rope (bf16)
  k_tcast<<<dim3(2048 / 32, 1536 / 32), blk, 0, stream>>>(Wq_idx, 1536, 2048, WT);
  k_gemm_bf16<<<dim3(16, 16), blk, 0, stream>>>(qa_b, 1536, WT, 1536, qi_b, 2048, 2048, 1);
  k_rope_b<<<dim3((S_ * 16 * 32) / 256), blk, 0, stream>>>(qi_b, 2048, 16, 128, 0, cosb, sinb, S_ * 16 * 32);
  // ki = layernorm(hs @ Wk_idx) + rope, then cast bf16
  k_tcast<<<dim3(128 / 32, 2048 / 32), blk, 0, stream>>>(Wk_idx, 2048, 128, WT);
  k_gemm_bf16<<<dim3(1, 16), blk, 0, stream>>>(hs_b, 2048, WT, 2048, ki, 128, 128, 0);
  k_ki_ln_rope<<<dim3(S_), dim3(128), 0, stream>>>(ki, kn_g, kn_b, cosb, sinb);
  k_cast_bf16<<<dim3((S_ * 128 / 4) / 256), blk, 0, stream>>>(ki, 128, ki_b, 128, S_, 128);
  // w = hs @ Ww_idx
  k_wb<<<dim3(S_ / 8), blk, 0, stream>>>(hs, Ww_idx, wb);
  // indexer scores (triangular grid)
  k_idx_mfma<<<dim3(528), blk, 0, stream>>>(qi_b, ki_b, wb, idxs);
  // top-512 per row -> bitmask
  k_topk_mask<<<dim3(S_), blk, 0, stream>>>(idxs, maskw);
  // MFMA flash attention -> attn_b (aliases dead qi_b)
  k_attn_mfma<<<dim3(32, 16), blk, 0, stream>>>(qb, kvb_b, kpe_b, maskw, attn_b);
  // out = attn @ Wo
  k_tcast<<<dim3(2048 / 32, 2048 / 32), blk, 0, stream>>>(Wo, 2048, 2048, WT);
  k_gemm_bf16<<<dim3(16, 16), blk, 0, stream>>>(attn_b, 2048, WT, 2048, out, 2048, 2048, 0);

  (void)in_sizes; (void)n_in; (void)out_size; (void)ws_size;
}

// Round 6
// 577.741 us; speedup vs baseline: 8.0587x; 1.2083x over previous
//
#include <hip/hip_runtime.h>
#include <cstdint>
#include <cstddef>
#include <cmath>

typedef unsigned long long u64;
typedef __attribute__((ext_vector_type(8))) short bf16x8;   // 8 bf16 in 4 VGPRs
typedef __attribute__((ext_vector_type(4))) float f32x4;

static constexpr int S_    = 2048;
static constexpr int H_    = 2048;
static constexpr int TOPKC = 512;

#define SCALE_ATTN 0.07216878364870323f   // (192)^-0.5
#define ISCALE_ID  0.08838834764831845f   // (128)^-0.5
#define EPS_F 1e-6f

__device__ inline unsigned short f2b(float f) {
  unsigned u = __float_as_uint(f);
  return (unsigned short)((u + 0x7FFFu + ((u >> 16) & 1u)) >> 16);
}
__device__ inline float b2f(unsigned short b) {
  return __uint_as_float(((unsigned)b) << 16);
}
// async global->LDS, 16B per lane; LDS dest = wave-uniform base + lane*16
__device__ inline void gload16(const unsigned short* g, unsigned short* l) {
  __builtin_amdgcn_global_load_lds((const __attribute__((address_space(1))) void*)g,
                                   (__attribute__((address_space(3))) void*)l, 16, 0, 0);
}

// ================= bf16 MFMA GEMM: C[M,N] = A[M,K] @ Bt[N,K]^T =================
// 128x128 tile, BK=64, 4 waves. M mult of 128. Linear LDS + global_load_lds.
// OOB Bt rows (N not mult of 128) read garbage inside caller-owned scratch; epilogue masks cols.
__global__ __launch_bounds__(256) void k_gemm_bf16(
    const unsigned short* __restrict__ A, int lda,
    const unsigned short* __restrict__ Bt, int K,      // Bt pitch = K
    void* __restrict__ C, int ldc, int N, int out_bf16) {
  __shared__ unsigned short As[128 * 64];
  __shared__ unsigned short Bs[128 * 64];
  const int bm = blockIdx.y * 128, bn = blockIdx.x * 128;
  const int tid = threadIdx.x;
  const int lane = tid & 63, w = tid >> 6;
  const int wm = w >> 1, wn = w & 1;
  const int l15 = lane & 15, quarter = lane >> 4;
  const int srow = (lane >> 3), scol = (lane & 7) * 8;   // staging: 8 rows/call, 8 bf16/lane

  f32x4 acc[4][4];
#pragma unroll
  for (int i = 0; i < 4; i++)
#pragma unroll
    for (int j = 0; j < 4; j++) acc[i][j] = (f32x4){0.f, 0.f, 0.f, 0.f};

  for (int k0 = 0; k0 < K; k0 += 64) {
    __syncthreads();
#pragma unroll
    for (int i = 0; i < 4; i++) {
      int r0 = w * 32 + i * 8;
      gload16(A  + (size_t)(bm + r0 + srow) * lda + k0 + scol, &As[r0 * 64]);
      gload16(Bt + (size_t)(bn + r0 + srow) * K   + k0 + scol, &Bs[r0 * 64]);
    }
    __syncthreads();
#pragma unroll
    for (int kc = 0; kc < 2; kc++) {
      bf16x8 af[4], bfr[4];
#pragma unroll
      for (int mf = 0; mf < 4; mf++)
        af[mf] = *(const bf16x8*)(As + (wm * 64 + mf * 16 + l15) * 64 + kc * 32 + quarter * 8);
#pragma unroll
      for (int nf = 0; nf < 4; nf++)
        bfr[nf] = *(const bf16x8*)(Bs + (wn * 64 + nf * 16 + l15) * 64 + kc * 32 + quarter * 8);
#pragma unroll
      for (int mf = 0; mf < 4; mf++)
#pragma unroll
        for (int nf = 0; nf < 4; nf++)
          acc[mf][nf] = __builtin_amdgcn_mfma_f32_16x16x32_bf16(af[mf], bfr[nf], acc[mf][nf], 0, 0, 0);
    }
  }
#pragma unroll
  for (int mf = 0; mf < 4; mf++)
#pragma unroll
    for (int nf = 0; nf < 4; nf++)
#pragma unroll
      for (int r = 0; r < 4; r++) {
        int grow = bm + wm * 64 + mf * 16 + quarter * 4 + r;
        int gcol = bn + wn * 64 + nf * 16 + l15;
        if (gcol < N) {
          if (out_bf16) ((unsigned short*)C)[(size_t)grow * ldc + gcol] = f2b(acc[mf][nf][r]);
          else          ((float*)C)[(size_t)grow * ldc + gcol] = acc[mf][nf][r];
        }
      }
}

// ================= transpose + cast: Wt[n][k] = bf16(W[k][n]) =================
__global__ __launch_bounds__(256) void k_tcast(const float* __restrict__ W, int K, int N,
                                               unsigned short* __restrict__ Wt) {
  __shared__ float T[32][33];
  int n0 = blockIdx.x * 32, k0 = blockIdx.y * 32;
  int tid = threadIdx.x;
#pragma unroll
  for (int i = 0; i < 4; i++) {
    int idx = tid + 256 * i;
    int r = idx >> 5, c = idx & 31;
    T[r][c] = W[(size_t)(k0 + r) * N + n0 + c];
  }
  __syncthreads();
#pragma unroll
  for (int i = 0; i < 4; i++) {
    int idx = tid + 256 * i;
    int r = idx >> 5, c = idx & 31;
    Wt[(size_t)(n0 + r) * K + k0 + c] = f2b(T[c][r]);
  }
}

// ================= strided f32 -> bf16 cast =================
__global__ __launch_bounds__(256) void k_cast_bf16(const float* __restrict__ in, int pin,
                                                   unsigned short* __restrict__ outp, int pout,
                                                   int rows, int cols) {
  int cols4 = cols >> 2;
  int idx = blockIdx.x * 256 + threadIdx.x;
  if (idx >= rows * cols4) return;
  int r = idx / cols4, c = (idx - r * cols4) * 4;
  const float* ip = in + (size_t)r * pin + c;
  unsigned short* op = outp + (size_t)r * pout + c;
  op[0] = f2b(ip[0]); op[1] = f2b(ip[1]); op[2] = f2b(ip[2]); op[3] = f2b(ip[3]);
}

// ================= wb = hs @ Ww_idx  GEMV-style =================
__global__ __launch_bounds__(256) void k_wb(const float* __restrict__ hs, const float* __restrict__ W,
                                            float* __restrict__ wb) {
  int r0 = blockIdx.x * 8;
  int tid = threadIdx.x;
  int w = tid >> 6, lane = tid & 63;
  int h = lane & 15, kg = lane >> 4;
#pragma unroll
  for (int rr = 0; rr < 2; rr++) {
    int r = r0 + w * 2 + rr;
    const float* hp = hs + (size_t)r * 2048;
    float acc = 0.f;
    int kbeg = kg * 512, kend = kbeg + 512;
    for (int k = kbeg; k < kend; k += 4) {
      float4 hv = *(const float4*)(hp + k);
      acc = fmaf(hv.x, W[(k    ) * 16 + h], acc);
      acc = fmaf(hv.y, W[(k + 1) * 16 + h], acc);
      acc = fmaf(hv.z, W[(k + 2) * 16 + h], acc);
      acc = fmaf(hv.w, W[(k + 3) * 16 + h], acc);
    }
    acc += __shfl_xor(acc, 16);
    acc += __shfl_xor(acc, 32);
    if (kg == 0) wb[(size_t)r * 16 + h] = acc;
  }
}

// ================= RMSNorm in-place =================
__global__ __launch_bounds__(256) void k_rmsnorm(float* __restrict__ x, const float* __restrict__ gamma,
                                                 int rowstride, int n) {
  int r = blockIdx.x;
  float* p = x + (size_t)r * rowstride;
  __shared__ float red[256];
  float s = 0.f;
  for (int i = threadIdx.x; i < n; i += 256) { float v = p[i]; s += v * v; }
  red[threadIdx.x] = s; __syncthreads();
  for (int st = 128; st > 0; st >>= 1) { if (threadIdx.x < st) red[threadIdx.x] += red[threadIdx.x + st]; __syncthreads(); }
  float scl = rsqrtf(red[0] / (float)n + EPS_F);
  for (int i = threadIdx.x; i < n; i += 256) p[i] = p[i] * scl * gamma[i];
}

// ================= RoPE in-place (f32) =================
__global__ __launch_bounds__(256) void k_rope(float* __restrict__ base, int rowstride, int nh, int hstride,
                                              int off, const float* __restrict__ cosb, const float* __restrict__ sinb,
                                              int total) {
  int idx = blockIdx.x * 256 + threadIdx.x;
  if (idx >= total) return;
  int i = idx & 31, h = (idx >> 5) % nh, t = idx / (32 * nh);
  float* p = base + (size_t)t * rowstride + h * hstride + off;
  float x1 = p[i], x2 = p[i + 32];
  float c = cosb[t * 32 + i], s = sinb[t * 32 + i];
  p[i] = x1 * c - x2 * s;
  p[i + 32] = x1 * s + x2 * c;
}

// ================= RoPE in-place (bf16) =================
__global__ __launch_bounds__(256) void k_rope_b(unsigned short* __restrict__ base, int rowstride, int nh,
                                                int hstride, int off, const float* __restrict__ cosb,
                                                const float* __restrict__ sinb, int total) {
  int idx = blockIdx.x * 256 + threadIdx.x;
  if (idx >= total) return;
  int i = idx & 31, h = (idx >> 5) % nh, t = idx / (32 * nh);
  unsigned short* p = base + (size_t)t * rowstride + h * hstride + off;
  float x1 = b2f(p[i]), x2 = b2f(p[i + 32]);
  float c = cosb[t * 32 + i], s = sinb[t * 32 + i];
  p[i] = f2b(x1 * c - x2 * s);
  p[i + 32] = f2b(x1 * s + x2 * c);
}

// ================= ki: LayerNorm(128) + RoPE on first 64, in-place, strided =================
__global__ __launch_bounds__(128) void k_ki_ln_rope(float* __restrict__ ki, int stride,
                                                    const float* __restrict__ g,
                                                    const float* __restrict__ b,
                                                    const float* __restrict__ cosb, const float* __restrict__ sinb) {
  int t = blockIdx.x, i = threadIdx.x;
  float* p = ki + (size_t)t * stride;
  __shared__ float red[128];
  __shared__ float buf[128];
  float v = p[i];
  red[i] = v; __syncthreads();
  for (int st = 64; st > 0; st >>= 1) { if (i < st) red[i] += red[i + st]; __syncthreads(); }
  float mean = red[0] * (1.f / 128.f);
  __syncthreads();
  float d = v - mean;
  red[i] = d * d; __syncthreads();
  for (int st = 64; st > 0; st >>= 1) { if (i < st) red[i] += red[i + st]; __syncthreads(); }
  float var = red[0] * (1.f / 128.f);
  float y = d * rsqrtf(var + EPS_F) * g[i] + b[i];
  buf[i] = y; __syncthreads();
  float outv;
  if (i < 32) {
    float c = cosb[t * 32 + i], s = sinb[t * 32 + i];
    outv = buf[i] * c - buf[i + 32] * s;
  } else if (i < 64) {
    int j = i - 32;
    float c = cosb[t * 32 + j], s = sinb[t * 32 + j];
    outv = buf[j] * s + buf[i] * c;
  } else outv = y;
  p[i] = outv;
}

// ================= indexer scores via MFMA: 64x64 causal tiles, double-buffered Q =================
__global__ __launch_bounds__(256) void k_idx_mfma(
    const unsigned short* __restrict__ qi_b, int qpitch,
    const unsigned short* __restrict__ ki_b,  // [S][128] bf16
    const float* __restrict__ wb,             // [S][16]  f32
    float* __restrict__ out) {                // [S][2048] f32
  int bid = blockIdx.x;
  int tb = (int)((sqrtf(8.f * bid + 1.f) - 1.f) * 0.5f);
  while ((tb + 1) * (tb + 2) / 2 <= bid) tb++;
  while (tb * (tb + 1) / 2 > bid) tb--;
  int sb = bid - tb * (tb + 1) / 2;
  int t0 = tb * 64, s0 = sb * 64;

  int tid = threadIdx.x, lane = tid & 63, w = tid >> 6;
  int wm = w >> 1, wn = w & 1;
  int l15 = lane & 15, quarter = lane >> 4;
  const int srow = lane >> 4, scol = (lane & 15) * 8;  // staging: 4 rows/call

  __shared__ unsigned short Ks[64 * 128];
  __shared__ unsigned short Qs[2][64 * 128];
  __shared__ float Ws[64][16];

#pragma unroll
  for (int i = 0; i < 4; i++) {
    int r0 = w * 16 + i * 4;
    gload16(ki_b + (size_t)(s0 + r0 + srow) * 128 + scol, &Ks[r0 * 128]);
    gload16(qi_b + (size_t)(t0 + r0 + srow) * qpitch + scol, &Qs[0][r0 * 128]);
  }
  for (int i = tid; i < 64 * 16; i += 256) Ws[i >> 4][i & 15] = wb[(size_t)(t0 + (i >> 4)) * 16 + (i & 15)];
  __syncthreads();

  bf16x8 bfr[2][4];
#pragma unroll
  for (int nf = 0; nf < 2; nf++)
#pragma unroll
    for (int kc = 0; kc < 4; kc++)
      bfr[nf][kc] = *(const bf16x8*)(Ks + (wn * 32 + nf * 16 + l15) * 128 + kc * 32 + quarter * 8);

  f32x4 acc[2][2];
#pragma unroll
  for (int mf = 0; mf < 2; mf++)
#pragma unroll
    for (int nf = 0; nf < 2; nf++) acc[mf][nf] = (f32x4){0.f, 0.f, 0.f, 0.f};

  for (int h = 0; h < 16; h++) {
    int cur = h & 1;
    if (h < 15) {   // prefetch next head while computing this one
#pragma unroll
      for (int i = 0; i < 4; i++) {
        int r0 = w * 16 + i * 4;
        gload16(qi_b + (size_t)(t0 + r0 + srow) * qpitch + (h + 1) * 128 + scol, &Qs[cur ^ 1][r0 * 128]);
      }
    }
    f32x4 acch[2][2];
#pragma unroll
    for (int mf = 0; mf < 2; mf++)
#pragma unroll
      for (int nf = 0; nf < 2; nf++) acch[mf][nf] = (f32x4){0.f, 0.f, 0.f, 0.f};

#pragma unroll
    for (int mf = 0; mf < 2; mf++) {
      bf16x8 af[4];
#pragma unroll
      for (int kc = 0; kc < 4; kc++)
        af[kc] = *(const bf16x8*)(Qs[cur] + (wm * 32 + mf * 16 + l15) * 128 + kc * 32 + quarter * 8);
#pragma unroll
      for (int nf = 0; nf < 2; nf++)
#pragma unroll
        for (int kc = 0; kc < 4; kc++)
          acch[mf][nf] = __builtin_amdgcn_mfma_f32_16x16x32_bf16(af[kc], bfr[nf][kc], acch[mf][nf], 0, 0, 0);
    }
#pragma unroll
    for (int mf = 0; mf < 2; mf++) {
#pragma unroll
      for (int r = 0; r < 4; r++) {
        float wv = Ws[wm * 32 + mf * 16 + quarter * 4 + r][h];
#pragma unroll
        for (int nf = 0; nf < 2; nf++)
          acc[mf][nf][r] = fmaf(wv, fmaxf(acch[mf][nf][r], 0.f), acc[mf][nf][r]);
      }
    }
    __syncthreads();   // waits prefetch (vmcnt) + guards Qs[cur] overwrite next iter
  }
#pragma unroll
  for (int mf = 0; mf < 2; mf++)
#pragma unroll
    for (int nf = 0; nf < 2; nf++)
#pragma unroll
      for (int r = 0; r < 4; r++) {
        int t = t0 + wm * 32 + mf * 16 + quarter * 4 + r;
        int s = s0 + wn * 32 + nf * 16 + l15;
        out[(size_t)t * 2048 + s] = acc[mf][nf][r] * ISCALE_ID;
      }
}

// ================= per-row top-K -> bitmask =================
__global__ __launch_bounds__(256) void k_topk_mask(const float* __restrict__ idx_sc, u64* __restrict__ maskw) {
  int t = blockIdx.x;
  int tid = threadIdx.x;
  int n = t + 1;
  if (n <= TOPKC) {
    if (tid < 32) {
      int lo = tid * 64, hi = lo + 63;
      u64 wv;
      if (t >= hi) wv = ~0ULL;
      else if (t < lo) wv = 0ULL;
      else wv = (~0ULL) >> (63 - (t - lo));
      maskw[(size_t)t * 32 + tid] = wv;
    }
    return;
  }
  __shared__ unsigned int u[2048];
  __shared__ int hist[256];
  __shared__ u64 mw[32];
  __shared__ int sel_b, new_target, tie_base;
  __shared__ int wcnt[4];
  if (tid < 32) mw[tid] = 0ULL;
  const float* row = idx_sc + (size_t)t * 2048;
  for (int s = tid; s < n; s += 256) {
    unsigned int bb = __float_as_uint(row[s]);
    u[s] = (bb & 0x80000000u) ? ~bb : (bb | 0x80000000u);
  }
  __syncthreads();
  unsigned int prefix = 0;
  int target = TOPKC;
  for (int shift = 24; shift >= 0; shift -= 8) {
    hist[tid] = 0;
    __syncthreads();
    unsigned int himask = (shift == 24) ? 0u : (0xFFFFFFFFu << (shift + 8));
    for (int s = tid; s < n; s += 256) {
      unsigned int uv = u[s];
      if ((uv & himask) == prefix) atomicAdd(&hist[(uv >> shift) & 0xFF], 1);
    }
    __syncthreads();
    if (tid == 0) {
      int cum = 0, b = 255;
      for (; b > 0; b--) {
        if (cum + hist[b] >= target) break;
        cum += hist[b];
      }
      sel_b = b;
      new_target = target - cum;
    }
    __syncthreads();
    prefix |= ((unsigned int)sel_b) << shift;
    target = new_target;
    __syncthreads();
  }
  if (tid == 0) tie_base = 0;
  __syncthreads();
  int wid = tid >> 6, lane = tid & 63;
  for (int s0 = 0; s0 < n; s0 += 256) {
    int s = s0 + tid;
    bool in = (s < n);
    unsigned int uv = in ? u[s] : 0u;
    bool gt = in && (uv > prefix);
    bool tie = in && (uv == prefix);
    u64 bal = __ballot(tie);
    if (lane == 0) wcnt[wid] = __popcll(bal);
    __syncthreads();
    int wbase = tie_base;
    for (int wI = 0; wI < wid; wI++) wbase += wcnt[wI];
    int rank = wbase + __popcll(bal & ((1ULL << lane) - 1ULL));
    bool sel = gt || (tie && rank < target);
    if (sel) atomicOr(&mw[s >> 6], 1ULL << (s & 63));
    __syncthreads();
    if (tid == 0) tie_base += wcnt[0] + wcnt[1] + wcnt[2] + wcnt[3];
    __syncthreads();
  }
  if (tid < 32) maskw[(size_t)t * 32 + tid] = mw[tid];
}

// ================= MFMA flash attention: 64-KV tiles, swapped QK^T, in-register P =================
__global__ __launch_bounds__(256) void k_attn_mfma(
    const unsigned short* __restrict__ qb, int qpitch,  // roped q, head h at h*192
    const unsigned short* __restrict__ kvb_b,  // [S][4096] bf16: k_nope@h*256, v@h*256+128
    const unsigned short* __restrict__ kpe_b,  // [S][64]   bf16, roped
    const u64* __restrict__ maskw,             // [S][32]
    unsigned short* __restrict__ attn_b) {     // [S][2048] bf16
  int ybm = blockIdx.x;                        // 0..31
  int h = blockIdx.y;                          // 0..15
  int yb = (h < 8) ? ybm : (31 - ybm);         // blocks b and b+256 share a CU -> complementary work
  int t0 = yb * 64;
  int tid = threadIdx.x;
  int lane = tid & 63, wq = tid >> 6;
  int quarter = lane >> 4, l15 = lane & 15;

  __shared__ unsigned short Ks[64 * 192];   // pitch 384B, swz ((r&7)<<4)
  __shared__ unsigned short Vts[128 * 64];  // V^T u32-pairs, pitch 128B, swz (((d>>2)&7)<<4)

  bf16x8 qf[6];
  {
    const unsigned short* qp = qb + (size_t)(t0 + wq * 16 + l15) * qpitch + h * 192 + quarter * 8;
#pragma unroll
    for (int kc = 0; kc < 6; kc++) qf[kc] = *(const bf16x8*)(qp + kc * 32);
  }
  f32x4 o[8];
#pragma unroll
  for (int df = 0; df < 8; df++) o[df] = (f32x4){0.f, 0.f, 0.f, 0.f};
  float mcol = -__builtin_inff(), lcol = 0.f;  // column state for t = t0+wq*16+l15
  const u64* mrow = maskw + (size_t)(t0 + wq * 16 + l15) * 32;

  int nsb = yb + 1;
  for (int sb = 0; sb < nsb; sb++) {
    int s0 = sb * 64;
    __syncthreads();
    // K stage: 64 rows x (16 nope + 8 pe) 16B chunks, swizzled
#pragma unroll
    for (int i = 0; i < 6; i++) {
      int c = tid + 256 * i;
      int row = c / 24, cc = c - row * 24;
      bf16x8 v;
      if (cc < 16) v = *(const bf16x8*)(kvb_b + (size_t)(s0 + row) * 4096 + h * 256 + cc * 8);
      else         v = *(const bf16x8*)(kpe_b + (size_t)(s0 + row) * 64 + (cc - 16) * 8);
      int byte = row * 384 + ((cc * 16) ^ ((row & 7) << 4));
      *(bf16x8*)((char*)Ks + byte) = v;
    }
    // V^T stage: thread (dg, sp) loads 4 rows, writes b64 packed pairs
    {
      int dg = tid & 15, sp = tid >> 4;
      const unsigned short* vp = kvb_b + (size_t)(s0 + sp * 4) * 4096 + h * 256 + 128 + dg * 8;
      bf16x8 v0 = *(const bf16x8*)vp;
      bf16x8 v1 = *(const bf16x8*)(vp + 4096);
      bf16x8 v2 = *(const bf16x8*)(vp + 8192);
      bf16x8 v3 = *(const bf16x8*)(vp + 12288);
#pragma unroll
      for (int j = 0; j < 8; j++) {
        int d = dg * 8 + j;
        uint2 w2;
        w2.x = (unsigned)(unsigned short)v0[j] | (((unsigned)(unsigned short)v1[j]) << 16);
        w2.y = (unsigned)(unsigned short)v2[j] | (((unsigned)(unsigned short)v3[j]) << 16);
        int byte = d * 128 + ((sp * 8) ^ (((d >> 2) & 7) << 4));
        *(uint2*)((char*)Vts + byte) = w2;
      }
    }
    __syncthreads();

    // swapped QK^T: S^T = mfma(K, Q); lane holds S[t=l15-col][s0 + sc*16 + quarter*4 + r]
    f32x4 sfT[4];
#pragma unroll
    for (int sc = 0; sc < 4; sc++) {
      f32x4 a = (f32x4){0.f, 0.f, 0.f, 0.f};
      int row = sc * 16 + l15;
      int rx = (row & 7) << 4;
#pragma unroll
      for (int kc = 0; kc < 6; kc++) {
        int byte = row * 384 + ((kc * 64 + quarter * 16) ^ rx);
        bf16x8 kf = *(const bf16x8*)((const char*)Ks + byte);
        a = __builtin_amdgcn_mfma_f32_16x16x32_bf16(kf, qf[kc], a, 0, 0, 0);
      }
      sfT[sc] = a;
    }
    u64 w64 = mrow[s0 >> 6];
    float p[4][4];
#pragma unroll
    for (int sc = 0; sc < 4; sc++)
#pragma unroll
      for (int r = 0; r < 4; r++) {
        int sbit = sc * 16 + quarter * 4 + r;
        bool sel = (w64 >> sbit) & 1ULL;
        p[sc][r] = sel ? sfT[sc][r] * SCALE_ATTN : -__builtin_inff();
      }
    // column softmax: 15 in-lane max + 2 shfl
    float v = p[0][0];
#pragma unroll
    for (int sc = 0; sc < 4; sc++)
#pragma unroll
      for (int r = 0; r < 4; r++) v = fmaxf(v, p[sc][r]);
    v = fmaxf(v, __shfl_xor(v, 16));
    v = fmaxf(v, __shfl_xor(v, 32));
    float mn = fmaxf(mcol, v);
    bool dead = (mn == -__builtin_inff());
    float scl = dead ? 1.f : __expf(mcol - mn);
#pragma unroll
    for (int sc = 0; sc < 4; sc++)
#pragma unroll
      for (int r = 0; r < 4; r++)
        p[sc][r] = dead ? 0.f : __expf(p[sc][r] - mn);
    mcol = dead ? mcol : mn;
    float rs = 0.f;
#pragma unroll
    for (int sc = 0; sc < 4; sc++)
#pragma unroll
      for (int r = 0; r < 4; r++) rs += p[sc][r];
    rs += __shfl_xor(rs, 16);
    rs += __shfl_xor(rs, 32);
    lcol = lcol * scl + rs;

    // pack P -> bf16 pairs, redistribute to PV A-fragments (2 kc halves)
    unsigned pk[4][2];
#pragma unroll
    for (int sc = 0; sc < 4; sc++)
#pragma unroll
      for (int rr = 0; rr < 2; rr++)
        pk[sc][rr] = (unsigned)f2b(p[sc][2 * rr]) | (((unsigned)f2b(p[sc][2 * rr + 1])) << 16);
    bf16x8 pa[2];
#pragma unroll
    for (int kc = 0; kc < 2; kc++) {
      union { unsigned d[4]; bf16x8 v; } pu;
#pragma unroll
      for (int jj = 0; jj < 4; jj++) {
        int src = ((quarter & 1) * 2 + (jj >> 1)) * 16 + l15;
        unsigned lo = (unsigned)__shfl((int)pk[kc * 2][jj & 1], src);
        unsigned hi = (unsigned)__shfl((int)pk[kc * 2 + 1][jj & 1], src);
        pu.d[jj] = (quarter < 2) ? lo : hi;
      }
      pa[kc] = pu.v;
    }
    // rescale O (row t-local = quarter*4+r takes scl from lane l15=quarter*4+r)
    float sclr[4];
#pragma unroll
    for (int r = 0; r < 4; r++) sclr[r] = __shfl(scl, quarter * 4 + r);
#pragma unroll
    for (int df = 0; df < 8; df++)
#pragma unroll
      for (int r = 0; r < 4; r++) o[df][r] *= sclr[r];
    // PV: 2 kc halves x 8 d-frags
#pragma unroll
    for (int kc = 0; kc < 2; kc++)
#pragma unroll
      for (int df = 0; df < 8; df++) {
        int d = df * 16 + l15;
        int vbyte = d * 128 + ((kc * 64 + quarter * 16) ^ (((d >> 2) & 7) << 4));
        bf16x8 vf = *(const bf16x8*)((const char*)Vts + vbyte);
        o[df] = __builtin_amdgcn_mfma_f32_16x16x32_bf16(pa[kc], vf, o[df], 0, 0, 0);
      }
  }
  float inv = (lcol > 0.f) ? 1.f / lcol : 0.f;
  float invr[4];
#pragma unroll
  for (int r = 0; r < 4; r++) invr[r] = __shfl(inv, quarter * 4 + r);
#pragma unroll
  for (int r = 0; r < 4; r++) {
    int t = t0 + wq * 16 + quarter * 4 + r;
    unsigned short* op = attn_b + (size_t)t * 2048 + h * 128 + l15;
#pragma unroll
    for (int df = 0; df < 8; df++) op[df * 16] = f2b(o[df][r] * invr[r]);
  }
}

// ================= host launch =================
extern "C" void kernel_launch(void* const* d_in, const int* in_sizes, int n_in,
                              void* d_out, int out_size, void* d_ws, size_t ws_size,
                              hipStream_t stream) {
  const float* hs     = (const float*)d_in[0];
  const float* cosb   = (const float*)d_in[1];
  const float* sinb   = (const float*)d_in[2];
  const float* Wq_a   = (const float*)d_in[3];
  const float* q_a_g  = (const float*)d_in[4];
  const float* Wq_b   = (const float*)d_in[5];
  const float* Wkv_a  = (const float*)d_in[6];
  const float* kv_a_g = (const float*)d_in[7];
  const float* Wkv_b  = (const float*)d_in[8];
  const float* Wo     = (const float*)d_in[9];
  const float* Wq_idx = (const float*)d_in[10];
  const float* Wk_idx = (const float*)d_in[11];
  const float* Ww_idx = (const float*)d_in[12];
  const float* kn_g   = (const float*)d_in[13];
  const float* kn_b   = (const float*)d_in[14];
  float* out = (float*)d_out;

  char* base = (char*)d_ws;
  size_t off = 0;
  auto alloc = [&](size_t bytes) { void* p = base + off; off += (bytes + 255) & ~size_t(255); return p; };

  // fat1 f32 [2048][2304]: qa(0..1535) | kv(1536..2111: c 512 + pe 64) | ki(2112..2239)
  // after consumption: reused as idxs (f32 16MB), then attn_b (bf16 8.4MB)
  float* fat1 = (float*)alloc((size_t)S_ * 2304 * 4);
  float* idxs = fat1;
  unsigned short* attn_b = (unsigned short*)fat1;
  // fat2 bf16 [2048][5120]: qb(0..3071) | qi(3072..5119)
  unsigned short* fat2 = (unsigned short*)alloc((size_t)S_ * 5120 * 2);
  float* wb    = (float*)alloc((size_t)S_ * 16 * 4);
  u64*   maskw = (u64*)alloc((size_t)S_ * 32 * 8);
  unsigned short* hs_b  = (unsigned short*)alloc((size_t)S_ * 2048 * 2);
  unsigned short* qa_b  = (unsigned short*)alloc((size_t)S_ * 1536 * 2);
  unsigned short* kvc_b = (unsigned short*)alloc((size_t)S_ * 512 * 2);
  unsigned short* kpe_b = (unsigned short*)alloc((size_t)S_ * 64 * 2);
  unsigned short* kvb_b = (unsigned short*)alloc((size_t)S_ * 4096 * 2);
  unsigned short* ki_b  = (unsigned short*)alloc((size_t)S_ * 128 * 2);
  unsigned short* WT    = (unsigned short*)alloc((size_t)5120 * 1536 * 2);  // JIT weight^T scratch

  dim3 blk(256);

  // hs -> bf16
  k_cast_bf16<<<dim3((S_ * 2048 / 4) / 256), blk, 0, stream>>>(hs, 2048, hs_b, 2048, S_, 2048);
  // fused hs-GEMM: [Wq_a | Wkv_a | Wk_idx], K=2048, N=2240 (grid covers 2304, masked)
  k_tcast<<<dim3(1536 / 32, 2048 / 32), blk, 0, stream>>>(Wq_a, 2048, 1536, WT);
  k_tcast<<<dim3(576 / 32, 2048 / 32), blk, 0, stream>>>(Wkv_a, 2048, 576, WT + (size_t)1536 * 2048);
  k_tcast<<<dim3(128 / 32, 2048 / 32), blk, 0, stream>>>(Wk_idx, 2048, 128, WT + (size_t)2112 * 2048);
  k_gemm_bf16<<<dim3(18, 16), blk, 0, stream>>>(hs_b, 2048, WT, 2048, fat1, 2304, 2240, 0);
  // norms + ropes on fat1 slices
  k_rmsnorm<<<dim3(S_), blk, 0, stream>>>(fat1, q_a_g, 2304, 1536);
  k_rmsnorm<<<dim3(S_), blk, 0, stream>>>(fat1 + 1536, kv_a_g, 2304, 512);
  k_rope<<<dim3((S_ * 32) / 256), blk, 0, stream>>>(fat1 + 1536, 2304, 1, 0, 512, cosb, sinb, S_ * 32);
  k_ki_ln_rope<<<dim3(S_), dim3(128), 0, stream>>>(fat1 + 2112, 2304, kn_g, kn_b, cosb, sinb);
  // casts out of fat1
  k_cast_bf16<<<dim3((S_ * 1536 / 4) / 256), blk, 0, stream>>>(fat1, 2304, qa_b, 1536, S_, 1536);
  k_cast_bf16<<<dim3((S_ * 512 / 4) / 256), blk, 0, stream>>>(fat1 + 1536, 2304, kvc_b, 512, S_, 512);
  k_cast_bf16<<<dim3((S_ * 64 / 4) / 256), blk, 0, stream>>>(fat1 + 2048, 2304, kpe_b, 64, S_, 64);
  k_cast_bf16<<<dim3((S_ * 128 / 4) / 256), blk, 0, stream>>>(fat1 + 2112, 2304, ki_b, 128, S_, 128);
  // w = hs @ Ww_idx
  k_wb<<<dim3(S_ / 8), blk, 0, stream>>>(hs, Ww_idx, wb);
  // fused qa-GEMM: [Wq_b | Wq_idx], K=1536, N=5120 -> fat2 bf16
  k_tcast<<<dim3(3072 / 32, 1536 / 32), blk, 0, stream>>>(Wq_b, 1536, 3072, WT);
  k_tcast<<<dim3(2048 / 32, 1536 / 32), blk, 0, stream>>>(Wq_idx, 1536, 2048, WT + (size_t)3072 * 1536);
  k_gemm_bf16<<<dim3(40, 16), blk, 0, stream>>>(qa_b, 1536, WT, 1536, fat2, 5120, 5120, 1);
  k_rope_b<<<dim3((S_ * 16 * 32) / 256), blk, 0, stream>>>(fat2, 5120, 16, 192, 128, cosb, sinb, S_ * 16 * 32);
  k_rope_b<<<dim3((S_ * 16 * 32) / 256), blk, 0, stream>>>(fat2 + 3072, 5120, 16, 128, 0, cosb, sinb, S_ * 16 * 32);
  // kvb = kv_c @ Wkv_b (bf16 out)
  k_tcast<<<dim3(4096 / 32, 512 / 32), blk, 0, stream>>>(Wkv_b, 512, 4096, WT);
  k_gemm_bf16<<<dim3(32, 16), blk, 0, stream>>>(kvc_b, 512, WT, 512, kvb_b, 4096, 4096, 1);
  // indexer scores (triangular grid) -> idxs (aliases fat1, fully consumed above)
  k_idx_mfma<<<dim3(528), blk, 0, stream>>>(fat2 + 3072, 5120, ki_b, wb, idxs);
  // top-512 per row -> bitmask
  k_topk_mask<<<dim3(S_), blk, 0, stream>>>(idxs, maskw);
  // MFMA flash attention -> attn_b (aliases fat1; idxs dead after topk)
  k_attn_mfma<<<dim3(32, 16), blk, 0, stream>>>(fat2, 5120, kvb_b, kpe_b, maskw, attn_b);
  // out = attn @ Wo
  k_tcast<<<dim3(2048 / 32, 2048 / 32), blk, 0, stream>>>(Wo, 2048, 2048, WT);
  k_gemm_bf16<<<dim3(16, 16), blk, 0, stream>>>(attn_b, 2048, WT, 2048, out, 2048, 2048, 0);

  (void)in_sizes; (void)n_in; (void)out_size; (void)ws_size;
}

// Round 7
// 450.287 us; speedup vs baseline: 10.3397x; 1.2831x over previous
//
#include <hip/hip_runtime.h>
#include <cstdint>
#include <cstddef>
#include <cmath>

typedef unsigned long long u64;
typedef __attribute__((ext_vector_type(8))) short bf16x8;   // 8 bf16 in 4 VGPRs
typedef __attribute__((ext_vector_type(4))) float f32x4;

static constexpr int S_    = 2048;
static constexpr int H_    = 2048;
static constexpr int TOPKC = 512;

#define SCALE_ATTN 0.07216878364870323f   // (192)^-0.5
#define ISCALE_ID  0.08838834764831845f   // (128)^-0.5
#define EPS_F 1e-6f

__device__ inline unsigned short f2b(float f) {
  unsigned u = __float_as_uint(f);
  return (unsigned short)((u + 0x7FFFu + ((u >> 16) & 1u)) >> 16);
}
__device__ inline float b2f(unsigned short b) {
  return __uint_as_float(((unsigned)b) << 16);
}
// async global->LDS, 16B per lane; LDS dest = wave-uniform base + lane*16, global src per-lane
__device__ inline void gload16(const unsigned short* g, unsigned short* l) {
  __builtin_amdgcn_global_load_lds((const __attribute__((address_space(1))) void*)g,
                                   (__attribute__((address_space(3))) void*)l, 16, 0, 0);
}

// ================= bf16 MFMA GEMM: C[M,N] = A[M,K] @ Bt[N,K]^T =================
// 128x128 tile, BK=64, 4 waves. M mult of 128. Linear LDS + global_load_lds (m97 structure).
__global__ __launch_bounds__(256) void k_gemm_bf16(
    const unsigned short* __restrict__ A, int lda,
    const unsigned short* __restrict__ Bt, int K,      // Bt pitch = K
    void* __restrict__ C, int ldc, int N, int out_bf16) {
  __shared__ unsigned short As[128 * 64];
  __shared__ unsigned short Bs[128 * 64];
  const int bm = blockIdx.y * 128, bn = blockIdx.x * 128;
  const int tid = threadIdx.x;
  const int lane = tid & 63, w = tid >> 6;
  const int wm = w >> 1, wn = w & 1;
  const int l15 = lane & 15, quarter = lane >> 4;
  const int srow = (lane >> 3), scol = (lane & 7) * 8;

  f32x4 acc[4][4];
#pragma unroll
  for (int i = 0; i < 4; i++)
#pragma unroll
    for (int j = 0; j < 4; j++) acc[i][j] = (f32x4){0.f, 0.f, 0.f, 0.f};

  for (int k0 = 0; k0 < K; k0 += 64) {
    __syncthreads();
#pragma unroll
    for (int i = 0; i < 4; i++) {
      int r0 = w * 32 + i * 8;
      gload16(A  + (size_t)(bm + r0 + srow) * lda + k0 + scol, &As[r0 * 64]);
      gload16(Bt + (size_t)(bn + r0 + srow) * K   + k0 + scol, &Bs[r0 * 64]);
    }
    __syncthreads();
#pragma unroll
    for (int kc = 0; kc < 2; kc++) {
      bf16x8 af[4], bfr[4];
#pragma unroll
      for (int mf = 0; mf < 4; mf++)
        af[mf] = *(const bf16x8*)(As + (wm * 64 + mf * 16 + l15) * 64 + kc * 32 + quarter * 8);
#pragma unroll
      for (int nf = 0; nf < 4; nf++)
        bfr[nf] = *(const bf16x8*)(Bs + (wn * 64 + nf * 16 + l15) * 64 + kc * 32 + quarter * 8);
#pragma unroll
      for (int mf = 0; mf < 4; mf++)
#pragma unroll
        for (int nf = 0; nf < 4; nf++)
          acc[mf][nf] = __builtin_amdgcn_mfma_f32_16x16x32_bf16(af[mf], bfr[nf], acc[mf][nf], 0, 0, 0);
    }
  }
#pragma unroll
  for (int mf = 0; mf < 4; mf++)
#pragma unroll
    for (int nf = 0; nf < 4; nf++)
#pragma unroll
      for (int r = 0; r < 4; r++) {
        int grow = bm + wm * 64 + mf * 16 + quarter * 4 + r;
        int gcol = bn + wn * 64 + nf * 16 + l15;
        if (gcol < N) {
          if (out_bf16) ((unsigned short*)C)[(size_t)grow * ldc + gcol] = f2b(acc[mf][nf][r]);
          else          ((float*)C)[(size_t)grow * ldc + gcol] = acc[mf][nf][r];
        }
      }
}

// ================= transpose + cast: Wt[n][k] = bf16(W[k][n]) =================
__global__ __launch_bounds__(256) void k_tcast(const float* __restrict__ W, int K, int N,
                                               unsigned short* __restrict__ Wt) {
  __shared__ float T[32][33];
  int n0 = blockIdx.x * 32, k0 = blockIdx.y * 32;
  int tid = threadIdx.x;
#pragma unroll
  for (int i = 0; i < 4; i++) {
    int idx = tid + 256 * i;
    int r = idx >> 5, c = idx & 31;
    T[r][c] = W[(size_t)(k0 + r) * N + n0 + c];
  }
  __syncthreads();
#pragma unroll
  for (int i = 0; i < 4; i++) {
    int idx = tid + 256 * i;
    int r = idx >> 5, c = idx & 31;
    Wt[(size_t)(n0 + r) * K + k0 + c] = f2b(T[c][r]);
  }
}

// ================= strided f32 -> bf16 cast =================
__global__ __launch_bounds__(256) void k_cast_bf16(const float* __restrict__ in, int pin,
                                                   unsigned short* __restrict__ outp, int pout,
                                                   int rows, int cols) {
  int cols4 = cols >> 2;
  int idx = blockIdx.x * 256 + threadIdx.x;
  if (idx >= rows * cols4) return;
  int r = idx / cols4, c = (idx - r * cols4) * 4;
  const float* ip = in + (size_t)r * pin + c;
  unsigned short* op = outp + (size_t)r * pout + c;
  op[0] = f2b(ip[0]); op[1] = f2b(ip[1]); op[2] = f2b(ip[2]); op[3] = f2b(ip[3]);
}

// ================= wb = hs @ Ww_idx  GEMV-style =================
__global__ __launch_bounds__(256) void k_wb(const float* __restrict__ hs, const float* __restrict__ W,
                                            float* __restrict__ wb) {
  int r0 = blockIdx.x * 8;
  int tid = threadIdx.x;
  int w = tid >> 6, lane = tid & 63;
  int h = lane & 15, kg = lane >> 4;
#pragma unroll
  for (int rr = 0; rr < 2; rr++) {
    int r = r0 + w * 2 + rr;
    const float* hp = hs + (size_t)r * 2048;
    float acc = 0.f;
    int kbeg = kg * 512, kend = kbeg + 512;
    for (int k = kbeg; k < kend; k += 4) {
      float4 hv = *(const float4*)(hp + k);
      acc = fmaf(hv.x, W[(k    ) * 16 + h], acc);
      acc = fmaf(hv.y, W[(k + 1) * 16 + h], acc);
      acc = fmaf(hv.z, W[(k + 2) * 16 + h], acc);
      acc = fmaf(hv.w, W[(k + 3) * 16 + h], acc);
    }
    acc += __shfl_xor(acc, 16);
    acc += __shfl_xor(acc, 32);
    if (kg == 0) wb[(size_t)r * 16 + h] = acc;
  }
}

// ================= RMSNorm + bf16 cast (separate dst) =================
__global__ __launch_bounds__(256) void k_rmsnorm_cast(
    const float* __restrict__ x, int stride, const float* __restrict__ gamma,
    unsigned short* __restrict__ outp, int n) {
  int r = blockIdx.x;
  const float* p = x + (size_t)r * stride;
  __shared__ float red[256];
  float s = 0.f;
  for (int i = threadIdx.x; i < n; i += 256) { float v = p[i]; s += v * v; }
  red[threadIdx.x] = s; __syncthreads();
  for (int st = 128; st > 0; st >>= 1) { if (threadIdx.x < st) red[threadIdx.x] += red[threadIdx.x + st]; __syncthreads(); }
  float scl = rsqrtf(red[0] / (float)n + EPS_F);
  unsigned short* op = outp + (size_t)r * n;
  for (int i = threadIdx.x; i < n; i += 256) op[i] = f2b(p[i] * scl * gamma[i]);
}

// ================= kv: RMSNorm(512)->kvc_b, rope(64)->kpe_b, one pass =================
__global__ __launch_bounds__(256) void k_kvfuse(
    const float* __restrict__ fat, int stride, const float* __restrict__ gamma,
    const float* __restrict__ cosb, const float* __restrict__ sinb,
    unsigned short* __restrict__ kvc_b, unsigned short* __restrict__ kpe_b) {
  int t = blockIdx.x, tid = threadIdx.x;
  const float* p = fat + (size_t)t * stride;
  __shared__ float red[256];
  float x0 = p[tid], x1 = p[tid + 256];
  red[tid] = x0 * x0 + x1 * x1; __syncthreads();
  for (int st = 128; st > 0; st >>= 1) { if (tid < st) red[tid] += red[tid + st]; __syncthreads(); }
  float scl = rsqrtf(red[0] * (1.f / 512.f) + EPS_F);
  kvc_b[(size_t)t * 512 + tid]       = f2b(x0 * scl * gamma[tid]);
  kvc_b[(size_t)t * 512 + tid + 256] = f2b(x1 * scl * gamma[tid + 256]);
  if (tid < 32) {
    float a = p[512 + tid], b = p[544 + tid];
    float c = cosb[t * 32 + tid], s = sinb[t * 32 + tid];
    kpe_b[(size_t)t * 64 + tid]      = f2b(a * c - b * s);
    kpe_b[(size_t)t * 64 + 32 + tid] = f2b(a * s + b * c);
  }
}

// ================= ki: LayerNorm(128) + RoPE(first 64) -> bf16 =================
__global__ __launch_bounds__(128) void k_ki_ln_rope_cast(
    const float* __restrict__ ki, int stride,
    const float* __restrict__ g, const float* __restrict__ b,
    const float* __restrict__ cosb, const float* __restrict__ sinb,
    unsigned short* __restrict__ ko) {
  int t = blockIdx.x, i = threadIdx.x;
  const float* p = ki + (size_t)t * stride;
  __shared__ float red[128];
  __shared__ float buf[128];
  float v = p[i];
  red[i] = v; __syncthreads();
  for (int st = 64; st > 0; st >>= 1) { if (i < st) red[i] += red[i + st]; __syncthreads(); }
  float mean = red[0] * (1.f / 128.f);
  __syncthreads();
  float d = v - mean;
  red[i] = d * d; __syncthreads();
  for (int st = 64; st > 0; st >>= 1) { if (i < st) red[i] += red[i + st]; __syncthreads(); }
  float var = red[0] * (1.f / 128.f);
  float y = d * rsqrtf(var + EPS_F) * g[i] + b[i];
  buf[i] = y; __syncthreads();
  float outv;
  if (i < 32) {
    float c = cosb[t * 32 + i], s = sinb[t * 32 + i];
    outv = buf[i] * c - buf[i + 32] * s;
  } else if (i < 64) {
    int j = i - 32;
    float c = cosb[t * 32 + j], s = sinb[t * 32 + j];
    outv = buf[j] * s + buf[i] * c;
  } else outv = y;
  ko[(size_t)t * 128 + i] = f2b(outv);
}

// ================= RoPE in-place (bf16) =================
__global__ __launch_bounds__(256) void k_rope_b(unsigned short* __restrict__ base, int rowstride, int nh,
                                                int hstride, int off, const float* __restrict__ cosb,
                                                const float* __restrict__ sinb, int total) {
  int idx = blockIdx.x * 256 + threadIdx.x;
  if (idx >= total) return;
  int i = idx & 31, h = (idx >> 5) % nh, t = idx / (32 * nh);
  unsigned short* p = base + (size_t)t * rowstride + h * hstride + off;
  float x1 = b2f(p[i]), x2 = b2f(p[i + 32]);
  float c = cosb[t * 32 + i], s = sinb[t * 32 + i];
  p[i] = f2b(x1 * c - x2 * s);
  p[i + 32] = f2b(x1 * s + x2 * c);
}

// ================= indexer scores via MFMA: 64x64 causal tiles, swizzled gload staging =================
__global__ __launch_bounds__(256) void k_idx_mfma(
    const unsigned short* __restrict__ qi_b, int qpitch,
    const unsigned short* __restrict__ ki_b,  // [S][128] bf16
    const float* __restrict__ wb,             // [S][16]  f32
    float* __restrict__ out) {                // [S][2048] f32
  int bid = blockIdx.x;
  int tb = (int)((sqrtf(8.f * bid + 1.f) - 1.f) * 0.5f);
  while ((tb + 1) * (tb + 2) / 2 <= bid) tb++;
  while (tb * (tb + 1) / 2 > bid) tb--;
  int sb = bid - tb * (tb + 1) / 2;
  int t0 = tb * 64, s0 = sb * 64;

  int tid = threadIdx.x, lane = tid & 63, w = tid >> 6;
  int wm = w >> 1, wn = w & 1;
  int l15 = lane & 15, quarter = lane >> 4;

  __shared__ unsigned short Ks[64 * 128];
  __shared__ unsigned short Qs[2][64 * 128];
  __shared__ float Ws[64][16];

  // per-thread pre-swizzled staging map: chunk cc lands so that read XOR ((row&7)<<3) works
  int srow_[4], scc_[4];
#pragma unroll
  for (int i = 0; i < 4; i++) {
    int row = w * 16 + i * 4 + (lane >> 4);
    int rr = row & 7;
    srow_[i] = row;
    scc_[i] = (lane & 15) ^ rr;
  }
#pragma unroll
  for (int i = 0; i < 4; i++) {
    gload16(ki_b + (size_t)(s0 + srow_[i]) * 128 + scc_[i] * 8, &Ks[(w * 16 + i * 4) * 128]);
    gload16(qi_b + (size_t)(t0 + srow_[i]) * qpitch + scc_[i] * 8, &Qs[0][(w * 16 + i * 4) * 128]);
  }
  for (int i = tid; i < 64 * 16; i += 256) Ws[i >> 4][i & 15] = wb[(size_t)(t0 + (i >> 4)) * 16 + (i & 15)];
  __syncthreads();

  bf16x8 bfr[2][4];
#pragma unroll
  for (int nf = 0; nf < 2; nf++) {
    int row = wn * 32 + nf * 16 + l15;
    int rx = (row & 7) << 3;
#pragma unroll
    for (int kc = 0; kc < 4; kc++)
      bfr[nf][kc] = *(const bf16x8*)(Ks + row * 128 + ((kc * 32 + quarter * 8) ^ rx));
  }

  f32x4 acc[2][2];
#pragma unroll
  for (int mf = 0; mf < 2; mf++)
#pragma unroll
    for (int nf = 0; nf < 2; nf++) acc[mf][nf] = (f32x4){0.f, 0.f, 0.f, 0.f};

  for (int h = 0; h < 16; h++) {
    int cur = h & 1;
    if (h < 15) {
#pragma unroll
      for (int i = 0; i < 4; i++)
        gload16(qi_b + (size_t)(t0 + srow_[i]) * qpitch + (h + 1) * 128 + scc_[i] * 8,
                &Qs[cur ^ 1][(w * 16 + i * 4) * 128]);
    }
    f32x4 acch[2][2];
#pragma unroll
    for (int mf = 0; mf < 2; mf++)
#pragma unroll
      for (int nf = 0; nf < 2; nf++) acch[mf][nf] = (f32x4){0.f, 0.f, 0.f, 0.f};

#pragma unroll
    for (int mf = 0; mf < 2; mf++) {
      int row = wm * 32 + mf * 16 + l15;
      int rx = (row & 7) << 3;
      bf16x8 af[4];
#pragma unroll
      for (int kc = 0; kc < 4; kc++)
        af[kc] = *(const bf16x8*)(Qs[cur] + row * 128 + ((kc * 32 + quarter * 8) ^ rx));
#pragma unroll
      for (int nf = 0; nf < 2; nf++)
#pragma unroll
        for (int kc = 0; kc < 4; kc++)
          acch[mf][nf] = __builtin_amdgcn_mfma_f32_16x16x32_bf16(af[kc], bfr[nf][kc], acch[mf][nf], 0, 0, 0);
    }
#pragma unroll
    for (int mf = 0; mf < 2; mf++) {
#pragma unroll
      for (int r = 0; r < 4; r++) {
        float wv = Ws[wm * 32 + mf * 16 + quarter * 4 + r][h];
#pragma unroll
        for (int nf = 0; nf < 2; nf++)
          acc[mf][nf][r] = fmaf(wv, fmaxf(acch[mf][nf][r], 0.f), acc[mf][nf][r]);
      }
    }
    __syncthreads();   // drains prefetch; guards Qs[cur] overwrite next iter
  }
#pragma unroll
  for (int mf = 0; mf < 2; mf++)
#pragma unroll
    for (int nf = 0; nf < 2; nf++)
#pragma unroll
      for (int r = 0; r < 4; r++) {
        int t = t0 + wm * 32 + mf * 16 + quarter * 4 + r;
        int s = s0 + wn * 32 + nf * 16 + l15;
        out[(size_t)t * 2048 + s] = acc[mf][nf][r] * ISCALE_ID;
      }
}

// ================= per-row top-K -> bitmask (parallel suffix-scan radix select) =================
__global__ __launch_bounds__(256) void k_topk_mask(const float* __restrict__ idx_sc, u64* __restrict__ maskw) {
  int t = blockIdx.x;
  int tid = threadIdx.x;
  int n = t + 1;
  if (n <= TOPKC) {
    if (tid < 32) {
      int lo = tid * 64, hi = lo + 63;
      u64 wv;
      if (t >= hi) wv = ~0ULL;
      else if (t < lo) wv = 0ULL;
      else wv = (~0ULL) >> (63 - (t - lo));
      maskw[(size_t)t * 32 + tid] = wv;
    }
    return;
  }
  __shared__ unsigned int u[2048];
  __shared__ int hist[256];
  __shared__ int scan[256];
  __shared__ u64 mw[32];
  __shared__ int sel_b, new_target, tie_base;
  __shared__ int wcnt[4];
  if (tid < 32) mw[tid] = 0ULL;
  const float* row = idx_sc + (size_t)t * 2048;
  for (int s = tid; s < n; s += 256) {
    unsigned int bb = __float_as_uint(row[s]);
    u[s] = (bb & 0x80000000u) ? ~bb : (bb | 0x80000000u);
  }
  __syncthreads();
  unsigned int prefix = 0;
  int target = TOPKC;
  for (int shift = 24; shift >= 0; shift -= 8) {
    hist[tid] = 0;
    __syncthreads();
    unsigned int himask = (shift == 24) ? 0u : (0xFFFFFFFFu << (shift + 8));
    for (int s = tid; s < n; s += 256) {
      unsigned int uv = u[s];
      if ((uv & himask) == prefix) atomicAdd(&hist[(uv >> shift) & 0xFF], 1);
    }
    __syncthreads();
    scan[tid] = hist[tid];
    __syncthreads();
#pragma unroll
    for (int st = 1; st < 256; st <<= 1) {
      int add = (tid + st < 256) ? scan[tid + st] : 0;
      __syncthreads();
      scan[tid] += add;
      __syncthreads();
    }
    int snext = (tid == 255) ? 0 : scan[tid + 1];
    if (scan[tid] >= target && snext < target) { sel_b = tid; new_target = target - snext; }
    __syncthreads();
    prefix |= ((unsigned int)sel_b) << shift;
    target = new_target;
    __syncthreads();
  }
  if (tid == 0) tie_base = 0;
  __syncthreads();
  int wid = tid >> 6, lane = tid & 63;
  for (int s0 = 0; s0 < n; s0 += 256) {
    int s = s0 + tid;
    bool in = (s < n);
    unsigned int uv = in ? u[s] : 0u;
    bool gt = in && (uv > prefix);
    bool tie = in && (uv == prefix);
    u64 bal = __ballot(tie);
    if (lane == 0) wcnt[wid] = __popcll(bal);
    __syncthreads();
    int wbase = tie_base;
    for (int wI = 0; wI < wid; wI++) wbase += wcnt[wI];
    int rank = wbase + __popcll(bal & ((1ULL << lane) - 1ULL));
    bool sel = gt || (tie && rank < target);
    if (sel) atomicOr(&mw[s >> 6], 1ULL << (s & 63));
    __syncthreads();
    if (tid == 0) tie_base += wcnt[0] + wcnt[1] + wcnt[2] + wcnt[3];
    __syncthreads();
  }
  if (tid < 32) maskw[(size_t)t * 32 + tid] = mw[tid];
}

// ================= MFMA flash attention: async double-buffered K (gload_lds), V reg-prefetch =================
__global__ __launch_bounds__(256) void k_attn_mfma(
    const unsigned short* __restrict__ qb, int qpitch,  // q, pe part roped here on load
    const unsigned short* __restrict__ kvb_b,  // [S][4096] bf16: k_nope@h*256, v@h*256+128
    const unsigned short* __restrict__ kpe_b,  // [S][64]   bf16, roped
    const float* __restrict__ cosb, const float* __restrict__ sinb,
    const u64* __restrict__ maskw,             // [S][32]
    unsigned short* __restrict__ attn_b) {     // [S][2048] bf16
  int ybm = blockIdx.x;                        // 0..31
  int h = blockIdx.y;                          // 0..15
  int yb = (h < 8) ? ybm : (31 - ybm);         // blocks b, b+256 share a CU -> complementary work
  int t0 = yb * 64;
  int tid = threadIdx.x;
  int lane = tid & 63, wq = tid >> 6;
  int quarter = lane >> 4, l15 = lane & 15;

  __shared__ unsigned short Kd[2][64 * 192];   // swizzled (pre-swizzled gload source), pitch 384B
  __shared__ unsigned short Vts[128 * 64];     // V^T u32-pairs, pitch 128B, swz (((d>>2)&7)<<4)

  // per-thread K staging map: LDS slot -> inverse-swizzled global chunk
  const unsigned short* kb_base[6];
  int kb_step[6];
#pragma unroll
  for (int i = 0; i < 6; i++) {
    int slot = (wq * 6 + i) * 1024 + lane * 16;
    int rowk = slot / 384;
    int coff = slot - rowk * 384;
    int cc = (coff ^ ((rowk & 7) << 4)) >> 4;
    if (cc < 16) { kb_base[i] = kvb_b + (size_t)rowk * 4096 + h * 256 + cc * 8; kb_step[i] = 4096; }
    else         { kb_base[i] = kpe_b + (size_t)rowk * 64 + (cc - 16) * 8;      kb_step[i] = 64; }
  }
  const int vdg = tid & 15, vsp = tid >> 4;
  const unsigned short* vbase = kvb_b + (size_t)(vsp * 4) * 4096 + h * 256 + 128 + vdg * 8;

  // Q fragments + fused RoPE on pe part (pairs qf[4][j]/qf[5][j], i = quarter*8+j)
  bf16x8 qf[6];
  {
    int t = t0 + wq * 16 + l15;
    const unsigned short* qp = qb + (size_t)t * qpitch + h * 192 + quarter * 8;
#pragma unroll
    for (int kc = 0; kc < 6; kc++) qf[kc] = *(const bf16x8*)(qp + kc * 32);
    const float* cp = cosb + t * 32 + quarter * 8;
    const float* sp = sinb + t * 32 + quarter * 8;
    float4 ca = *(const float4*)cp,  cb2 = *(const float4*)(cp + 4);
    float4 sa = *(const float4*)sp,  sb2 = *(const float4*)(sp + 4);
    float carr[8] = {ca.x, ca.y, ca.z, ca.w, cb2.x, cb2.y, cb2.z, cb2.w};
    float sarr[8] = {sa.x, sa.y, sa.z, sa.w, sb2.x, sb2.y, sb2.z, sb2.w};
#pragma unroll
    for (int j = 0; j < 8; j++) {
      float x1 = b2f((unsigned short)qf[4][j]);
      float x2 = b2f((unsigned short)qf[5][j]);
      qf[4][j] = (short)f2b(x1 * carr[j] - x2 * sarr[j]);
      qf[5][j] = (short)f2b(x1 * sarr[j] + x2 * carr[j]);
    }
  }

  f32x4 o[8];
#pragma unroll
  for (int df = 0; df < 8; df++) o[df] = (f32x4){0.f, 0.f, 0.f, 0.f};
  float mcol = -__builtin_inff(), lcol = 0.f;  // column state for t = t0+wq*16+l15
  const u64* mrow = maskw + (size_t)(t0 + wq * 16 + l15) * 32;
  int nsb = yb + 1;

  // prologue: tile 0 K DMA + V reg loads
#pragma unroll
  for (int i = 0; i < 6; i++) gload16(kb_base[i], &Kd[0][(wq * 6 + i) * 512]);
  bf16x8 vr0 = *(const bf16x8*)(vbase);
  bf16x8 vr1 = *(const bf16x8*)(vbase + 4096);
  bf16x8 vr2 = *(const bf16x8*)(vbase + 8192);
  bf16x8 vr3 = *(const bf16x8*)(vbase + 12288);
  __syncthreads();   // K(0) in LDS, V(0) in regs
#pragma unroll
  for (int j = 0; j < 8; j++) {
    int d = vdg * 8 + j;
    uint2 w2;
    w2.x = (unsigned)(unsigned short)vr0[j] | (((unsigned)(unsigned short)vr1[j]) << 16);
    w2.y = (unsigned)(unsigned short)vr2[j] | (((unsigned)(unsigned short)vr3[j]) << 16);
    *(uint2*)((char*)Vts + d * 128 + ((vsp * 8) ^ (((d >> 2) & 7) << 4))) = w2;
  }

  for (int sb = 0; sb < nsb; sb++) {
    int cur = sb & 1;
    __syncthreads();       // barrier B: Kd[cur] + Vts ready
    bool pf = (sb + 1 < nsb);
    if (pf) {              // prefetch next tile: K DMA + V regs (latency hidden under compute)
      size_t s1 = (size_t)(sb + 1) * 64;
#pragma unroll
      for (int i = 0; i < 6; i++)
        gload16(kb_base[i] + s1 * kb_step[i], &Kd[cur ^ 1][(wq * 6 + i) * 512]);
      const unsigned short* vp = vbase + s1 * 4096;
      vr0 = *(const bf16x8*)(vp);
      vr1 = *(const bf16x8*)(vp + 4096);
      vr2 = *(const bf16x8*)(vp + 8192);
      vr3 = *(const bf16x8*)(vp + 12288);
    }
    // swapped QK^T: S^T = mfma(K, Q); lane holds S[t=l15][s0 + sc*16 + quarter*4 + r]
    const unsigned short* Kc = Kd[cur];
    f32x4 sfT[4];
#pragma unroll
    for (int sc = 0; sc < 4; sc++) {
      f32x4 a = (f32x4){0.f, 0.f, 0.f, 0.f};
      int row = sc * 16 + l15;
      int rx = (row & 7) << 4;
#pragma unroll
      for (int kc = 0; kc < 6; kc++) {
        int byte = row * 384 + ((kc * 64 + quarter * 16) ^ rx);
        bf16x8 kf = *(const bf16x8*)((const char*)Kc + byte);
        a = __builtin_amdgcn_mfma_f32_16x16x32_bf16(kf, qf[kc], a, 0, 0, 0);
      }
      sfT[sc] = a;
    }
    u64 w64 = mrow[sb];
    float p[4][4];
#pragma unroll
    for (int sc = 0; sc < 4; sc++)
#pragma unroll
      for (int r = 0; r < 4; r++) {
        int sbit = sc * 16 + quarter * 4 + r;
        bool sel = (w64 >> sbit) & 1ULL;
        p[sc][r] = sel ? sfT[sc][r] * SCALE_ATTN : -__builtin_inff();
      }
    // column softmax: 15 in-lane max + 2 shfl
    float v = p[0][0];
#pragma unroll
    for (int sc = 0; sc < 4; sc++)
#pragma unroll
      for (int r = 0; r < 4; r++) v = fmaxf(v, p[sc][r]);
    v = fmaxf(v, __shfl_xor(v, 16));
    v = fmaxf(v, __shfl_xor(v, 32));
    float mn = fmaxf(mcol, v);
    bool dead = (mn == -__builtin_inff());
    float scl = dead ? 1.f : __expf(mcol - mn);
#pragma unroll
    for (int sc = 0; sc < 4; sc++)
#pragma unroll
      for (int r = 0; r < 4; r++)
        p[sc][r] = dead ? 0.f : __expf(p[sc][r] - mn);
    mcol = dead ? mcol : mn;
    float rs = 0.f;
#pragma unroll
    for (int sc = 0; sc < 4; sc++)
#pragma unroll
      for (int r = 0; r < 4; r++) rs += p[sc][r];
    rs += __shfl_xor(rs, 16);
    rs += __shfl_xor(rs, 32);
    lcol = lcol * scl + rs;

    // pack P -> bf16 pairs, redistribute to PV A-fragments
    unsigned pk[4][2];
#pragma unroll
    for (int sc = 0; sc < 4; sc++)
#pragma unroll
      for (int rr = 0; rr < 2; rr++)
        pk[sc][rr] = (unsigned)f2b(p[sc][2 * rr]) | (((unsigned)f2b(p[sc][2 * rr + 1])) << 16);
    bf16x8 pa[2];
#pragma unroll
    for (int kc = 0; kc < 2; kc++) {
      union { unsigned d[4]; bf16x8 v; } pu;
#pragma unroll
      for (int jj = 0; jj < 4; jj++) {
        int src = ((quarter & 1) * 2 + (jj >> 1)) * 16 + l15;
        unsigned lo = (unsigned)__shfl((int)pk[kc * 2][jj & 1], src);
        unsigned hi = (unsigned)__shfl((int)pk[kc * 2 + 1][jj & 1], src);
        pu.d[jj] = (quarter < 2) ? lo : hi;
      }
      pa[kc] = pu.v;
    }
    float sclr[4];
#pragma unroll
    for (int r = 0; r < 4; r++) sclr[r] = __shfl(scl, quarter * 4 + r);
#pragma unroll
    for (int df = 0; df < 8; df++)
#pragma unroll
      for (int r = 0; r < 4; r++) o[df][r] *= sclr[r];
    // PV
#pragma unroll
    for (int kc = 0; kc < 2; kc++)
#pragma unroll
      for (int df = 0; df < 8; df++) {
        int d = df * 16 + l15;
        int vbyte = d * 128 + ((kc * 64 + quarter * 16) ^ (((d >> 2) & 7) << 4));
        bf16x8 vf = *(const bf16x8*)((const char*)Vts + vbyte);
        o[df] = __builtin_amdgcn_mfma_f32_16x16x32_bf16(pa[kc], vf, o[df], 0, 0, 0);
      }
    __syncthreads();       // barrier A: Vts reads done; prefetch K DMA + V regs drained
    if (pf) {
#pragma unroll
      for (int j = 0; j < 8; j++) {
        int d = vdg * 8 + j;
        uint2 w2;
        w2.x = (unsigned)(unsigned short)vr0[j] | (((unsigned)(unsigned short)vr1[j]) << 16);
        w2.y = (unsigned)(unsigned short)vr2[j] | (((unsigned)(unsigned short)vr3[j]) << 16);
        *(uint2*)((char*)Vts + d * 128 + ((vsp * 8) ^ (((d >> 2) & 7) << 4))) = w2;
      }
    }
  }
  float inv = (lcol > 0.f) ? 1.f / lcol : 0.f;
  float invr[4];
#pragma unroll
  for (int r = 0; r < 4; r++) invr[r] = __shfl(inv, quarter * 4 + r);
#pragma unroll
  for (int r = 0; r < 4; r++) {
    int t = t0 + wq * 16 + quarter * 4 + r;
    unsigned short* op = attn_b + (size_t)t * 2048 + h * 128 + l15;
#pragma unroll
    for (int df = 0; df < 8; df++) op[df * 16] = f2b(o[df][r] * invr[r]);
  }
}

// ================= host launch =================
extern "C" void kernel_launch(void* const* d_in, const int* in_sizes, int n_in,
                              void* d_out, int out_size, void* d_ws, size_t ws_size,
                              hipStream_t stream) {
  const float* hs     = (const float*)d_in[0];
  const float* cosb   = (const float*)d_in[1];
  const float* sinb   = (const float*)d_in[2];
  const float* Wq_a   = (const float*)d_in[3];
  const float* q_a_g  = (const float*)d_in[4];
  const float* Wq_b   = (const float*)d_in[5];
  const float* Wkv_a  = (const float*)d_in[6];
  const float* kv_a_g = (const float*)d_in[7];
  const float* Wkv_b  = (const float*)d_in[8];
  const float* Wo     = (const float*)d_in[9];
  const float* Wq_idx = (const float*)d_in[10];
  const float* Wk_idx = (const float*)d_in[11];
  const float* Ww_idx = (const float*)d_in[12];
  const float* kn_g   = (const float*)d_in[13];
  const float* kn_b   = (const float*)d_in[14];
  float* out = (float*)d_out;

  char* base = (char*)d_ws;
  size_t off = 0;
  auto alloc = [&](size_t bytes) { void* p = base + off; off += (bytes + 255) & ~size_t(255); return p; };

  // fat1 f32 [2048][2304]: qa(0..1535) | kv(1536..2111) | ki(2112..2239); later idxs, then attn_b
  float* fat1 = (float*)alloc((size_t)S_ * 2304 * 4);
  float* idxs = fat1;
  unsigned short* attn_b = (unsigned short*)fat1;
  // fat2 bf16 [2048][5120]: qb(0..3071) | qi(3072..5119)
  unsigned short* fat2 = (unsigned short*)alloc((size_t)S_ * 5120 * 2);
  float* wb    = (float*)alloc((size_t)S_ * 16 * 4);
  u64*   maskw = (u64*)alloc((size_t)S_ * 32 * 8);
  unsigned short* hs_b  = (unsigned short*)alloc((size_t)S_ * 2048 * 2);
  unsigned short* qa_b  = (unsigned short*)alloc((size_t)S_ * 1536 * 2);
  unsigned short* kvc_b = (unsigned short*)alloc((size_t)S_ * 512 * 2);
  unsigned short* kpe_b = (unsigned short*)alloc((size_t)S_ * 64 * 2);
  unsigned short* kvb_b = (unsigned short*)alloc((size_t)S_ * 4096 * 2);
  unsigned short* ki_b  = (unsigned short*)alloc((size_t)S_ * 128 * 2);
  unsigned short* WT    = (unsigned short*)alloc((size_t)5120 * 1536 * 2);  // JIT weight^T scratch

  dim3 blk(256);

  // hs -> bf16
  k_cast_bf16<<<dim3((S_ * 2048 / 4) / 256), blk, 0, stream>>>(hs, 2048, hs_b, 2048, S_, 2048);
  // fused hs-GEMM: [Wq_a | Wkv_a | Wk_idx], K=2048, N=2240
  k_tcast<<<dim3(1536 / 32, 2048 / 32), blk, 0, stream>>>(Wq_a, 2048, 1536, WT);
  k_tcast<<<dim3(576 / 32, 2048 / 32), blk, 0, stream>>>(Wkv_a, 2048, 576, WT + (size_t)1536 * 2048);
  k_tcast<<<dim3(128 / 32, 2048 / 32), blk, 0, stream>>>(Wk_idx, 2048, 128, WT + (size_t)2112 * 2048);
  k_gemm_bf16<<<dim3(18, 16), blk, 0, stream>>>(hs_b, 2048, WT, 2048, fat1, 2304, 2240, 0);
  // fused norm/rope/cast passes
  k_rmsnorm_cast<<<dim3(S_), blk, 0, stream>>>(fat1, 2304, q_a_g, qa_b, 1536);
  k_kvfuse<<<dim3(S_), blk, 0, stream>>>(fat1 + 1536, 2304, kv_a_g, cosb, sinb, kvc_b, kpe_b);
  k_ki_ln_rope_cast<<<dim3(S_), dim3(128), 0, stream>>>(fat1 + 2112, 2304, kn_g, kn_b, cosb, sinb, ki_b);
  // w = hs @ Ww_idx
  k_wb<<<dim3(S_ / 8), blk, 0, stream>>>(hs, Ww_idx, wb);
  // fused qa-GEMM: [Wq_b | Wq_idx], K=1536, N=5120 -> fat2 bf16
  k_tcast<<<dim3(3072 / 32, 1536 / 32), blk, 0, stream>>>(Wq_b, 1536, 3072, WT);
  k_tcast<<<dim3(2048 / 32, 1536 / 32), blk, 0, stream>>>(Wq_idx, 1536, 2048, WT + (size_t)3072 * 1536);
  k_gemm_bf16<<<dim3(40, 16), blk, 0, stream>>>(qa_b, 1536, WT, 1536, fat2, 5120, 5120, 1);
  // qi rope (q_pe rope fused into attention)
  k_rope_b<<<dim3((S_ * 16 * 32) / 256), blk, 0, stream>>>(fat2 + 3072, 5120, 16, 128, 0, cosb, sinb, S_ * 16 * 32);
  // kvb = kv_c @ Wkv_b (bf16 out)
  k_tcast<<<dim3(4096 / 32, 512 / 32), blk, 0, stream>>>(Wkv_b, 512, 4096, WT);
  k_gemm_bf16<<<dim3(32, 16), blk, 0, stream>>>(kvc_b, 512, WT, 512, kvb_b, 4096, 4096, 1);
  // indexer scores (triangular grid)
  k_idx_mfma<<<dim3(528), blk, 0, stream>>>(fat2 + 3072, 5120, ki_b, wb, idxs);
  // top-512 per row -> bitmask
  k_topk_mask<<<dim3(S_), blk, 0, stream>>>(idxs, maskw);
  // MFMA flash attention -> attn_b (aliases fat1; idxs dead after topk)
  k_attn_mfma<<<dim3(32, 16), blk, 0, stream>>>(fat2, 5120, kvb_b, kpe_b, cosb, sinb, maskw, attn_b);
  // out = attn @ Wo
  k_tcast<<<dim3(2048 / 32, 2048 / 32), blk, 0, stream>>>(Wo, 2048, 2048, WT);
  k_gemm_bf16<<<dim3(16, 16), blk, 0, stream>>>(attn_b, 2048, WT, 2048, out, 2048, 2048, 0);

  (void)in_sizes; (void)n_in; (void)out_size; (void)ws_size;
}

// Round 8
// 367.998 us; speedup vs baseline: 12.6518x; 1.2236x over previous
//
#include <hip/hip_runtime.h>
#include <cstdint>
#include <cstddef>
#include <cmath>

typedef unsigned long long u64;
typedef __attribute__((ext_vector_type(8))) short bf16x8;   // 8 bf16 in 4 VGPRs
typedef __attribute__((ext_vector_type(4))) float f32x4;

static constexpr int S_    = 2048;
static constexpr int H_    = 2048;
static constexpr int TOPKC = 512;

#define SCALE_ATTN 0.07216878364870323f   // (192)^-0.5
#define ISCALE_ID  0.08838834764831845f   // (128)^-0.5
#define EPS_F 1e-6f

__device__ inline unsigned short f2b(float f) {
  unsigned u = __float_as_uint(f);
  return (unsigned short)((u + 0x7FFFu + ((u >> 16) & 1u)) >> 16);
}
__device__ inline float b2f(unsigned short b) {
  return __uint_as_float(((unsigned)b) << 16);
}
// async global->LDS, 16B per lane; LDS dest = wave-uniform base + lane*16, global src per-lane
__device__ inline void gload16(const unsigned short* g, unsigned short* l) {
  __builtin_amdgcn_global_load_lds((const __attribute__((address_space(1))) void*)g,
                                   (__attribute__((address_space(3))) void*)l, 16, 0, 0);
}

// ================= bf16 MFMA GEMM: C[M,N] = A[M,K] @ Bt[N,K]^T =================
// 128x128 tile, BK=64, 4 waves. M mult of 128. Linear LDS + global_load_lds (m97 structure).
__global__ __launch_bounds__(256) void k_gemm_bf16(
    const unsigned short* __restrict__ A, int lda,
    const unsigned short* __restrict__ Bt, int K,      // Bt pitch = K
    void* __restrict__ C, int ldc, int N, int out_bf16) {
  __shared__ unsigned short As[128 * 64];
  __shared__ unsigned short Bs[128 * 64];
  const int bm = blockIdx.y * 128, bn = blockIdx.x * 128;
  const int tid = threadIdx.x;
  const int lane = tid & 63, w = tid >> 6;
  const int wm = w >> 1, wn = w & 1;
  const int l15 = lane & 15, quarter = lane >> 4;
  const int srow = (lane >> 3), scol = (lane & 7) * 8;

  f32x4 acc[4][4];
#pragma unroll
  for (int i = 0; i < 4; i++)
#pragma unroll
    for (int j = 0; j < 4; j++) acc[i][j] = (f32x4){0.f, 0.f, 0.f, 0.f};

  for (int k0 = 0; k0 < K; k0 += 64) {
    __syncthreads();
#pragma unroll
    for (int i = 0; i < 4; i++) {
      int r0 = w * 32 + i * 8;
      gload16(A  + (size_t)(bm + r0 + srow) * lda + k0 + scol, &As[r0 * 64]);
      gload16(Bt + (size_t)(bn + r0 + srow) * K   + k0 + scol, &Bs[r0 * 64]);
    }
    __syncthreads();
#pragma unroll
    for (int kc = 0; kc < 2; kc++) {
      bf16x8 af[4], bfr[4];
#pragma unroll
      for (int mf = 0; mf < 4; mf++)
        af[mf] = *(const bf16x8*)(As + (wm * 64 + mf * 16 + l15) * 64 + kc * 32 + quarter * 8);
#pragma unroll
      for (int nf = 0; nf < 4; nf++)
        bfr[nf] = *(const bf16x8*)(Bs + (wn * 64 + nf * 16 + l15) * 64 + kc * 32 + quarter * 8);
#pragma unroll
      for (int mf = 0; mf < 4; mf++)
#pragma unroll
        for (int nf = 0; nf < 4; nf++)
          acc[mf][nf] = __builtin_amdgcn_mfma_f32_16x16x32_bf16(af[mf], bfr[nf], acc[mf][nf], 0, 0, 0);
    }
  }
#pragma unroll
  for (int mf = 0; mf < 4; mf++)
#pragma unroll
    for (int nf = 0; nf < 4; nf++)
#pragma unroll
      for (int r = 0; r < 4; r++) {
        int grow = bm + wm * 64 + mf * 16 + quarter * 4 + r;
        int gcol = bn + wn * 64 + nf * 16 + l15;
        if (gcol < N) {
          if (out_bf16) ((unsigned short*)C)[(size_t)grow * ldc + gcol] = f2b(acc[mf][nf][r]);
          else          ((float*)C)[(size_t)grow * ldc + gcol] = acc[mf][nf][r];
        }
      }
}

// ================= transpose + cast: Wt[n][k] = bf16(W[k][n]) =================
__global__ __launch_bounds__(256) void k_tcast(const float* __restrict__ W, int K, int N,
                                               unsigned short* __restrict__ Wt) {
  __shared__ float T[32][33];
  int n0 = blockIdx.x * 32, k0 = blockIdx.y * 32;
  int tid = threadIdx.x;
#pragma unroll
  for (int i = 0; i < 4; i++) {
    int idx = tid + 256 * i;
    int r = idx >> 5, c = idx & 31;
    T[r][c] = W[(size_t)(k0 + r) * N + n0 + c];
  }
  __syncthreads();
#pragma unroll
  for (int i = 0; i < 4; i++) {
    int idx = tid + 256 * i;
    int r = idx >> 5, c = idx & 31;
    Wt[(size_t)(n0 + r) * K + k0 + c] = f2b(T[c][r]);
  }
}

// ================= transpose + cast for 16-col W: Wt[n][k] = bf16(W[k][n]), n<16 =================
__global__ __launch_bounds__(256) void k_tcast16(const float* __restrict__ W, int K,
                                                 unsigned short* __restrict__ Wt) {
  // thread -> (k block of 16, n)
  int idx = blockIdx.x * 256 + threadIdx.x;   // K*16/ (16*16)=... total K*16 elems
  if (idx >= K * 16) return;
  int k = idx >> 4, n = idx & 15;
  Wt[(size_t)n * K + k] = f2b(W[(size_t)k * 16 + n]);
}

// ================= strided f32 -> bf16 cast =================
__global__ __launch_bounds__(256) void k_cast_bf16(const float* __restrict__ in, int pin,
                                                   unsigned short* __restrict__ outp, int pout,
                                                   int rows, int cols) {
  int cols4 = cols >> 2;
  int idx = blockIdx.x * 256 + threadIdx.x;
  if (idx >= rows * cols4) return;
  int r = idx / cols4, c = (idx - r * cols4) * 4;
  const float* ip = in + (size_t)r * pin + c;
  unsigned short* op = outp + (size_t)r * pout + c;
  op[0] = f2b(ip[0]); op[1] = f2b(ip[1]); op[2] = f2b(ip[2]); op[3] = f2b(ip[3]);
}

// ================= RMSNorm + bf16 cast (separate dst) =================
__global__ __launch_bounds__(256) void k_rmsnorm_cast(
    const float* __restrict__ x, int stride, const float* __restrict__ gamma,
    unsigned short* __restrict__ outp, int n) {
  int r = blockIdx.x;
  const float* p = x + (size_t)r * stride;
  __shared__ float red[256];
  float s = 0.f;
  for (int i = threadIdx.x; i < n; i += 256) { float v = p[i]; s += v * v; }
  red[threadIdx.x] = s; __syncthreads();
  for (int st = 128; st > 0; st >>= 1) { if (threadIdx.x < st) red[threadIdx.x] += red[threadIdx.x + st]; __syncthreads(); }
  float scl = rsqrtf(red[0] / (float)n + EPS_F);
  unsigned short* op = outp + (size_t)r * n;
  for (int i = threadIdx.x; i < n; i += 256) op[i] = f2b(p[i] * scl * gamma[i]);
}

// ================= kv: RMSNorm(512)->kvc_b, rope(64)->kpe_b, one pass =================
__global__ __launch_bounds__(256) void k_kvfuse(
    const float* __restrict__ fat, int stride, const float* __restrict__ gamma,
    const float* __restrict__ cosb, const float* __restrict__ sinb,
    unsigned short* __restrict__ kvc_b, unsigned short* __restrict__ kpe_b) {
  int t = blockIdx.x, tid = threadIdx.x;
  const float* p = fat + (size_t)t * stride;
  __shared__ float red[256];
  float x0 = p[tid], x1 = p[tid + 256];
  red[tid] = x0 * x0 + x1 * x1; __syncthreads();
  for (int st = 128; st > 0; st >>= 1) { if (tid < st) red[tid] += red[tid + st]; __syncthreads(); }
  float scl = rsqrtf(red[0] * (1.f / 512.f) + EPS_F);
  kvc_b[(size_t)t * 512 + tid]       = f2b(x0 * scl * gamma[tid]);
  kvc_b[(size_t)t * 512 + tid + 256] = f2b(x1 * scl * gamma[tid + 256]);
  if (tid < 32) {
    float a = p[512 + tid], b = p[544 + tid];
    float c = cosb[t * 32 + tid], s = sinb[t * 32 + tid];
    kpe_b[(size_t)t * 64 + tid]      = f2b(a * c - b * s);
    kpe_b[(size_t)t * 64 + 32 + tid] = f2b(a * s + b * c);
  }
}

// ================= ki: LayerNorm(128) + RoPE(first 64) -> bf16 =================
__global__ __launch_bounds__(128) void k_ki_ln_rope_cast(
    const float* __restrict__ ki, int stride,
    const float* __restrict__ g, const float* __restrict__ b,
    const float* __restrict__ cosb, const float* __restrict__ sinb,
    unsigned short* __restrict__ ko) {
  int t = blockIdx.x, i = threadIdx.x;
  const float* p = ki + (size_t)t * stride;
  __shared__ float red[128];
  __shared__ float buf[128];
  float v = p[i];
  red[i] = v; __syncthreads();
  for (int st = 64; st > 0; st >>= 1) { if (i < st) red[i] += red[i + st]; __syncthreads(); }
  float mean = red[0] * (1.f / 128.f);
  __syncthreads();
  float d = v - mean;
  red[i] = d * d; __syncthreads();
  for (int st = 64; st > 0; st >>= 1) { if (i < st) red[i] += red[i + st]; __syncthreads(); }
  float var = red[0] * (1.f / 128.f);
  float y = d * rsqrtf(var + EPS_F) * g[i] + b[i];
  buf[i] = y; __syncthreads();
  float outv;
  if (i < 32) {
    float c = cosb[t * 32 + i], s = sinb[t * 32 + i];
    outv = buf[i] * c - buf[i + 32] * s;
  } else if (i < 64) {
    int j = i - 32;
    float c = cosb[t * 32 + j], s = sinb[t * 32 + j];
    outv = buf[j] * s + buf[i] * c;
  } else outv = y;
  ko[(size_t)t * 128 + i] = f2b(outv);
}

// ================= RoPE in-place (bf16) =================
__global__ __launch_bounds__(256) void k_rope_b(unsigned short* __restrict__ base, int rowstride, int nh,
                                                int hstride, int off, const float* __restrict__ cosb,
                                                const float* __restrict__ sinb, int total) {
  int idx = blockIdx.x * 256 + threadIdx.x;
  if (idx >= total) return;
  int i = idx & 31, h = (idx >> 5) % nh, t = idx / (32 * nh);
  unsigned short* p = base + (size_t)t * rowstride + h * hstride + off;
  float x1 = b2f(p[i]), x2 = b2f(p[i + 32]);
  float c = cosb[t * 32 + i], s = sinb[t * 32 + i];
  p[i] = f2b(x1 * c - x2 * s);
  p[i + 32] = f2b(x1 * s + x2 * c);
}

// ================= indexer scores via MFMA: 64x64 causal tiles, swizzled gload staging =================
__global__ __launch_bounds__(256) void k_idx_mfma(
    const unsigned short* __restrict__ qi_b, int qpitch,
    const unsigned short* __restrict__ ki_b,  // [S][128] bf16
    const float* __restrict__ wb, int wstride, // per-row head weights (f32, strided)
    float* __restrict__ out) {                // [S][2048] f32
  int bid = blockIdx.x;
  int tb = (int)((sqrtf(8.f * bid + 1.f) - 1.f) * 0.5f);
  while ((tb + 1) * (tb + 2) / 2 <= bid) tb++;
  while (tb * (tb + 1) / 2 > bid) tb--;
  int sb = bid - tb * (tb + 1) / 2;
  int t0 = tb * 64, s0 = sb * 64;

  int tid = threadIdx.x, lane = tid & 63, w = tid >> 6;
  int wm = w >> 1, wn = w & 1;
  int l15 = lane & 15, quarter = lane >> 4;

  __shared__ unsigned short Ks[64 * 128];
  __shared__ unsigned short Qs[2][64 * 128];
  __shared__ float Ws[64][16];

  // per-thread pre-swizzled staging map: chunk cc lands so that read XOR ((row&7)<<3) works
  int srow_[4], scc_[4];
#pragma unroll
  for (int i = 0; i < 4; i++) {
    int row = w * 16 + i * 4 + (lane >> 4);
    int rr = row & 7;
    srow_[i] = row;
    scc_[i] = (lane & 15) ^ rr;
  }
#pragma unroll
  for (int i = 0; i < 4; i++) {
    gload16(ki_b + (size_t)(s0 + srow_[i]) * 128 + scc_[i] * 8, &Ks[(w * 16 + i * 4) * 128]);
    gload16(qi_b + (size_t)(t0 + srow_[i]) * qpitch + scc_[i] * 8, &Qs[0][(w * 16 + i * 4) * 128]);
  }
  for (int i = tid; i < 64 * 16; i += 256) Ws[i >> 4][i & 15] = wb[(size_t)(t0 + (i >> 4)) * wstride + (i & 15)];
  __syncthreads();

  bf16x8 bfr[2][4];
#pragma unroll
  for (int nf = 0; nf < 2; nf++) {
    int row = wn * 32 + nf * 16 + l15;
    int rx = (row & 7) << 3;
#pragma unroll
    for (int kc = 0; kc < 4; kc++)
      bfr[nf][kc] = *(const bf16x8*)(Ks + row * 128 + ((kc * 32 + quarter * 8) ^ rx));
  }

  f32x4 acc[2][2];
#pragma unroll
  for (int mf = 0; mf < 2; mf++)
#pragma unroll
    for (int nf = 0; nf < 2; nf++) acc[mf][nf] = (f32x4){0.f, 0.f, 0.f, 0.f};

  for (int h = 0; h < 16; h++) {
    int cur = h & 1;
    if (h < 15) {
#pragma unroll
      for (int i = 0; i < 4; i++)
        gload16(qi_b + (size_t)(t0 + srow_[i]) * qpitch + (h + 1) * 128 + scc_[i] * 8,
                &Qs[cur ^ 1][(w * 16 + i * 4) * 128]);
    }
    f32x4 acch[2][2];
#pragma unroll
    for (int mf = 0; mf < 2; mf++)
#pragma unroll
      for (int nf = 0; nf < 2; nf++) acch[mf][nf] = (f32x4){0.f, 0.f, 0.f, 0.f};

#pragma unroll
    for (int mf = 0; mf < 2; mf++) {
      int row = wm * 32 + mf * 16 + l15;
      int rx = (row & 7) << 3;
      bf16x8 af[4];
#pragma unroll
      for (int kc = 0; kc < 4; kc++)
        af[kc] = *(const bf16x8*)(Qs[cur] + row * 128 + ((kc * 32 + quarter * 8) ^ rx));
#pragma unroll
      for (int nf = 0; nf < 2; nf++)
#pragma unroll
        for (int kc = 0; kc < 4; kc++)
          acch[mf][nf] = __builtin_amdgcn_mfma_f32_16x16x32_bf16(af[kc], bfr[nf][kc], acch[mf][nf], 0, 0, 0);
    }
#pragma unroll
    for (int mf = 0; mf < 2; mf++) {
#pragma unroll
      for (int r = 0; r < 4; r++) {
        float wv = Ws[wm * 32 + mf * 16 + quarter * 4 + r][h];
#pragma unroll
        for (int nf = 0; nf < 2; nf++)
          acc[mf][nf][r] = fmaf(wv, fmaxf(acch[mf][nf][r], 0.f), acc[mf][nf][r]);
      }
    }
    __syncthreads();   // drains prefetch; guards Qs[cur] overwrite next iter
  }
#pragma unroll
  for (int mf = 0; mf < 2; mf++)
#pragma unroll
    for (int nf = 0; nf < 2; nf++)
#pragma unroll
      for (int r = 0; r < 4; r++) {
        int t = t0 + wm * 32 + mf * 16 + quarter * 4 + r;
        int s = s0 + wn * 32 + nf * 16 + l15;
        out[(size_t)t * 2048 + s] = acc[mf][nf][r] * ISCALE_ID;
      }
}

// ================= per-row top-K -> bitmask (parallel suffix-scan radix select) =================
__global__ __launch_bounds__(256) void k_topk_mask(const float* __restrict__ idx_sc, u64* __restrict__ maskw) {
  int t = blockIdx.x;
  int tid = threadIdx.x;
  int n = t + 1;
  if (n <= TOPKC) {
    if (tid < 32) {
      int lo = tid * 64, hi = lo + 63;
      u64 wv;
      if (t >= hi) wv = ~0ULL;
      else if (t < lo) wv = 0ULL;
      else wv = (~0ULL) >> (63 - (t - lo));
      maskw[(size_t)t * 32 + tid] = wv;
    }
    return;
  }
  __shared__ unsigned int u[2048];
  __shared__ int hist[256];
  __shared__ int scan[256];
  __shared__ u64 mw[32];
  __shared__ int sel_b, new_target, tie_base;
  __shared__ int wcnt[4];
  if (tid < 32) mw[tid] = 0ULL;
  const float* row = idx_sc + (size_t)t * 2048;
  for (int s = tid; s < n; s += 256) {
    unsigned int bb = __float_as_uint(row[s]);
    u[s] = (bb & 0x80000000u) ? ~bb : (bb | 0x80000000u);
  }
  __syncthreads();
  unsigned int prefix = 0;
  int target = TOPKC;
  for (int shift = 24; shift >= 0; shift -= 8) {
    hist[tid] = 0;
    __syncthreads();
    unsigned int himask = (shift == 24) ? 0u : (0xFFFFFFFFu << (shift + 8));
    for (int s = tid; s < n; s += 256) {
      unsigned int uv = u[s];
      if ((uv & himask) == prefix) atomicAdd(&hist[(uv >> shift) & 0xFF], 1);
    }
    __syncthreads();
    scan[tid] = hist[tid];
    __syncthreads();
#pragma unroll
    for (int st = 1; st < 256; st <<= 1) {
      int add = (tid + st < 256) ? scan[tid + st] : 0;
      __syncthreads();
      scan[tid] += add;
      __syncthreads();
    }
    int snext = (tid == 255) ? 0 : scan[tid + 1];
    if (scan[tid] >= target && snext < target) { sel_b = tid; new_target = target - snext; }
    __syncthreads();
    prefix |= ((unsigned int)sel_b) << shift;
    target = new_target;
    __syncthreads();
  }
  if (tid == 0) tie_base = 0;
  __syncthreads();
  int wid = tid >> 6, lane = tid & 63;
  for (int s0 = 0; s0 < n; s0 += 256) {
    int s = s0 + tid;
    bool in = (s < n);
    unsigned int uv = in ? u[s] : 0u;
    bool gt = in && (uv > prefix);
    bool tie = in && (uv == prefix);
    u64 bal = __ballot(tie);
    if (lane == 0) wcnt[wid] = __popcll(bal);
    __syncthreads();
    int wbase = tie_base;
    for (int wI = 0; wI < wid; wI++) wbase += wcnt[wI];
    int rank = wbase + __popcll(bal & ((1ULL << lane) - 1ULL));
    bool sel = gt || (tie && rank < target);
    if (sel) atomicOr(&mw[s >> 6], 1ULL << (s & 63));
    __syncthreads();
    if (tid == 0) tie_base += wcnt[0] + wcnt[1] + wcnt[2] + wcnt[3];
    __syncthreads();
  }
  if (tid < 32) maskw[(size_t)t * 32 + tid] = mw[tid];
}

// ================= MFMA flash attention: async double-buffered K (gload_lds), V reg-prefetch =================
__global__ __launch_bounds__(256) void k_attn_mfma(
    const unsigned short* __restrict__ qb, int qpitch,  // q, pe part roped here on load
    const unsigned short* __restrict__ kvb_b,  // [S][4096] bf16: k_nope@h*256, v@h*256+128
    const unsigned short* __restrict__ kpe_b,  // [S][64]   bf16, roped
    const float* __restrict__ cosb, const float* __restrict__ sinb,
    const u64* __restrict__ maskw,             // [S][32]
    unsigned short* __restrict__ attn_b) {     // [S][2048] bf16
  int ybm = blockIdx.x;                        // 0..31
  int h = blockIdx.y;                          // 0..15
  int yb = (h < 8) ? ybm : (31 - ybm);         // blocks b, b+256 share a CU -> complementary work
  int t0 = yb * 64;
  int tid = threadIdx.x;
  int lane = tid & 63, wq = tid >> 6;
  int quarter = lane >> 4, l15 = lane & 15;

  __shared__ unsigned short Kd[2][64 * 192];   // swizzled (pre-swizzled gload source), pitch 384B
  __shared__ unsigned short Vts[128 * 64];     // V^T u32-pairs, pitch 128B, swz (((d>>2)&7)<<4)

  // per-thread K staging map: LDS slot -> inverse-swizzled global chunk
  const unsigned short* kb_base[6];
  int kb_step[6];
#pragma unroll
  for (int i = 0; i < 6; i++) {
    int slot = (wq * 6 + i) * 1024 + lane * 16;
    int rowk = slot / 384;
    int coff = slot - rowk * 384;
    int cc = (coff ^ ((rowk & 7) << 4)) >> 4;
    if (cc < 16) { kb_base[i] = kvb_b + (size_t)rowk * 4096 + h * 256 + cc * 8; kb_step[i] = 4096; }
    else         { kb_base[i] = kpe_b + (size_t)rowk * 64 + (cc - 16) * 8;      kb_step[i] = 64; }
  }
  const int vdg = tid & 15, vsp = tid >> 4;
  const unsigned short* vbase = kvb_b + (size_t)(vsp * 4) * 4096 + h * 256 + 128 + vdg * 8;

  // Q fragments + fused RoPE on pe part (pairs qf[4][j]/qf[5][j], i = quarter*8+j)
  bf16x8 qf[6];
  {
    int t = t0 + wq * 16 + l15;
    const unsigned short* qp = qb + (size_t)t * qpitch + h * 192 + quarter * 8;
#pragma unroll
    for (int kc = 0; kc < 6; kc++) qf[kc] = *(const bf16x8*)(qp + kc * 32);
    const float* cp = cosb + t * 32 + quarter * 8;
    const float* sp = sinb + t * 32 + quarter * 8;
    float4 ca = *(const float4*)cp,  cb2 = *(const float4*)(cp + 4);
    float4 sa = *(const float4*)sp,  sb2 = *(const float4*)(sp + 4);
    float carr[8] = {ca.x, ca.y, ca.z, ca.w, cb2.x, cb2.y, cb2.z, cb2.w};
    float sarr[8] = {sa.x, sa.y, sa.z, sa.w, sb2.x, sb2.y, sb2.z, sb2.w};
#pragma unroll
    for (int j = 0; j < 8; j++) {
      float x1 = b2f((unsigned short)qf[4][j]);
      float x2 = b2f((unsigned short)qf[5][j]);
      qf[4][j] = (short)f2b(x1 * carr[j] - x2 * sarr[j]);
      qf[5][j] = (short)f2b(x1 * sarr[j] + x2 * carr[j]);
    }
  }

  f32x4 o[8];
#pragma unroll
  for (int df = 0; df < 8; df++) o[df] = (f32x4){0.f, 0.f, 0.f, 0.f};
  float mcol = -__builtin_inff(), lcol = 0.f;  // column state for t = t0+wq*16+l15
  const u64* mrow = maskw + (size_t)(t0 + wq * 16 + l15) * 32;
  int nsb = yb + 1;

  // prologue: tile 0 K DMA + V reg loads
#pragma unroll
  for (int i = 0; i < 6; i++) gload16(kb_base[i], &Kd[0][(wq * 6 + i) * 512]);
  bf16x8 vr0 = *(const bf16x8*)(vbase);
  bf16x8 vr1 = *(const bf16x8*)(vbase + 4096);
  bf16x8 vr2 = *(const bf16x8*)(vbase + 8192);
  bf16x8 vr3 = *(const bf16x8*)(vbase + 12288);
  __syncthreads();   // K(0) in LDS, V(0) in regs
#pragma unroll
  for (int j = 0; j < 8; j++) {
    int d = vdg * 8 + j;
    uint2 w2;
    w2.x = (unsigned)(unsigned short)vr0[j] | (((unsigned)(unsigned short)vr1[j]) << 16);
    w2.y = (unsigned)(unsigned short)vr2[j] | (((unsigned)(unsigned short)vr3[j]) << 16);
    *(uint2*)((char*)Vts + d * 128 + ((vsp * 8) ^ (((d >> 2) & 7) << 4))) = w2;
  }

  for (int sb = 0; sb < nsb; sb++) {
    int cur = sb & 1;
    __syncthreads();       // barrier B: Kd[cur] + Vts ready
    bool pf = (sb + 1 < nsb);
    if (pf) {              // prefetch next tile: K DMA + V regs (latency hidden under compute)
      size_t s1 = (size_t)(sb + 1) * 64;
#pragma unroll
      for (int i = 0; i < 6; i++)
        gload16(kb_base[i] + s1 * kb_step[i], &Kd[cur ^ 1][(wq * 6 + i) * 512]);
      const unsigned short* vp = vbase + s1 * 4096;
      vr0 = *(const bf16x8*)(vp);
      vr1 = *(const bf16x8*)(vp + 4096);
      vr2 = *(const bf16x8*)(vp + 8192);
      vr3 = *(const bf16x8*)(vp + 12288);
    }
    // swapped QK^T: S^T = mfma(K, Q); lane holds S[t=l15][s0 + sc*16 + quarter*4 + r]
    const unsigned short* Kc = Kd[cur];
    f32x4 sfT[4];
#pragma unroll
    for (int sc = 0; sc < 4; sc++) {
      f32x4 a = (f32x4){0.f, 0.f, 0.f, 0.f};
      int row = sc * 16 + l15;
      int rx = (row & 7) << 4;
#pragma unroll
      for (int kc = 0; kc < 6; kc++) {
        int byte = row * 384 + ((kc * 64 + quarter * 16) ^ rx);
        bf16x8 kf = *(const bf16x8*)((const char*)Kc + byte);
        a = __builtin_amdgcn_mfma_f32_16x16x32_bf16(kf, qf[kc], a, 0, 0, 0);
      }
      sfT[sc] = a;
    }
    u64 w64 = mrow[sb];
    float p[4][4];
#pragma unroll
    for (int sc = 0; sc < 4; sc++)
#pragma unroll
      for (int r = 0; r < 4; r++) {
        int sbit = sc * 16 + quarter * 4 + r;
        bool sel = (w64 >> sbit) & 1ULL;
        p[sc][r] = sel ? sfT[sc][r] * SCALE_ATTN : -__builtin_inff();
      }
    // column softmax: 15 in-lane max + 2 shfl
    float v = p[0][0];
#pragma unroll
    for (int sc = 0; sc < 4; sc++)
#pragma unroll
      for (int r = 0; r < 4; r++) v = fmaxf(v, p[sc][r]);
    v = fmaxf(v, __shfl_xor(v, 16));
    v = fmaxf(v, __shfl_xor(v, 32));
    float mn = fmaxf(mcol, v);
    bool dead = (mn == -__builtin_inff());
    float scl = dead ? 1.f : __expf(mcol - mn);
#pragma unroll
    for (int sc = 0; sc < 4; sc++)
#pragma unroll
      for (int r = 0; r < 4; r++)
        p[sc][r] = dead ? 0.f : __expf(p[sc][r] - mn);
    mcol = dead ? mcol : mn;
    float rs = 0.f;
#pragma unroll
    for (int sc = 0; sc < 4; sc++)
#pragma unroll
      for (int r = 0; r < 4; r++) rs += p[sc][r];
    rs += __shfl_xor(rs, 16);
    rs += __shfl_xor(rs, 32);
    lcol = lcol * scl + rs;

    // pack P -> bf16 pairs, redistribute to PV A-fragments
    unsigned pk[4][2];
#pragma unroll
    for (int sc = 0; sc < 4; sc++)
#pragma unroll
      for (int rr = 0; rr < 2; rr++)
        pk[sc][rr] = (unsigned)f2b(p[sc][2 * rr]) | (((unsigned)f2b(p[sc][2 * rr + 1])) << 16);
    bf16x8 pa[2];
#pragma unroll
    for (int kc = 0; kc < 2; kc++) {
      union { unsigned d[4]; bf16x8 v; } pu;
#pragma unroll
      for (int jj = 0; jj < 4; jj++) {
        int src = ((quarter & 1) * 2 + (jj >> 1)) * 16 + l15;
        unsigned lo = (unsigned)__shfl((int)pk[kc * 2][jj & 1], src);
        unsigned hi = (unsigned)__shfl((int)pk[kc * 2 + 1][jj & 1], src);
        pu.d[jj] = (quarter < 2) ? lo : hi;
      }
      pa[kc] = pu.v;
    }
    float sclr[4];
#pragma unroll
    for (int r = 0; r < 4; r++) sclr[r] = __shfl(scl, quarter * 4 + r);
#pragma unroll
    for (int df = 0; df < 8; df++)
#pragma unroll
      for (int r = 0; r < 4; r++) o[df][r] *= sclr[r];
    // PV
#pragma unroll
    for (int kc = 0; kc < 2; kc++)
#pragma unroll
      for (int df = 0; df < 8; df++) {
        int d = df * 16 + l15;
        int vbyte = d * 128 + ((kc * 64 + quarter * 16) ^ (((d >> 2) & 7) << 4));
        bf16x8 vf = *(const bf16x8*)((const char*)Vts + vbyte);
        o[df] = __builtin_amdgcn_mfma_f32_16x16x32_bf16(pa[kc], vf, o[df], 0, 0, 0);
      }
    __syncthreads();       // barrier A: Vts reads done; prefetch K DMA + V regs drained
    if (pf) {
#pragma unroll
      for (int j = 0; j < 8; j++) {
        int d = vdg * 8 + j;
        uint2 w2;
        w2.x = (unsigned)(unsigned short)vr0[j] | (((unsigned)(unsigned short)vr1[j]) << 16);
        w2.y = (unsigned)(unsigned short)vr2[j] | (((unsigned)(unsigned short)vr3[j]) << 16);
        *(uint2*)((char*)Vts + d * 128 + ((vsp * 8) ^ (((d >> 2) & 7) << 4))) = w2;
      }
    }
  }
  float inv = (lcol > 0.f) ? 1.f / lcol : 0.f;
  float invr[4];
#pragma unroll
  for (int r = 0; r < 4; r++) invr[r] = __shfl(inv, quarter * 4 + r);
#pragma unroll
  for (int r = 0; r < 4; r++) {
    int t = t0 + wq * 16 + quarter * 4 + r;
    unsigned short* op = attn_b + (size_t)t * 2048 + h * 128 + l15;
#pragma unroll
    for (int df = 0; df < 8; df++) op[df * 16] = f2b(o[df][r] * invr[r]);
  }
}

// ================= host launch =================
extern "C" void kernel_launch(void* const* d_in, const int* in_sizes, int n_in,
                              void* d_out, int out_size, void* d_ws, size_t ws_size,
                              hipStream_t stream) {
  const float* hs     = (const float*)d_in[0];
  const float* cosb   = (const float*)d_in[1];
  const float* sinb   = (const float*)d_in[2];
  const float* Wq_a   = (const float*)d_in[3];
  const float* q_a_g  = (const float*)d_in[4];
  const float* Wq_b   = (const float*)d_in[5];
  const float* Wkv_a  = (const float*)d_in[6];
  const float* kv_a_g = (const float*)d_in[7];
  const float* Wkv_b  = (const float*)d_in[8];
  const float* Wo     = (const float*)d_in[9];
  const float* Wq_idx = (const float*)d_in[10];
  const float* Wk_idx = (const float*)d_in[11];
  const float* Ww_idx = (const float*)d_in[12];
  const float* kn_g   = (const float*)d_in[13];
  const float* kn_b   = (const float*)d_in[14];
  float* out = (float*)d_out;

  char* base = (char*)d_ws;
  size_t off = 0;
  auto alloc = [&](size_t bytes) { void* p = base + off; off += (bytes + 255) & ~size_t(255); return p; };

  // fat1 f32 [2048][2304]: qa(0..1535) | kv(1536..2111) | ki(2112..2239) | wb(2240..2255)
  float* fat1 = (float*)alloc((size_t)S_ * 2304 * 4);
  // idxs separate (16 MB) so fat1's wb slice survives; attn_b aliases idxs after topk
  float* idxs = (float*)alloc((size_t)S_ * 2048 * 4);
  unsigned short* attn_b = (unsigned short*)idxs;
  // fat2 bf16 [2048][5120]: qb(0..3071) | qi(3072..5119)
  unsigned short* fat2 = (unsigned short*)alloc((size_t)S_ * 5120 * 2);
  u64*   maskw = (u64*)alloc((size_t)S_ * 32 * 8);
  unsigned short* hs_b  = (unsigned short*)alloc((size_t)S_ * 2048 * 2);
  unsigned short* qa_b  = (unsigned short*)alloc((size_t)S_ * 1536 * 2);
  unsigned short* kvc_b = (unsigned short*)alloc((size_t)S_ * 512 * 2);
  unsigned short* kpe_b = (unsigned short*)alloc((size_t)S_ * 64 * 2);
  unsigned short* kvb_b = (unsigned short*)alloc((size_t)S_ * 4096 * 2);
  unsigned short* ki_b  = (unsigned short*)alloc((size_t)S_ * 128 * 2);
  unsigned short* WT    = (unsigned short*)alloc((size_t)5120 * 1536 * 2);  // JIT weight^T scratch

  dim3 blk(256);

  // hs -> bf16
  k_cast_bf16<<<dim3((S_ * 2048 / 4) / 256), blk, 0, stream>>>(hs, 2048, hs_b, 2048, S_, 2048);
  // fused hs-GEMM: [Wq_a | Wkv_a | Wk_idx | Ww_idx], K=2048, N=2256
  k_tcast<<<dim3(1536 / 32, 2048 / 32), blk, 0, stream>>>(Wq_a, 2048, 1536, WT);
  k_tcast<<<dim3(576 / 32, 2048 / 32), blk, 0, stream>>>(Wkv_a, 2048, 576, WT + (size_t)1536 * 2048);
  k_tcast<<<dim3(128 / 32, 2048 / 32), blk, 0, stream>>>(Wk_idx, 2048, 128, WT + (size_t)2112 * 2048);
  k_tcast16<<<dim3((2048 * 16) / 256), blk, 0, stream>>>(Ww_idx, 2048, WT + (size_t)2240 * 2048);
  k_gemm_bf16<<<dim3(18, 16), blk, 0, stream>>>(hs_b, 2048, WT, 2048, fat1, 2304, 2256, 0);
  // fused norm/rope/cast passes
  k_rmsnorm_cast<<<dim3(S_), blk, 0, stream>>>(fat1, 2304, q_a_g, qa_b, 1536);
  k_kvfuse<<<dim3(S_), blk, 0, stream>>>(fat1 + 1536, 2304, kv_a_g, cosb, sinb, kvc_b, kpe_b);
  k_ki_ln_rope_cast<<<dim3(S_), dim3(128), 0, stream>>>(fat1 + 2112, 2304, kn_g, kn_b, cosb, sinb, ki_b);
  // fused qa-GEMM: [Wq_b | Wq_idx], K=1536, N=5120 -> fat2 bf16
  k_tcast<<<dim3(3072 / 32, 1536 / 32), blk, 0, stream>>>(Wq_b, 1536, 3072, WT);
  k_tcast<<<dim3(2048 / 32, 1536 / 32), blk, 0, stream>>>(Wq_idx, 1536, 2048, WT + (size_t)3072 * 1536);
  k_gemm_bf16<<<dim3(40, 16), blk, 0, stream>>>(qa_b, 1536, WT, 1536, fat2, 5120, 5120, 1);
  // qi rope (q_pe rope fused into attention)
  k_rope_b<<<dim3((S_ * 16 * 32) / 256), blk, 0, stream>>>(fat2 + 3072, 5120, 16, 128, 0, cosb, sinb, S_ * 16 * 32);
  // kvb = kv_c @ Wkv_b (bf16 out)
  k_tcast<<<dim3(4096 / 32, 512 / 32), blk, 0, stream>>>(Wkv_b, 512, 4096, WT);
  k_gemm_bf16<<<dim3(32, 16), blk, 0, stream>>>(kvc_b, 512, WT, 512, kvb_b, 4096, 4096, 1);
  // indexer scores (triangular grid); wb read from fat1 cols 2240.. (stride 2304)
  k_idx_mfma<<<dim3(528), blk, 0, stream>>>(fat2 + 3072, 5120, ki_b, fat1 + 2240, 2304, idxs);
  // top-512 per row -> bitmask
  k_topk_mask<<<dim3(S_), blk, 0, stream>>>(idxs, maskw);
  // MFMA flash attention -> attn_b (aliases idxs; dead after topk)
  k_attn_mfma<<<dim3(32, 16), blk, 0, stream>>>(fat2, 5120, kvb_b, kpe_b, cosb, sinb, maskw, attn_b);
  // out = attn @ Wo
  k_tcast<<<dim3(2048 / 32, 2048 / 32), blk, 0, stream>>>(Wo, 2048, 2048, WT);
  k_gemm_bf16<<<dim3(16, 16), blk, 0, stream>>>(attn_b, 2048, WT, 2048, out, 2048, 2048, 0);

  (void)in_sizes; (void)n_in; (void)out_size; (void)ws_size;
}